// Round 11
// baseline (178.722 us; speedup 1.0000x reference)
//
#include <hip/hip_runtime.h>

#define BATCH 128
#define AST 88  // padded-A LDS row stride in ushorts (176B, 16B-aligned)

typedef __attribute__((ext_vector_type(8))) short bf16x8;
typedef __attribute__((ext_vector_type(16))) float f32x16;

// ---------------------------------------------------------------------------
// Spline activation: act[0] = silu(x), act[1..8] = cubic B-spline bases
// ---------------------------------------------------------------------------
__device__ __forceinline__ void spline_acts(float xv, float act[9]) {
    act[0] = xv * (1.0f / (1.0f + __expf(-xv)));  // silu
    float g[12];
#pragma unroll
    for (int i = 0; i < 12; ++i) g[i] = (float)(i - 3) * 0.4f - 1.0f;
    float bb[11];
#pragma unroll
    for (int c = 0; c < 11; ++c) bb[c] = (xv >= g[c] && xv < g[c + 1]) ? 1.0f : 0.0f;
#pragma unroll
    for (int k = 1; k <= 3; ++k) {
#pragma unroll
        for (int c = 0; c + k < 11; ++c) {
            float left  = (xv - g[c]) * (1.0f / (g[c + k] - g[c])) * bb[c];
            float right = (g[c + k + 1] - xv) * (1.0f / (g[c + k + 1] - g[c + 1])) * bb[c + 1];
            bb[c] = left + right;
        }
    }
#pragma unroll
    for (int c = 0; c < 8; ++c) act[c + 1] = bb[c];
}

__device__ __constant__ float ZPAD[9] = {0.0f, 0.0f, 0.0f, 0.02083333333f,
                                         0.47916666667f, 0.47916666667f,
                                         0.02083333333f, 0.0f, 0.0f};

// bf16 hi/lo split (round-to-nearest-even); x = hi + lo + O(2^-18 x)
__device__ __forceinline__ void bf16split(float x, ushort& h, ushort& l) {
    union { float f; unsigned u; } a; a.f = x;
    unsigned r = a.u + 0x7FFF + ((a.u >> 16) & 1);
    h = (ushort)(r >> 16);
    union { unsigned u; float f; } hf; hf.u = (unsigned)h << 16;
    union { float f; unsigned u; } bres; bres.f = x - hf.f;
    unsigned r2 = bres.u + 0x7FFF + ((bres.u >> 16) & 1);
    l = (ushort)(r2 >> 16);
}

// ---------------------------------------------------------------------------
// Pack weights (fp32): wpack[(cin*9+tap)*9*O + j*O + o] = j==0 ? bw : sw*sc
// ---------------------------------------------------------------------------
__device__ __forceinline__ void pack_one(int i, const float* bw, const float* sw,
                                         const float* sc, float* out, int F, int O) {
    int o = i % O;
    int j = (i / O) % 9;
    int f = i / (9 * O);
    float v;
    if (j == 0) v = bw[o * F + f];
    else        v = sw[(o * F + f) * 8 + (j - 1)] * sc[o * F + f];
    out[i] = v;
}

__global__ void pack_all(const float* __restrict__ bw1, const float* __restrict__ sw1,
                         const float* __restrict__ sc1, const float* __restrict__ bw2,
                         const float* __restrict__ sw2, const float* __restrict__ sc2,
                         const float* __restrict__ bw3, const float* __restrict__ sw3,
                         const float* __restrict__ sc3, const float* __restrict__ bw4,
                         const float* __restrict__ sw4, const float* __restrict__ sc4,
                         float* __restrict__ ws) {
    int i = blockIdx.x * blockDim.x + threadIdx.x;
    if (i < 972)        pack_one(i,         bw1, sw1, sc1, ws,         27, 4);
    else if (i < 3564)  pack_one(i - 972,   bw2, sw2, sc2, ws + 972,   36, 8);
    else if (i < 13932) pack_one(i - 3564,  bw3, sw3, sc3, ws + 3564,  72, 16);
    else if (i < 55404) pack_one(i - 13932, bw4, sw4, sc4, ws + 13932, 144, 32);
}

// ---------------------------------------------------------------------------
// Pack MFMA B-fragments (bf16 hi/lo) for all 4 conv layers + zp pattern.
// B-frag (32x32x16): value(lane l, elem e) = W[k = s*16+(l>>5)*8+e][o = l&31]
// ---------------------------------------------------------------------------
__global__ void pack_frags(const float* __restrict__ wp1, const float* __restrict__ wp2,
                           const float* __restrict__ wp3, const float* __restrict__ wp4,
                           ushort* __restrict__ k1h, ushort* __restrict__ k1l,
                           ushort* __restrict__ k2h, ushort* __restrict__ k2l,
                           ushort* __restrict__ k3h, ushort* __restrict__ k3l,
                           ushort* __restrict__ k4h, ushort* __restrict__ k4l,
                           ushort* __restrict__ zph, ushort* __restrict__ zpl) {
    int i = blockIdx.x * 256 + threadIdx.x;
    if (i < 1152) {                            // conv1: (t, 2 ksteps, l)
        int l = i & 63, s = (i >> 6) & 1, t = i / 128;
#pragma unroll
        for (int e = 0; e < 8; ++e) {
            int k = s * 16 + ((l >> 5) * 8) + e, o = l & 31;
            float w = 0.f;
            if (k < 27 && o < 4) w = wp1[(((k / 9) * 9 + t) * 9 + (k % 9)) * 4 + o];
            ushort h, lo; bf16split(w, h, lo);
            k1h[i * 8 + e] = h; k1l[i * 8 + e] = lo;
        }
    } else if (i < 2880) {                     // conv2: (t, 3 ksteps, l)
        int q = i - 1152;
        int l = q & 63, s = (q >> 6) % 3, t = q / 192;
#pragma unroll
        for (int e = 0; e < 8; ++e) {
            int k = s * 16 + ((l >> 5) * 8) + e, o = l & 31;
            float w = 0.f;
            if (k < 36 && o < 8) w = wp2[(((k / 9) * 9 + t) * 9 + (k % 9)) * 8 + o];
            ushort h, lo; bf16split(w, h, lo);
            k2h[q * 8 + e] = h; k2l[q * 8 + e] = lo;
        }
    } else if (i < 5760) {                     // conv3: (t, 5 ksteps, l)
        int q = i - 2880;
        int l = q & 63, s = (q >> 6) % 5, t = q / 320;
#pragma unroll
        for (int e = 0; e < 8; ++e) {
            int k = s * 16 + ((l >> 5) * 8) + e, o = l & 31;
            float w = 0.f;
            if (k < 72 && o < 16) w = wp3[(((k / 9) * 9 + t) * 9 + (k % 9)) * 16 + o];
            ushort h, lo; bf16split(w, h, lo);
            k3h[q * 8 + e] = h; k3l[q * 8 + e] = lo;
        }
    } else if (i < 11520) {                    // conv4: (phase, t, 5 ksteps, l)
        int q = i - 5760;
        int l = q & 63, s = (q >> 6) % 5, t = (q / 320) % 9, p = q / 2880;
#pragma unroll
        for (int e = 0; e < 8; ++e) {
            int k = s * 16 + ((l >> 5) * 8) + e, o = l & 31;
            float w = 0.f;
            if (k < 72) w = wp4[(((p * 8 + k / 9) * 9 + t) * 9 + (k % 9)) * 32 + o];
            ushort h, lo; bf16split(w, h, lo);
            k4h[q * 8 + e] = h; k4l[q * 8 + e] = lo;
        }
    } else if (i < 11600) {
        int c = i - 11520;
        ushort h, lo; bf16split(ZPAD[c % 9], h, lo);
        zph[c] = h; zpl[c] = lo;
    }
}

// ---------------------------------------------------------------------------
// spline_x: raw x (B,3,32,32) -> A1 (B,1024,28) bf16 hi/lo, coalesced via LDS
// ---------------------------------------------------------------------------
__global__ __launch_bounds__(256) void spline_x(const float* __restrict__ x,
                                                ushort* __restrict__ A1h,
                                                ushort* __restrict__ A1l) {
    __shared__ unsigned SB[7168];  // hi words [0,3584), lo words [3584,7168)
    int i = blockIdx.x * 256 + threadIdx.x;
    int px = i & 1023, b = i >> 10;
    const float* xb = x + (size_t)b * 3072 + px;
    unsigned rh[14] = {}, rl[14] = {};
#pragma unroll
    for (int cin = 0; cin < 3; ++cin) {
        float a9[9];
        spline_acts(xb[cin * 1024], a9);
#pragma unroll
        for (int j = 0; j < 9; ++j) {
            ushort h, l2; bf16split(a9[j], h, l2);
            int c = cin * 9 + j;
            if (c & 1) { rh[c >> 1] |= (unsigned)h << 16; rl[c >> 1] |= (unsigned)l2 << 16; }
            else       { rh[c >> 1] |= h;                  rl[c >> 1] |= l2; }
        }
    }
    int wb = threadIdx.x * 14;
#pragma unroll
    for (int w = 0; w < 14; ++w) { SB[wb + w] = rh[w]; SB[3584 + wb + w] = rl[w]; }
    __syncthreads();
    const ushort* sb = (const ushort*)SB;
    size_t base = (size_t)blockIdx.x * 7168;
#pragma unroll
    for (int e = 0; e < 4; ++e) {
        int q = e * 256 + threadIdx.x;
        if (q < 896) {
            *(uint4*)(A1h + base + q * 8) = *(const uint4*)(sb + q * 8);
            *(uint4*)(A1l + base + q * 8) = *(const uint4*)(sb + 7168 + q * 8);
        }
    }
}

// ---------------------------------------------------------------------------
// Strip MFMA conv for 32x32 layers (conv1/conv2) — unchanged from round 10.
// ---------------------------------------------------------------------------
template <int KG, int CHG, int CHL, int ASTR, int KSTEPS, int NCO, int EPI>
__global__ __launch_bounds__(256) void conv_strip(
    const ushort* __restrict__ Agh, const ushort* __restrict__ Agl,
    const ushort* __restrict__ Bgh, const ushort* __restrict__ Bgl,
    const ushort* __restrict__ zph, const ushort* __restrict__ zpl,
    ushort* __restrict__ Oh, ushort* __restrict__ Ol) {
    __shared__ ushort AH[340 * ASTR];
    __shared__ ushort AL[340 * ASTR];
    const int tid = threadIdx.x;
    const int b = blockIdx.x >> 2, strip = blockIdx.x & 3;
    const int r0 = strip * 8;
    const int lane = tid & 63, wv = tid >> 6;

    {
        const ushort* ash = Agh + (size_t)b * 1024 * KG;
        const ushort* asl = Agl + (size_t)b * 1024 * KG;
        for (int idx = tid; idx < 320 * CHL; idx += 256) {
            int pxl = idx / CHL, ch = idx - pxl * CHL;
            int lr = pxl >> 5, c = pxl & 31;
            int grow = r0 - 1 + lr;
            uint2 vh, vl;
            if (ch >= CHG) { vh = make_uint2(0u, 0u); vl = make_uint2(0u, 0u); }
            else if ((unsigned)grow < 32u) {
                vh = *(const uint2*)(ash + (size_t)(grow * 32 + c) * KG + ch * 4);
                vl = *(const uint2*)(asl + (size_t)(grow * 32 + c) * KG + ch * 4);
            } else {
                vh = *(const uint2*)(zph + ch * 4);
                vl = *(const uint2*)(zpl + ch * 4);
            }
            int spx = lr * 34 + c + 1;
            *(uint2*)(&AH[spx * ASTR + ch * 4]) = vh;
            *(uint2*)(&AL[spx * ASTR + ch * 4]) = vl;
        }
        for (int idx = tid; idx < 20 * CHL; idx += 256) {
            int sel = idx / CHL, ch = idx - sel * CHL;
            int lr = sel >> 1, c = (sel & 1) ? 33 : 0;
            int spx = lr * 34 + c;
            uint2 vh, vl;
            if (ch >= CHG) { vh = make_uint2(0u, 0u); vl = make_uint2(0u, 0u); }
            else { vh = *(const uint2*)(zph + ch * 4); vl = *(const uint2*)(zpl + ch * 4); }
            *(uint2*)(&AH[spx * ASTR + ch * 4]) = vh;
            *(uint2*)(&AL[spx * ASTR + ch * 4]) = vl;
        }
    }
    __syncthreads();

    f32x16 acc0, acc1;
#pragma unroll
    for (int i = 0; i < 16; ++i) { acc0[i] = 0.f; acc1[i] = 0.f; }

    const int p0 = wv * 64 + (lane & 31);
    const int sp0 = ((p0 >> 5) + 1) * 34 + (p0 & 31) + 1;
    const int sp1 = sp0 + 34;
    const int koff = (lane >> 5) * 8;

#pragma unroll 1
    for (int t = 0; t < 9; ++t) {
        const int dA = ((t / 3) - 1) * 34 + (t % 3) - 1;
#pragma unroll
        for (int s = 0; s < KSTEPS; ++s) {
            bf16x8 a0h = *(const bf16x8*)(&AH[(sp0 + dA) * ASTR + s * 16 + koff]);
            bf16x8 a0l = *(const bf16x8*)(&AL[(sp0 + dA) * ASTR + s * 16 + koff]);
            bf16x8 a1h = *(const bf16x8*)(&AH[(sp1 + dA) * ASTR + s * 16 + koff]);
            bf16x8 a1l = *(const bf16x8*)(&AL[(sp1 + dA) * ASTR + s * 16 + koff]);
            bf16x8 bh = *(const bf16x8*)(Bgh + (size_t)((t * KSTEPS + s) * 64 + lane) * 8);
            bf16x8 bl = *(const bf16x8*)(Bgl + (size_t)((t * KSTEPS + s) * 64 + lane) * 8);
            acc0 = __builtin_amdgcn_mfma_f32_32x32x16_bf16(a0h, bh, acc0, 0, 0, 0);
            acc1 = __builtin_amdgcn_mfma_f32_32x32x16_bf16(a1h, bh, acc1, 0, 0, 0);
            acc0 = __builtin_amdgcn_mfma_f32_32x32x16_bf16(a0h, bl, acc0, 0, 0, 0);
            acc1 = __builtin_amdgcn_mfma_f32_32x32x16_bf16(a1h, bl, acc1, 0, 0, 0);
            acc0 = __builtin_amdgcn_mfma_f32_32x32x16_bf16(a0l, bh, acc0, 0, 0, 0);
            acc1 = __builtin_amdgcn_mfma_f32_32x32x16_bf16(a1l, bh, acc1, 0, 0, 0);
        }
    }
    __syncthreads();

    float* fl = (float*)AH;
    {
        int ccol = lane & 31;
        if (ccol < NCO) {
#pragma unroll
            for (int r = 0; r < 16; ++r) {
                int row = (r & 3) + 8 * (r >> 2) + 4 * (lane >> 5);
                fl[ccol * 257 + wv * 64 + row] = acc0[r];
                fl[ccol * 257 + wv * 64 + 32 + row] = acc1[r];
            }
        }
    }
    __syncthreads();

    if (EPI == 0) {
        unsigned* ubh = (unsigned*)AL;
        unsigned* ubl = (unsigned*)AH + 1032;
        unsigned rwh[18], rwl[18];
#pragma unroll
        for (int w = 0; w < 18; ++w) { rwh[w] = 0u; rwl[w] = 0u; }
#pragma unroll
        for (int co = 0; co < 4; ++co) {
            float a9[9];
            spline_acts(fl[co * 257 + tid], a9);
#pragma unroll
            for (int j = 0; j < 9; ++j) {
                ushort h, l2; bf16split(a9[j], h, l2);
                int c = co * 9 + j;
                if (c & 1) { rwh[c >> 1] |= (unsigned)h << 16; rwl[c >> 1] |= (unsigned)l2 << 16; }
                else       { rwh[c >> 1] |= h;                  rwl[c >> 1] |= l2; }
            }
        }
#pragma unroll
        for (int w = 0; w < 18; ++w) { ubh[tid * 18 + w] = rwh[w]; ubl[tid * 18 + w] = rwl[w]; }
        __syncthreads();
        size_t basew = ((size_t)b * 1024 + strip * 256) * 18;
        unsigned* goh = (unsigned*)Oh + basew;
        unsigned* gol = (unsigned*)Ol + basew;
#pragma unroll
        for (int e = 0; e < 18; ++e) {
            int q = e * 256 + tid;
            goh[q] = ubh[q];
            gol[q] = ubl[q];
        }
    } else {
        int cg = tid >> 6, pl = tid & 63;
        int phl = pl >> 4, pw = pl & 15;
        int base_m = (2 * phl) * 32 + 2 * pw;
        unsigned rwh[9], rwl[9];
#pragma unroll
        for (int w = 0; w < 9; ++w) { rwh[w] = 0u; rwl[w] = 0u; }
#pragma unroll
        for (int e = 0; e < 2; ++e) {
            int co = cg * 2 + e;
            const float* fb = fl + co * 257 + base_m;
            float m = fmaxf(fmaxf(fb[0], fb[1]), fmaxf(fb[32], fb[33]));
            float a9[9];
            spline_acts(m, a9);
#pragma unroll
            for (int j = 0; j < 9; ++j) {
                ushort h, l2; bf16split(a9[j], h, l2);
                int c = e * 9 + j;
                if (c & 1) { rwh[c >> 1] |= (unsigned)h << 16; rwl[c >> 1] |= (unsigned)l2 << 16; }
                else       { rwh[c >> 1] |= h;                  rwl[c >> 1] |= l2; }
            }
        }
        unsigned* ubh = (unsigned*)AL;
        unsigned* ubl = (unsigned*)AL + 2560;
#pragma unroll
        for (int w = 0; w < 9; ++w) {
            ubh[pl * 40 + cg * 9 + w] = rwh[w];
            ubl[pl * 40 + cg * 9 + w] = rwl[w];
        }
        if (cg == 3) {
#pragma unroll
            for (int w = 0; w < 4; ++w) { ubh[pl * 40 + 36 + w] = 0u; ubl[pl * 40 + 36 + w] = 0u; }
        }
        __syncthreads();
        size_t base = ((size_t)b * 256 + strip * 64) * 80;
        const ushort* sbh = (const ushort*)ubh;
        const ushort* sbl = (const ushort*)ubl;
#pragma unroll
        for (int e = 0; e < 3; ++e) {
            int q = e * 256 + tid;
            if (q < 640) {
                *(uint4*)(Oh + base + q * 8) = *(const uint4*)(sbh + q * 8);
                *(uint4*)(Ol + base + q * 8) = *(const uint4*)(sbl + q * 8);
            }
        }
    }
}

// ---------------------------------------------------------------------------
// conv34_part: split-K MFMA partial for 16x16 layers.
// Block = (b, half 8-rows, z) where z = phase*3 + dh-group. Stages only the
// 8 input rows this dh-group needs (LDS 50KB -> 3 blocks/CU).
// Writes fp32 partials P[z][b*2+half][px 0..127][NCO] (coalesced from C-frag).
// ---------------------------------------------------------------------------
template <int NPH, int NCO>
__global__ __launch_bounds__(256) void conv34_part(
    const ushort* __restrict__ Agh, const ushort* __restrict__ Agl,
    const ushort* __restrict__ Bgh, const ushort* __restrict__ Bgl,
    const ushort* __restrict__ zph, const ushort* __restrict__ zpl,
    float* __restrict__ P) {
    __shared__ ushort AH[144 * AST];  // 25344 B
    __shared__ ushort AL[144 * AST];
    const int tid = threadIdx.x;
    const int b = blockIdx.x, half = blockIdx.y, z = blockIdx.z;
    const int p = z / 3, g = z % 3;   // cin-phase, dh-group
    const int r0 = half * 8;
    const int lane = tid & 63, wv = tid >> 6;

    // stage 8 rows x 18 padded cols of phase p: input rows r0-1+g .. r0+6+g
    {
        const ushort* ash = Agh + ((size_t)b * NPH + p) * 256 * 80;
        const ushort* asl = Agl + ((size_t)b * NPH + p) * 256 * 80;
#pragma unroll
        for (int e = 0; e < 6; ++e) {
            int idx = e * 256 + tid;
            if (idx < 1440) {
                int px = idx / 10, ch = idx - px * 10;
                int pr = px / 18, pc = px - pr * 18;
                int r = r0 - 1 + g + pr, c = pc - 1;
                bool inb = ((unsigned)r < 16u) && ((unsigned)c < 16u);
                uint4 vh, vl;
                if (inb) {
                    vh = *(const uint4*)(ash + (size_t)(r * 16 + c) * 80 + ch * 8);
                    vl = *(const uint4*)(asl + (size_t)(r * 16 + c) * 80 + ch * 8);
                } else {
                    vh = *(const uint4*)(zph + ch * 8);
                    vl = *(const uint4*)(zpl + ch * 8);
                }
                *(uint4*)(&AH[px * AST + ch * 8]) = vh;
                *(uint4*)(&AL[px * AST + ch * 8]) = vl;
            }
        }
    }
    __syncthreads();

    f32x16 acc;
#pragma unroll
    for (int i = 0; i < 16; ++i) acc[i] = 0.f;

    const int m = wv * 32 + (lane & 31);        // local px 0..127
    const int sbase = (m >> 4) * 18 + (m & 15); // staged slot (row mr, col mc)
    const int koff = (lane >> 5) * 8;
    const ushort* bsh = Bgh + (size_t)p * 2880 * 8;
    const ushort* bsl = Bgl + (size_t)p * 2880 * 8;

#pragma unroll
    for (int dw = 0; dw < 3; ++dw) {
        const int t = g * 3 + dw;
#pragma unroll
        for (int s = 0; s < 5; ++s) {
            bf16x8 ah = *(const bf16x8*)(&AH[(sbase + dw) * AST + s * 16 + koff]);
            bf16x8 al = *(const bf16x8*)(&AL[(sbase + dw) * AST + s * 16 + koff]);
            bf16x8 bh = *(const bf16x8*)(bsh + (size_t)((t * 5 + s) * 64 + lane) * 8);
            bf16x8 bl = *(const bf16x8*)(bsl + (size_t)((t * 5 + s) * 64 + lane) * 8);
            acc = __builtin_amdgcn_mfma_f32_32x32x16_bf16(ah, bh, acc, 0, 0, 0);
            acc = __builtin_amdgcn_mfma_f32_32x32x16_bf16(ah, bl, acc, 0, 0, 0);
            acc = __builtin_amdgcn_mfma_f32_32x32x16_bf16(al, bh, acc, 0, 0, 0);
        }
    }

    // write partials: C-frag col (lane&31) = cout, coalesced over cout
    int co = lane & 31;
    if (co < NCO) {
        float* pb = P + ((size_t)(z * 256 + b * 2 + half) * 128) * NCO;
#pragma unroll
        for (int r = 0; r < 16; ++r) {
            int px = wv * 32 + (r & 3) + 8 * (r >> 2) + 4 * (lane >> 5);
            pb[px * NCO + co] = acc[r];
        }
    }
}

// ---------------------------------------------------------------------------
// conv3_reduce: sum 3 partials + spline -> A4 (B,2,256,80) bf16 hi/lo.
// Block = (b, out-phase p2); thread = px 0..255. LDS bounce for coalescing.
// ---------------------------------------------------------------------------
__global__ __launch_bounds__(256) void conv3_reduce(const float* __restrict__ P3,
                                                    ushort* __restrict__ A4h,
                                                    ushort* __restrict__ A4l) {
    __shared__ unsigned UBH[10240], UBL[10240];  // 256 px x 40 words
    int b = blockIdx.x, p2 = blockIdx.y;
    int px = threadIdx.x;
    int bh = b * 2 + (px >> 7), lpx = px & 127;

    unsigned rwh[40], rwl[40];
#pragma unroll
    for (int w = 0; w < 40; ++w) { rwh[w] = 0u; rwl[w] = 0u; }
#pragma unroll
    for (int e = 0; e < 8; ++e) {
        int co = p2 * 8 + e;
        float s = 0.f;
#pragma unroll
        for (int zz = 0; zz < 3; ++zz)
            s += P3[((size_t)(zz * 256 + bh) * 128 + lpx) * 16 + co];
        float a9[9];
        spline_acts(s, a9);
#pragma unroll
        for (int j = 0; j < 9; ++j) {
            ushort h, l2; bf16split(a9[j], h, l2);
            int c = e * 9 + j;
            if (c & 1) { rwh[c >> 1] |= (unsigned)h << 16; rwl[c >> 1] |= (unsigned)l2 << 16; }
            else       { rwh[c >> 1] |= h;                  rwl[c >> 1] |= l2; }
        }
    }
#pragma unroll
    for (int w = 0; w < 40; ++w) { UBH[px * 40 + w] = rwh[w]; UBL[px * 40 + w] = rwl[w]; }
    __syncthreads();
    const ushort* sbh = (const ushort*)UBH;
    const ushort* sbl = (const ushort*)UBL;
    size_t base = ((size_t)(b * 2 + p2) * 256) * 80;
#pragma unroll
    for (int e = 0; e < 10; ++e) {
        int q = e * 256 + px;  // 2560 uint4 per buffer
        *(uint4*)(A4h + base + q * 8) = *(const uint4*)(sbh + q * 8);
        *(uint4*)(A4l + base + q * 8) = *(const uint4*)(sbl + q * 8);
    }
}

// ---------------------------------------------------------------------------
// conv4_reduce_pool: sum 6 partials + 2x2 maxpool -> pooled (B, 2048) fp32.
// ---------------------------------------------------------------------------
__global__ __launch_bounds__(256) void conv4_reduce_pool(const float* __restrict__ P4,
                                                         float* __restrict__ pooled) {
    int i = blockIdx.x * 256 + threadIdx.x;  // 128*2048
    int b = i >> 11, idx = i & 2047;
    int co = idx >> 6, pp = idx & 63;
    int pr = pp >> 3, pc = pp & 7;
    int half = pr >> 2, lr = pr & 3;
    int bh = b * 2 + half;
    int px00 = (2 * lr) * 16 + 2 * pc;
    float s00 = 0.f, s01 = 0.f, s10 = 0.f, s11 = 0.f;
#pragma unroll
    for (int zz = 0; zz < 6; ++zz) {
        const float* pb = P4 + ((size_t)(zz * 256 + bh) * 128) * 32 + co;
        s00 += pb[(size_t)px00 * 32];
        s01 += pb[(size_t)(px00 + 1) * 32];
        s10 += pb[(size_t)(px00 + 16) * 32];
        s11 += pb[(size_t)(px00 + 17) * 32];
    }
    pooled[(size_t)b * 2048 + idx] = fmaxf(fmaxf(s00, s01), fmaxf(s10, s11));
}

// ---------------------------------------------------------------------------
// fc_big: 64x64 tile, 4x4/thread, K_TILE=32, split-K via blockIdx.z.
// ---------------------------------------------------------------------------
template <int SPLIT>
__global__ __launch_bounds__(256) void fc_big(const float* __restrict__ A,
                                              const float* __restrict__ Wt,
                                              float* __restrict__ part,
                                              int M, int N, int K) {
    __shared__ float As[32][68];
    __shared__ float Ws[32][68];
    const int tid = threadIdx.x;
    const int tx = tid & 15, ty = tid >> 4;
    const int bm = blockIdx.y * 64, bn = blockIdx.x * 64;
    const int kc = K / SPLIT;
    const int kbeg = blockIdx.z * kc;
    float acc[4][4] = {};
    for (int k0 = kbeg; k0 < kbeg + kc; k0 += 32) {
#pragma unroll
        for (int e = 0; e < 8; ++e) {
            int g = e * 256 + tid;
            int k = g & 31, r = g >> 5;
            As[k][r] = A[(size_t)(bm + r) * K + k0 + k];
            Ws[k][r] = Wt[(size_t)(bn + r) * K + k0 + k];
        }
        __syncthreads();
#pragma unroll
        for (int kk = 0; kk < 32; ++kk) {
            float4 av = *(const float4*)(&As[kk][ty * 4]);
            float4 wv = *(const float4*)(&Ws[kk][tx * 4]);
            acc[0][0] = fmaf(av.x, wv.x, acc[0][0]);
            acc[0][1] = fmaf(av.x, wv.y, acc[0][1]);
            acc[0][2] = fmaf(av.x, wv.z, acc[0][2]);
            acc[0][3] = fmaf(av.x, wv.w, acc[0][3]);
            acc[1][0] = fmaf(av.y, wv.x, acc[1][0]);
            acc[1][1] = fmaf(av.y, wv.y, acc[1][1]);
            acc[1][2] = fmaf(av.y, wv.z, acc[1][2]);
            acc[1][3] = fmaf(av.y, wv.w, acc[1][3]);
            acc[2][0] = fmaf(av.z, wv.x, acc[2][0]);
            acc[2][1] = fmaf(av.z, wv.y, acc[2][1]);
            acc[2][2] = fmaf(av.z, wv.z, acc[2][2]);
            acc[2][3] = fmaf(av.z, wv.w, acc[2][3]);
            acc[3][0] = fmaf(av.w, wv.x, acc[3][0]);
            acc[3][1] = fmaf(av.w, wv.y, acc[3][1]);
            acc[3][2] = fmaf(av.w, wv.z, acc[3][2]);
            acc[3][3] = fmaf(av.w, wv.w, acc[3][3]);
        }
        __syncthreads();
    }
    float* p = part + (size_t)blockIdx.z * M * N;
#pragma unroll
    for (int i = 0; i < 4; ++i) {
        float4 v = make_float4(acc[i][0], acc[i][1], acc[i][2], acc[i][3]);
        *(float4*)&p[(size_t)(bm + ty * 4 + i) * N + (bn + tx * 4)] = v;
    }
}

template <int SPLIT>
__global__ void fc_reduce(const float* __restrict__ part, const float* __restrict__ bias,
                          float* __restrict__ C, int MN, int N, int relu) {
    int i = blockIdx.x * 256 + threadIdx.x;
    if (i >= MN) return;
    float s = bias[i % N];
#pragma unroll
    for (int z = 0; z < SPLIT; ++z) s += part[(size_t)z * MN + i];
    C[i] = relu ? fmaxf(s, 0.f) : s;
}

__global__ __launch_bounds__(256) void fc3_kernel(const float* __restrict__ A,
                                                  const float* __restrict__ Wt,
                                                  const float* __restrict__ bias,
                                                  float* __restrict__ C) {
    int gid = blockIdx.x * 256 + threadIdx.x;
    int wid = gid >> 6;
    int lane = gid & 63;
    int m = wid / 10, n = wid - m * 10;
    const float4* a = (const float4*)(A + (size_t)m * 1024);
    const float4* w = (const float4*)(Wt + (size_t)n * 1024);
    float s = 0.f;
#pragma unroll
    for (int it = 0; it < 4; ++it) {
        float4 av = a[it * 64 + lane];
        float4 wv = w[it * 64 + lane];
        s += av.x * wv.x + av.y * wv.y + av.z * wv.z + av.w * wv.w;
    }
#pragma unroll
    for (int off = 32; off; off >>= 1) s += __shfl_xor(s, off);
    if (lane == 0) C[wid] = s + bias[n];
}

// ---------------------------------------------------------------------------
extern "C" void kernel_launch(void* const* d_in, const int* in_sizes, int n_in,
                              void* d_out, int out_size, void* d_ws, size_t ws_size,
                              hipStream_t stream) {
    const float* x   = (const float*)d_in[0];
    const float* bw1 = (const float*)d_in[1];
    const float* sw1 = (const float*)d_in[2];
    const float* sc1 = (const float*)d_in[3];
    const float* bw2 = (const float*)d_in[4];
    const float* sw2 = (const float*)d_in[5];
    const float* sc2 = (const float*)d_in[6];
    const float* bw3 = (const float*)d_in[7];
    const float* sw3 = (const float*)d_in[8];
    const float* sc3 = (const float*)d_in[9];
    const float* bw4 = (const float*)d_in[10];
    const float* sw4 = (const float*)d_in[11];
    const float* sc4 = (const float*)d_in[12];
    const float* w1  = (const float*)d_in[13];
    const float* b1  = (const float*)d_in[14];
    const float* w2  = (const float*)d_in[15];
    const float* b2  = (const float*)d_in[16];
    const float* w3  = (const float*)d_in[17];
    const float* b3  = (const float*)d_in[18];

    float*  wsf = (float*)d_ws;
    ushort* wsu = (ushort*)d_ws;
    float* wp1 = wsf;
    float* wp2 = wsf + 972;
    float* wp3 = wsf + 3564;
    float* wp4 = wsf + 13932;
    ushort* k1h = wsu + 110848;
    ushort* k1l = wsu + 120064;
    ushort* k2h = wsu + 129280;
    ushort* k2l = wsu + 143104;
    ushort* k3h = wsu + 156928;
    ushort* k3l = wsu + 179968;
    ushort* k4h = wsu + 203008;
    ushort* k4l = wsu + 249088;
    ushort* zph = wsu + 295168;
    ushort* zpl = wsu + 295248;
    ushort* A1h = wsu + 524288;     // byte [1.0M, 8.4M)
    ushort* A1l = wsu + 4194304;    // byte [8.4M, 15.7M)
    ushort* A2h = wsu + 7864320;    // byte [15.7M, 25.2M)
    ushort* A2l = wsu + 12582912;   // byte [25.2M, 34.6M)
    ushort* A3h = wsu + 524288;     // byte [1.0M, 6.3M)  over dead A1
    ushort* A3l = wsu + 3145728;    // byte [6.3M, 11.5M)
    ushort* A4h = wsu + 5767168;    // byte [11.5M, 22.0M) over dead A2h-part
    ushort* A4l = wsu + 11010048;   // byte [22.0M, 32.5M)
    float* P3   = wsf + 9437184;    // byte [36.0M, 42.3M) 3x256x128x16
    float* P4   = wsf + 11534336;   // byte [44.0M, 69.2M) 6x256x128x32
    float* pooled = wsf + 262144;   // byte [1.0M, 2.0M)
    float* part1  = wsf + 524288;   // byte [2.0M, 10.4M)
    float* fc1o   = wsf + 2621440;  // byte [10.4M, 11.5M)
    float* part2  = wsf + 2883584;  // byte [11.5M, 15.5M)
    float* fc2o   = wsf + 3932160;  // byte [15.7M, 16.3M)
    // ws_size ~268 MB (observed poison fill); peak use ~69 MB

    pack_all<<<(55404 + 255) / 256, 256, 0, stream>>>(bw1, sw1, sc1, bw2, sw2, sc2,
                                                      bw3, sw3, sc3, bw4, sw4, sc4, wsf);
    pack_frags<<<46, 256, 0, stream>>>(wp1, wp2, wp3, wp4, k1h, k1l, k2h, k2l,
                                       k3h, k3l, k4h, k4l, zph, zpl);

    spline_x<<<512, 256, 0, stream>>>(x, A1h, A1l);
    conv_strip<28, 7, 8, 40, 2, 4, 0><<<512, 256, 0, stream>>>(A1h, A1l, k1h, k1l,
                                                               zph, zpl, A2h, A2l);
    conv_strip<36, 9, 12, 56, 3, 8, 1><<<512, 256, 0, stream>>>(A2h, A2l, k2h, k2l,
                                                                zph, zpl, A3h, A3l);
    // conv3: split-K partials (z = dh-group) + reduce/spline -> A4
    conv34_part<1, 16><<<dim3(128, 2, 3), 256, 0, stream>>>(A3h, A3l, k3h, k3l,
                                                            zph, zpl, P3);
    conv3_reduce<<<dim3(128, 2), 256, 0, stream>>>(P3, A4h, A4l);
    // conv4: split-K partials (z = phase*3 + dh-group) + reduce/pool -> pooled
    conv34_part<2, 32><<<dim3(128, 2, 6), 256, 0, stream>>>(A4h, A4l, k4h, k4l,
                                                            zph, zpl, P4);
    conv4_reduce_pool<<<1024, 256, 0, stream>>>(P4, pooled);

    fc_big<8><<<dim3(32, 2, 8), 256, 0, stream>>>(pooled, w1, part1, 128, 2048, 2048);
    fc_reduce<8><<<1024, 256, 0, stream>>>(part1, b1, fc1o, 262144, 2048, 1);
    fc_big<8><<<dim3(16, 2, 8), 256, 0, stream>>>(fc1o, w2, part2, 128, 1024, 2048);
    fc_reduce<8><<<512, 256, 0, stream>>>(part2, b2, fc2o, 131072, 1024, 1);
    fc3_kernel<<<320, 256, 0, stream>>>(fc2o, w3, b3, (float*)d_out);
}

// Round 12
// 152.426 us; speedup vs baseline: 1.1725x; 1.1725x over previous
//
#include <hip/hip_runtime.h>

#define BATCH 128
#define AST 88  // padded-A LDS row stride in ushorts (176B, 16B-aligned)

typedef __attribute__((ext_vector_type(8))) short bf16x8;
typedef __attribute__((ext_vector_type(16))) float f32x16;

// ---------------------------------------------------------------------------
// Spline activation: act[0] = silu(x), act[1..8] = cubic B-spline bases
// ---------------------------------------------------------------------------
__device__ __forceinline__ void spline_acts(float xv, float act[9]) {
    act[0] = xv * (1.0f / (1.0f + __expf(-xv)));  // silu
    float g[12];
#pragma unroll
    for (int i = 0; i < 12; ++i) g[i] = (float)(i - 3) * 0.4f - 1.0f;
    float bb[11];
#pragma unroll
    for (int c = 0; c < 11; ++c) bb[c] = (xv >= g[c] && xv < g[c + 1]) ? 1.0f : 0.0f;
#pragma unroll
    for (int k = 1; k <= 3; ++k) {
#pragma unroll
        for (int c = 0; c + k < 11; ++c) {
            float left  = (xv - g[c]) * (1.0f / (g[c + k] - g[c])) * bb[c];
            float right = (g[c + k + 1] - xv) * (1.0f / (g[c + k + 1] - g[c + 1])) * bb[c + 1];
            bb[c] = left + right;
        }
    }
#pragma unroll
    for (int c = 0; c < 8; ++c) act[c + 1] = bb[c];
}

__device__ __constant__ float ZPAD[9] = {0.0f, 0.0f, 0.0f, 0.02083333333f,
                                         0.47916666667f, 0.47916666667f,
                                         0.02083333333f, 0.0f, 0.0f};

// bf16 hi/lo split (round-to-nearest-even); x = hi + lo + O(2^-18 x)
__device__ __forceinline__ void bf16split(float x, ushort& h, ushort& l) {
    union { float f; unsigned u; } a; a.f = x;
    unsigned r = a.u + 0x7FFF + ((a.u >> 16) & 1);
    h = (ushort)(r >> 16);
    union { unsigned u; float f; } hf; hf.u = (unsigned)h << 16;
    union { float f; unsigned u; } bres; bres.f = x - hf.f;
    unsigned r2 = bres.u + 0x7FFF + ((bres.u >> 16) & 1);
    l = (ushort)(r2 >> 16);
}

// packed conv weight value: f = cin*9 + tap, j = spline idx
__device__ __forceinline__ float wval(const float* bw, const float* sw, const float* sc,
                                      int F, int f, int j, int o) {
    if (j == 0) return bw[o * F + f];
    return sw[(o * F + f) * 8 + (j - 1)] * sc[o * F + f];
}

// ---------------------------------------------------------------------------
// Pack MFMA B-fragments (bf16 hi/lo) for all 4 conv layers + zp pattern.
// Weights computed inline from bw/sw/sc (pack_all folded in).
// B-frag (32x32x16): value(lane l, elem e) = W[k = s*16+(l>>5)*8+e][o = l&31]
// ---------------------------------------------------------------------------
__global__ void pack_frags(
    const float* __restrict__ bw1, const float* __restrict__ sw1, const float* __restrict__ sc1,
    const float* __restrict__ bw2, const float* __restrict__ sw2, const float* __restrict__ sc2,
    const float* __restrict__ bw3, const float* __restrict__ sw3, const float* __restrict__ sc3,
    const float* __restrict__ bw4, const float* __restrict__ sw4, const float* __restrict__ sc4,
    ushort* __restrict__ k1h, ushort* __restrict__ k1l,
    ushort* __restrict__ k2h, ushort* __restrict__ k2l,
    ushort* __restrict__ k3h, ushort* __restrict__ k3l,
    ushort* __restrict__ k4h, ushort* __restrict__ k4l,
    ushort* __restrict__ zph, ushort* __restrict__ zpl) {
    int i = blockIdx.x * 256 + threadIdx.x;
    if (i < 1152) {                            // conv1: (t, 2 ksteps, l)
        int l = i & 63, s = (i >> 6) & 1, t = i / 128;
#pragma unroll
        for (int e = 0; e < 8; ++e) {
            int k = s * 16 + ((l >> 5) * 8) + e, o = l & 31;
            float w = 0.f;
            if (k < 27 && o < 4) w = wval(bw1, sw1, sc1, 27, (k / 9) * 9 + t, k % 9, o);
            ushort h, lo; bf16split(w, h, lo);
            k1h[i * 8 + e] = h; k1l[i * 8 + e] = lo;
        }
    } else if (i < 2880) {                     // conv2: (t, 3 ksteps, l)
        int q = i - 1152;
        int l = q & 63, s = (q >> 6) % 3, t = q / 192;
#pragma unroll
        for (int e = 0; e < 8; ++e) {
            int k = s * 16 + ((l >> 5) * 8) + e, o = l & 31;
            float w = 0.f;
            if (k < 36 && o < 8) w = wval(bw2, sw2, sc2, 36, (k / 9) * 9 + t, k % 9, o);
            ushort h, lo; bf16split(w, h, lo);
            k2h[q * 8 + e] = h; k2l[q * 8 + e] = lo;
        }
    } else if (i < 5760) {                     // conv3: (t, 5 ksteps, l)
        int q = i - 2880;
        int l = q & 63, s = (q >> 6) % 5, t = q / 320;
#pragma unroll
        for (int e = 0; e < 8; ++e) {
            int k = s * 16 + ((l >> 5) * 8) + e, o = l & 31;
            float w = 0.f;
            if (k < 72 && o < 16) w = wval(bw3, sw3, sc3, 72, (k / 9) * 9 + t, k % 9, o);
            ushort h, lo; bf16split(w, h, lo);
            k3h[q * 8 + e] = h; k3l[q * 8 + e] = lo;
        }
    } else if (i < 11520) {                    // conv4: (phase, t, 5 ksteps, l)
        int q = i - 5760;
        int l = q & 63, s = (q >> 6) % 5, t = (q / 320) % 9, p = q / 2880;
#pragma unroll
        for (int e = 0; e < 8; ++e) {
            int k = s * 16 + ((l >> 5) * 8) + e, o = l & 31;
            float w = 0.f;
            if (k < 72) w = wval(bw4, sw4, sc4, 144, (p * 8 + k / 9) * 9 + t, k % 9, o);
            ushort h, lo; bf16split(w, h, lo);
            k4h[q * 8 + e] = h; k4l[q * 8 + e] = lo;
        }
    } else if (i < 11600) {
        int c = i - 11520;
        ushort h, lo; bf16split(ZPAD[c % 9], h, lo);
        zph[c] = h; zpl[c] = lo;
    }
}

// ---------------------------------------------------------------------------
// spline_x: raw x (B,3,32,32) -> A1 (B,1024,28) bf16 hi/lo, coalesced via LDS
// ---------------------------------------------------------------------------
__global__ __launch_bounds__(256) void spline_x(const float* __restrict__ x,
                                                ushort* __restrict__ A1h,
                                                ushort* __restrict__ A1l) {
    __shared__ unsigned SB[7168];  // hi words [0,3584), lo words [3584,7168)
    int i = blockIdx.x * 256 + threadIdx.x;
    int px = i & 1023, b = i >> 10;
    const float* xb = x + (size_t)b * 3072 + px;
    unsigned rh[14] = {}, rl[14] = {};
#pragma unroll
    for (int cin = 0; cin < 3; ++cin) {
        float a9[9];
        spline_acts(xb[cin * 1024], a9);
#pragma unroll
        for (int j = 0; j < 9; ++j) {
            ushort h, l2; bf16split(a9[j], h, l2);
            int c = cin * 9 + j;
            if (c & 1) { rh[c >> 1] |= (unsigned)h << 16; rl[c >> 1] |= (unsigned)l2 << 16; }
            else       { rh[c >> 1] |= h;                  rl[c >> 1] |= l2; }
        }
    }
    int wb = threadIdx.x * 14;
#pragma unroll
    for (int w = 0; w < 14; ++w) { SB[wb + w] = rh[w]; SB[3584 + wb + w] = rl[w]; }
    __syncthreads();
    const ushort* sb = (const ushort*)SB;
    size_t base = (size_t)blockIdx.x * 7168;
#pragma unroll
    for (int e = 0; e < 4; ++e) {
        int q = e * 256 + threadIdx.x;
        if (q < 896) {
            *(uint4*)(A1h + base + q * 8) = *(const uint4*)(sb + q * 8);
            *(uint4*)(A1l + base + q * 8) = *(const uint4*)(sb + 7168 + q * 8);
        }
    }
}

// ---------------------------------------------------------------------------
// Strip MFMA conv for 32x32 layers (conv1/conv2) — unchanged (verified).
// ---------------------------------------------------------------------------
template <int KG, int CHG, int CHL, int ASTR, int KSTEPS, int NCO, int EPI>
__global__ __launch_bounds__(256) void conv_strip(
    const ushort* __restrict__ Agh, const ushort* __restrict__ Agl,
    const ushort* __restrict__ Bgh, const ushort* __restrict__ Bgl,
    const ushort* __restrict__ zph, const ushort* __restrict__ zpl,
    ushort* __restrict__ Oh, ushort* __restrict__ Ol) {
    __shared__ ushort AH[340 * ASTR];
    __shared__ ushort AL[340 * ASTR];
    const int tid = threadIdx.x;
    const int b = blockIdx.x >> 2, strip = blockIdx.x & 3;
    const int r0 = strip * 8;
    const int lane = tid & 63, wv = tid >> 6;

    {
        const ushort* ash = Agh + (size_t)b * 1024 * KG;
        const ushort* asl = Agl + (size_t)b * 1024 * KG;
        for (int idx = tid; idx < 320 * CHL; idx += 256) {
            int pxl = idx / CHL, ch = idx - pxl * CHL;
            int lr = pxl >> 5, c = pxl & 31;
            int grow = r0 - 1 + lr;
            uint2 vh, vl;
            if (ch >= CHG) { vh = make_uint2(0u, 0u); vl = make_uint2(0u, 0u); }
            else if ((unsigned)grow < 32u) {
                vh = *(const uint2*)(ash + (size_t)(grow * 32 + c) * KG + ch * 4);
                vl = *(const uint2*)(asl + (size_t)(grow * 32 + c) * KG + ch * 4);
            } else {
                vh = *(const uint2*)(zph + ch * 4);
                vl = *(const uint2*)(zpl + ch * 4);
            }
            int spx = lr * 34 + c + 1;
            *(uint2*)(&AH[spx * ASTR + ch * 4]) = vh;
            *(uint2*)(&AL[spx * ASTR + ch * 4]) = vl;
        }
        for (int idx = tid; idx < 20 * CHL; idx += 256) {
            int sel = idx / CHL, ch = idx - sel * CHL;
            int lr = sel >> 1, c = (sel & 1) ? 33 : 0;
            int spx = lr * 34 + c;
            uint2 vh, vl;
            if (ch >= CHG) { vh = make_uint2(0u, 0u); vl = make_uint2(0u, 0u); }
            else { vh = *(const uint2*)(zph + ch * 4); vl = *(const uint2*)(zpl + ch * 4); }
            *(uint2*)(&AH[spx * ASTR + ch * 4]) = vh;
            *(uint2*)(&AL[spx * ASTR + ch * 4]) = vl;
        }
    }
    __syncthreads();

    f32x16 acc0, acc1;
#pragma unroll
    for (int i = 0; i < 16; ++i) { acc0[i] = 0.f; acc1[i] = 0.f; }

    const int p0 = wv * 64 + (lane & 31);
    const int sp0 = ((p0 >> 5) + 1) * 34 + (p0 & 31) + 1;
    const int sp1 = sp0 + 34;
    const int koff = (lane >> 5) * 8;

#pragma unroll 1
    for (int t = 0; t < 9; ++t) {
        const int dA = ((t / 3) - 1) * 34 + (t % 3) - 1;
#pragma unroll
        for (int s = 0; s < KSTEPS; ++s) {
            bf16x8 a0h = *(const bf16x8*)(&AH[(sp0 + dA) * ASTR + s * 16 + koff]);
            bf16x8 a0l = *(const bf16x8*)(&AL[(sp0 + dA) * ASTR + s * 16 + koff]);
            bf16x8 a1h = *(const bf16x8*)(&AH[(sp1 + dA) * ASTR + s * 16 + koff]);
            bf16x8 a1l = *(const bf16x8*)(&AL[(sp1 + dA) * ASTR + s * 16 + koff]);
            bf16x8 bh = *(const bf16x8*)(Bgh + (size_t)((t * KSTEPS + s) * 64 + lane) * 8);
            bf16x8 bl = *(const bf16x8*)(Bgl + (size_t)((t * KSTEPS + s) * 64 + lane) * 8);
            acc0 = __builtin_amdgcn_mfma_f32_32x32x16_bf16(a0h, bh, acc0, 0, 0, 0);
            acc1 = __builtin_amdgcn_mfma_f32_32x32x16_bf16(a1h, bh, acc1, 0, 0, 0);
            acc0 = __builtin_amdgcn_mfma_f32_32x32x16_bf16(a0h, bl, acc0, 0, 0, 0);
            acc1 = __builtin_amdgcn_mfma_f32_32x32x16_bf16(a1h, bl, acc1, 0, 0, 0);
            acc0 = __builtin_amdgcn_mfma_f32_32x32x16_bf16(a0l, bh, acc0, 0, 0, 0);
            acc1 = __builtin_amdgcn_mfma_f32_32x32x16_bf16(a1l, bh, acc1, 0, 0, 0);
        }
    }
    __syncthreads();

    float* fl = (float*)AH;
    {
        int ccol = lane & 31;
        if (ccol < NCO) {
#pragma unroll
            for (int r = 0; r < 16; ++r) {
                int row = (r & 3) + 8 * (r >> 2) + 4 * (lane >> 5);
                fl[ccol * 257 + wv * 64 + row] = acc0[r];
                fl[ccol * 257 + wv * 64 + 32 + row] = acc1[r];
            }
        }
    }
    __syncthreads();

    if (EPI == 0) {
        unsigned* ubh = (unsigned*)AL;
        unsigned* ubl = (unsigned*)AH + 1032;
        unsigned rwh[18], rwl[18];
#pragma unroll
        for (int w = 0; w < 18; ++w) { rwh[w] = 0u; rwl[w] = 0u; }
#pragma unroll
        for (int co = 0; co < 4; ++co) {
            float a9[9];
            spline_acts(fl[co * 257 + tid], a9);
#pragma unroll
            for (int j = 0; j < 9; ++j) {
                ushort h, l2; bf16split(a9[j], h, l2);
                int c = co * 9 + j;
                if (c & 1) { rwh[c >> 1] |= (unsigned)h << 16; rwl[c >> 1] |= (unsigned)l2 << 16; }
                else       { rwh[c >> 1] |= h;                  rwl[c >> 1] |= l2; }
            }
        }
#pragma unroll
        for (int w = 0; w < 18; ++w) { ubh[tid * 18 + w] = rwh[w]; ubl[tid * 18 + w] = rwl[w]; }
        __syncthreads();
        size_t basew = ((size_t)b * 1024 + strip * 256) * 18;
        unsigned* goh = (unsigned*)Oh + basew;
        unsigned* gol = (unsigned*)Ol + basew;
#pragma unroll
        for (int e = 0; e < 18; ++e) {
            int q = e * 256 + tid;
            goh[q] = ubh[q];
            gol[q] = ubl[q];
        }
    } else {
        int cg = tid >> 6, pl = tid & 63;
        int phl = pl >> 4, pw = pl & 15;
        int base_m = (2 * phl) * 32 + 2 * pw;
        unsigned rwh[9], rwl[9];
#pragma unroll
        for (int w = 0; w < 9; ++w) { rwh[w] = 0u; rwl[w] = 0u; }
#pragma unroll
        for (int e = 0; e < 2; ++e) {
            int co = cg * 2 + e;
            const float* fb = fl + co * 257 + base_m;
            float m = fmaxf(fmaxf(fb[0], fb[1]), fmaxf(fb[32], fb[33]));
            float a9[9];
            spline_acts(m, a9);
#pragma unroll
            for (int j = 0; j < 9; ++j) {
                ushort h, l2; bf16split(a9[j], h, l2);
                int c = e * 9 + j;
                if (c & 1) { rwh[c >> 1] |= (unsigned)h << 16; rwl[c >> 1] |= (unsigned)l2 << 16; }
                else       { rwh[c >> 1] |= h;                  rwl[c >> 1] |= l2; }
            }
        }
        unsigned* ubh = (unsigned*)AL;
        unsigned* ubl = (unsigned*)AL + 2560;
#pragma unroll
        for (int w = 0; w < 9; ++w) {
            ubh[pl * 40 + cg * 9 + w] = rwh[w];
            ubl[pl * 40 + cg * 9 + w] = rwl[w];
        }
        if (cg == 3) {
#pragma unroll
            for (int w = 0; w < 4; ++w) { ubh[pl * 40 + 36 + w] = 0u; ubl[pl * 40 + 36 + w] = 0u; }
        }
        __syncthreads();
        size_t base = ((size_t)b * 256 + strip * 64) * 80;
        const ushort* sbh = (const ushort*)ubh;
        const ushort* sbl = (const ushort*)ubl;
#pragma unroll
        for (int e = 0; e < 3; ++e) {
            int q = e * 256 + tid;
            if (q < 640) {
                *(uint4*)(Oh + base + q * 8) = *(const uint4*)(sbh + q * 8);
                *(uint4*)(Ol + base + q * 8) = *(const uint4*)(sbl + q * 8);
            }
        }
    }
}

// ---------------------------------------------------------------------------
// conv34_part: split-K MFMA partial for 16x16 layers (unchanged, verified).
// Writes fp32 partials P[z][b*2+half][px 0..127][NCO] (co-fast, coalesced).
// ---------------------------------------------------------------------------
template <int NPH, int NCO>
__global__ __launch_bounds__(256) void conv34_part(
    const ushort* __restrict__ Agh, const ushort* __restrict__ Agl,
    const ushort* __restrict__ Bgh, const ushort* __restrict__ Bgl,
    const ushort* __restrict__ zph, const ushort* __restrict__ zpl,
    float* __restrict__ P) {
    __shared__ ushort AH[144 * AST];
    __shared__ ushort AL[144 * AST];
    const int tid = threadIdx.x;
    const int b = blockIdx.x, half = blockIdx.y, z = blockIdx.z;
    const int p = z / 3, g = z % 3;
    const int r0 = half * 8;
    const int lane = tid & 63, wv = tid >> 6;

    {
        const ushort* ash = Agh + ((size_t)b * NPH + p) * 256 * 80;
        const ushort* asl = Agl + ((size_t)b * NPH + p) * 256 * 80;
#pragma unroll
        for (int e = 0; e < 6; ++e) {
            int idx = e * 256 + tid;
            if (idx < 1440) {
                int px = idx / 10, ch = idx - px * 10;
                int pr = px / 18, pc = px - pr * 18;
                int r = r0 - 1 + g + pr, c = pc - 1;
                bool inb = ((unsigned)r < 16u) && ((unsigned)c < 16u);
                uint4 vh, vl;
                if (inb) {
                    vh = *(const uint4*)(ash + (size_t)(r * 16 + c) * 80 + ch * 8);
                    vl = *(const uint4*)(asl + (size_t)(r * 16 + c) * 80 + ch * 8);
                } else {
                    vh = *(const uint4*)(zph + ch * 8);
                    vl = *(const uint4*)(zpl + ch * 8);
                }
                *(uint4*)(&AH[px * AST + ch * 8]) = vh;
                *(uint4*)(&AL[px * AST + ch * 8]) = vl;
            }
        }
    }
    __syncthreads();

    f32x16 acc;
#pragma unroll
    for (int i = 0; i < 16; ++i) acc[i] = 0.f;

    const int m = wv * 32 + (lane & 31);
    const int sbase = (m >> 4) * 18 + (m & 15);
    const int koff = (lane >> 5) * 8;
    const ushort* bsh = Bgh + (size_t)p * 2880 * 8;
    const ushort* bsl = Bgl + (size_t)p * 2880 * 8;

#pragma unroll
    for (int dw = 0; dw < 3; ++dw) {
        const int t = g * 3 + dw;
#pragma unroll
        for (int s = 0; s < 5; ++s) {
            bf16x8 ah = *(const bf16x8*)(&AH[(sbase + dw) * AST + s * 16 + koff]);
            bf16x8 al = *(const bf16x8*)(&AL[(sbase + dw) * AST + s * 16 + koff]);
            bf16x8 bh = *(const bf16x8*)(bsh + (size_t)((t * 5 + s) * 64 + lane) * 8);
            bf16x8 bl = *(const bf16x8*)(bsl + (size_t)((t * 5 + s) * 64 + lane) * 8);
            acc = __builtin_amdgcn_mfma_f32_32x32x16_bf16(ah, bh, acc, 0, 0, 0);
            acc = __builtin_amdgcn_mfma_f32_32x32x16_bf16(ah, bl, acc, 0, 0, 0);
            acc = __builtin_amdgcn_mfma_f32_32x32x16_bf16(al, bh, acc, 0, 0, 0);
        }
    }

    int co = lane & 31;
    if (co < NCO) {
        float* pb = P + ((size_t)(z * 256 + b * 2 + half) * 128) * NCO;
#pragma unroll
        for (int r = 0; r < 16; ++r) {
            int px = wv * 32 + (r & 3) + 8 * (r >> 2) + 4 * (lane >> 5);
            pb[px * NCO + co] = acc[r];
        }
    }
}

// ---------------------------------------------------------------------------
// conv3_reduce v2: sum 3 partials + spline -> A4 (B,2,256,80) bf16 hi/lo.
// Thread = (co8 fast, px slow) so P3 reads are lane-coalesced over co.
// ---------------------------------------------------------------------------
__global__ __launch_bounds__(256) void conv3_reduce(const float* __restrict__ P3,
                                                    ushort* __restrict__ A4h,
                                                    ushort* __restrict__ A4l) {
    __shared__ ushort SBH[20480], SBL[20480];  // 256 px x 80 ushorts
    int b = blockIdx.x, p2 = blockIdx.y;
    int t = threadIdx.x;
    int co8 = t & 7, pxg = t >> 3;  // 0..31
    int co = p2 * 8 + co8;

#pragma unroll
    for (int q = 0; q < 8; ++q) {
        int px = pxg * 8 + q;                 // 0..255
        int bh = b * 2 + (px >> 7), lpx = px & 127;
        float s = 0.f;
#pragma unroll
        for (int zz = 0; zz < 3; ++zz)
            s += P3[((size_t)(zz * 256 + bh) * 128 + lpx) * 16 + co];
        float a9[9];
        spline_acts(s, a9);
#pragma unroll
        for (int j = 0; j < 9; ++j) {
            ushort h, l2; bf16split(a9[j], h, l2);
            SBH[px * 80 + co8 * 9 + j] = h;
            SBL[px * 80 + co8 * 9 + j] = l2;
        }
        if (co8 == 7) {
#pragma unroll
            for (int w = 0; w < 8; ++w) { SBH[px * 80 + 72 + w] = 0; SBL[px * 80 + 72 + w] = 0; }
        }
    }
    __syncthreads();
    size_t base = ((size_t)(b * 2 + p2) * 256) * 80;
#pragma unroll
    for (int e = 0; e < 10; ++e) {
        int q = e * 256 + t;  // 2560 uint4 per buffer
        *(uint4*)(A4h + base + q * 8) = *(const uint4*)(SBH + q * 8);
        *(uint4*)(A4l + base + q * 8) = *(const uint4*)(SBL + q * 8);
    }
}

// ---------------------------------------------------------------------------
// conv4_reduce_pool v2: sum 6 partials + 2x2 maxpool -> pooled (B,2048) fp32.
// Thread = (co fast, pool-px slow): P4 reads lane-coalesced; LDS bounce store.
// ---------------------------------------------------------------------------
__global__ __launch_bounds__(256) void conv4_reduce_pool(const float* __restrict__ P4,
                                                         float* __restrict__ pooled) {
    __shared__ float SM[32 * 65];
    int b = blockIdx.x;
    int t = threadIdx.x;
    int co = t & 31, pg = t >> 5;  // pg 0..7
#pragma unroll
    for (int q = 0; q < 8; ++q) {
        int pp = pg * 8 + q;       // 0..63
        int pr = pp >> 3, pc = pp & 7;
        int half = pr >> 2, lr = pr & 3;
        int bh = b * 2 + half;
        int px00 = (2 * lr) * 16 + 2 * pc;
        float s00 = 0.f, s01 = 0.f, s10 = 0.f, s11 = 0.f;
#pragma unroll
        for (int zz = 0; zz < 6; ++zz) {
            const float* pb = P4 + ((size_t)(zz * 256 + bh) * 128) * 32 + co;
            s00 += pb[(size_t)px00 * 32];
            s01 += pb[(size_t)(px00 + 1) * 32];
            s10 += pb[(size_t)(px00 + 16) * 32];
            s11 += pb[(size_t)(px00 + 17) * 32];
        }
        SM[co * 65 + pp] = fmaxf(fmaxf(s00, s01), fmaxf(s10, s11));
    }
    __syncthreads();
#pragma unroll
    for (int e = 0; e < 8; ++e) {
        int idx = e * 256 + t;     // 0..2047
        pooled[(size_t)b * 2048 + idx] = SM[(idx >> 6) * 65 + (idx & 63)];
    }
}

// ---------------------------------------------------------------------------
// fc_big: 64x64 tile, 4x4/thread, K_TILE=32, split-K via blockIdx.z.
// ---------------------------------------------------------------------------
template <int SPLIT>
__global__ __launch_bounds__(256) void fc_big(const float* __restrict__ A,
                                              const float* __restrict__ Wt,
                                              float* __restrict__ part,
                                              int M, int N, int K) {
    __shared__ float As[32][68];
    __shared__ float Ws[32][68];
    const int tid = threadIdx.x;
    const int tx = tid & 15, ty = tid >> 4;
    const int bm = blockIdx.y * 64, bn = blockIdx.x * 64;
    const int kc = K / SPLIT;
    const int kbeg = blockIdx.z * kc;
    float acc[4][4] = {};
    for (int k0 = kbeg; k0 < kbeg + kc; k0 += 32) {
#pragma unroll
        for (int e = 0; e < 8; ++e) {
            int g = e * 256 + tid;
            int k = g & 31, r = g >> 5;
            As[k][r] = A[(size_t)(bm + r) * K + k0 + k];
            Ws[k][r] = Wt[(size_t)(bn + r) * K + k0 + k];
        }
        __syncthreads();
#pragma unroll
        for (int kk = 0; kk < 32; ++kk) {
            float4 av = *(const float4*)(&As[kk][ty * 4]);
            float4 wv = *(const float4*)(&Ws[kk][tx * 4]);
            acc[0][0] = fmaf(av.x, wv.x, acc[0][0]);
            acc[0][1] = fmaf(av.x, wv.y, acc[0][1]);
            acc[0][2] = fmaf(av.x, wv.z, acc[0][2]);
            acc[0][3] = fmaf(av.x, wv.w, acc[0][3]);
            acc[1][0] = fmaf(av.y, wv.x, acc[1][0]);
            acc[1][1] = fmaf(av.y, wv.y, acc[1][1]);
            acc[1][2] = fmaf(av.y, wv.z, acc[1][2]);
            acc[1][3] = fmaf(av.y, wv.w, acc[1][3]);
            acc[2][0] = fmaf(av.z, wv.x, acc[2][0]);
            acc[2][1] = fmaf(av.z, wv.y, acc[2][1]);
            acc[2][2] = fmaf(av.z, wv.z, acc[2][2]);
            acc[2][3] = fmaf(av.z, wv.w, acc[2][3]);
            acc[3][0] = fmaf(av.w, wv.x, acc[3][0]);
            acc[3][1] = fmaf(av.w, wv.y, acc[3][1]);
            acc[3][2] = fmaf(av.w, wv.z, acc[3][2]);
            acc[3][3] = fmaf(av.w, wv.w, acc[3][3]);
        }
        __syncthreads();
    }
    float* p = part + (size_t)blockIdx.z * M * N;
#pragma unroll
    for (int i = 0; i < 4; ++i) {
        float4 v = make_float4(acc[i][0], acc[i][1], acc[i][2], acc[i][3]);
        *(float4*)&p[(size_t)(bm + ty * 4 + i) * N + (bn + tx * 4)] = v;
    }
}

template <int SPLIT>
__global__ void fc_reduce(const float* __restrict__ part, const float* __restrict__ bias,
                          float* __restrict__ C, int MN, int N, int relu) {
    int i = blockIdx.x * 256 + threadIdx.x;
    if (i >= MN) return;
    float s = bias[i % N];
#pragma unroll
    for (int z = 0; z < SPLIT; ++z) s += part[(size_t)z * MN + i];
    C[i] = relu ? fmaxf(s, 0.f) : s;
}

__global__ __launch_bounds__(256) void fc3_kernel(const float* __restrict__ A,
                                                  const float* __restrict__ Wt,
                                                  const float* __restrict__ bias,
                                                  float* __restrict__ C) {
    int gid = blockIdx.x * 256 + threadIdx.x;
    int wid = gid >> 6;
    int lane = gid & 63;
    int m = wid / 10, n = wid - m * 10;
    const float4* a = (const float4*)(A + (size_t)m * 1024);
    const float4* w = (const float4*)(Wt + (size_t)n * 1024);
    float s = 0.f;
#pragma unroll
    for (int it = 0; it < 4; ++it) {
        float4 av = a[it * 64 + lane];
        float4 wv = w[it * 64 + lane];
        s += av.x * wv.x + av.y * wv.y + av.z * wv.z + av.w * wv.w;
    }
#pragma unroll
    for (int off = 32; off; off >>= 1) s += __shfl_xor(s, off);
    if (lane == 0) C[wid] = s + bias[n];
}

// ---------------------------------------------------------------------------
extern "C" void kernel_launch(void* const* d_in, const int* in_sizes, int n_in,
                              void* d_out, int out_size, void* d_ws, size_t ws_size,
                              hipStream_t stream) {
    const float* x   = (const float*)d_in[0];
    const float* bw1 = (const float*)d_in[1];
    const float* sw1 = (const float*)d_in[2];
    const float* sc1 = (const float*)d_in[3];
    const float* bw2 = (const float*)d_in[4];
    const float* sw2 = (const float*)d_in[5];
    const float* sc2 = (const float*)d_in[6];
    const float* bw3 = (const float*)d_in[7];
    const float* sw3 = (const float*)d_in[8];
    const float* sc3 = (const float*)d_in[9];
    const float* bw4 = (const float*)d_in[10];
    const float* sw4 = (const float*)d_in[11];
    const float* sc4 = (const float*)d_in[12];
    const float* w1  = (const float*)d_in[13];
    const float* b1  = (const float*)d_in[14];
    const float* w2  = (const float*)d_in[15];
    const float* b2  = (const float*)d_in[16];
    const float* w3  = (const float*)d_in[17];
    const float* b3  = (const float*)d_in[18];

    float*  wsf = (float*)d_ws;
    ushort* wsu = (ushort*)d_ws;
    ushort* k1h = wsu + 110848;
    ushort* k1l = wsu + 120064;
    ushort* k2h = wsu + 129280;
    ushort* k2l = wsu + 143104;
    ushort* k3h = wsu + 156928;
    ushort* k3l = wsu + 179968;
    ushort* k4h = wsu + 203008;
    ushort* k4l = wsu + 249088;
    ushort* zph = wsu + 295168;
    ushort* zpl = wsu + 295248;
    ushort* A1h = wsu + 524288;
    ushort* A1l = wsu + 4194304;
    ushort* A2h = wsu + 7864320;
    ushort* A2l = wsu + 12582912;
    ushort* A3h = wsu + 524288;
    ushort* A3l = wsu + 3145728;
    ushort* A4h = wsu + 5767168;
    ushort* A4l = wsu + 11010048;
    float* P3   = wsf + 9437184;
    float* P4   = wsf + 11534336;
    float* pooled = wsf + 262144;
    float* part1  = wsf + 524288;
    float* fc1o   = wsf + 2621440;
    float* part2  = wsf + 2883584;
    float* fc2o   = wsf + 3932160;

    pack_frags<<<46, 256, 0, stream>>>(bw1, sw1, sc1, bw2, sw2, sc2,
                                       bw3, sw3, sc3, bw4, sw4, sc4,
                                       k1h, k1l, k2h, k2l, k3h, k3l, k4h, k4l,
                                       zph, zpl);

    spline_x<<<512, 256, 0, stream>>>(x, A1h, A1l);
    conv_strip<28, 7, 8, 40, 2, 4, 0><<<512, 256, 0, stream>>>(A1h, A1l, k1h, k1l,
                                                               zph, zpl, A2h, A2l);
    conv_strip<36, 9, 12, 56, 3, 8, 1><<<512, 256, 0, stream>>>(A2h, A2l, k2h, k2l,
                                                                zph, zpl, A3h, A3l);
    conv34_part<1, 16><<<dim3(128, 2, 3), 256, 0, stream>>>(A3h, A3l, k3h, k3l,
                                                            zph, zpl, P3);
    conv3_reduce<<<dim3(128, 2), 256, 0, stream>>>(P3, A4h, A4l);
    conv34_part<2, 32><<<dim3(128, 2, 6), 256, 0, stream>>>(A4h, A4l, k4h, k4l,
                                                            zph, zpl, P4);
    conv4_reduce_pool<<<128, 256, 0, stream>>>(P4, pooled);

    fc_big<8><<<dim3(32, 2, 8), 256, 0, stream>>>(pooled, w1, part1, 128, 2048, 2048);
    fc_reduce<8><<<1024, 256, 0, stream>>>(part1, b1, fc1o, 262144, 2048, 1);
    fc_big<8><<<dim3(16, 2, 8), 256, 0, stream>>>(fc1o, w2, part2, 128, 1024, 2048);
    fc_reduce<8><<<512, 256, 0, stream>>>(part2, b2, fc2o, 131072, 1024, 1);
    fc3_kernel<<<320, 256, 0, stream>>>(fc2o, w3, b3, (float*)d_out);
}

// Round 13
// 141.218 us; speedup vs baseline: 1.2656x; 1.0794x over previous
//
#include <hip/hip_runtime.h>

#define BATCH 128
#define AST 88  // padded-A LDS row stride in ushorts (176B, 16B-aligned)

typedef __attribute__((ext_vector_type(8))) short bf16x8;
typedef __attribute__((ext_vector_type(16))) float f32x16;

// ---------------------------------------------------------------------------
// Spline activation: act[0] = silu(x), act[1..8] = cubic B-spline bases
// ---------------------------------------------------------------------------
__device__ __forceinline__ void spline_acts(float xv, float act[9]) {
    act[0] = xv * (1.0f / (1.0f + __expf(-xv)));  // silu
    float g[12];
#pragma unroll
    for (int i = 0; i < 12; ++i) g[i] = (float)(i - 3) * 0.4f - 1.0f;
    float bb[11];
#pragma unroll
    for (int c = 0; c < 11; ++c) bb[c] = (xv >= g[c] && xv < g[c + 1]) ? 1.0f : 0.0f;
#pragma unroll
    for (int k = 1; k <= 3; ++k) {
#pragma unroll
        for (int c = 0; c + k < 11; ++c) {
            float left  = (xv - g[c]) * (1.0f / (g[c + k] - g[c])) * bb[c];
            float right = (g[c + k + 1] - xv) * (1.0f / (g[c + k + 1] - g[c + 1])) * bb[c + 1];
            bb[c] = left + right;
        }
    }
#pragma unroll
    for (int c = 0; c < 8; ++c) act[c + 1] = bb[c];
}

__device__ __constant__ float ZPAD[9] = {0.0f, 0.0f, 0.0f, 0.02083333333f,
                                         0.47916666667f, 0.47916666667f,
                                         0.02083333333f, 0.0f, 0.0f};

// bf16 hi/lo split (round-to-nearest-even); x = hi + lo + O(2^-18 x)
__device__ __forceinline__ void bf16split(float x, ushort& h, ushort& l) {
    union { float f; unsigned u; } a; a.f = x;
    unsigned r = a.u + 0x7FFF + ((a.u >> 16) & 1);
    h = (ushort)(r >> 16);
    union { unsigned u; float f; } hf; hf.u = (unsigned)h << 16;
    union { float f; unsigned u; } bres; bres.f = x - hf.f;
    unsigned r2 = bres.u + 0x7FFF + ((bres.u >> 16) & 1);
    l = (ushort)(r2 >> 16);
}

// packed conv weight value: f = cin*9 + tap, j = spline idx
__device__ __forceinline__ float wval(const float* bw, const float* sw, const float* sc,
                                      int F, int f, int j, int o) {
    if (j == 0) return bw[o * F + f];
    return sw[(o * F + f) * 8 + (j - 1)] * sc[o * F + f];
}

// ---------------------------------------------------------------------------
// prep: blocks 0..45 pack MFMA B-fragments; blocks 46..557 do spline_x.
// B-frag (32x32x16): value(lane l, elem e) = W[k = s*16+(l>>5)*8+e][o = l&31]
// spline_x: raw x (B,3,32,32) -> A1 (B,1024,28) bf16 hi/lo via LDS bounce.
// ---------------------------------------------------------------------------
__global__ __launch_bounds__(256) void prep_kernel(
    const float* __restrict__ x,
    const float* __restrict__ bw1, const float* __restrict__ sw1, const float* __restrict__ sc1,
    const float* __restrict__ bw2, const float* __restrict__ sw2, const float* __restrict__ sc2,
    const float* __restrict__ bw3, const float* __restrict__ sw3, const float* __restrict__ sc3,
    const float* __restrict__ bw4, const float* __restrict__ sw4, const float* __restrict__ sc4,
    ushort* __restrict__ k1h, ushort* __restrict__ k1l,
    ushort* __restrict__ k2h, ushort* __restrict__ k2l,
    ushort* __restrict__ k3h, ushort* __restrict__ k3l,
    ushort* __restrict__ k4h, ushort* __restrict__ k4l,
    ushort* __restrict__ zph, ushort* __restrict__ zpl,
    ushort* __restrict__ A1h, ushort* __restrict__ A1l) {
    __shared__ unsigned SB[7168];
    if (blockIdx.x >= 46) {
        // ---- spline_x path ----
        int bid = blockIdx.x - 46;
        int i = bid * 256 + threadIdx.x;
        int px = i & 1023, b = i >> 10;
        const float* xb = x + (size_t)b * 3072 + px;
        unsigned rh[14] = {}, rl[14] = {};
#pragma unroll
        for (int cin = 0; cin < 3; ++cin) {
            float a9[9];
            spline_acts(xb[cin * 1024], a9);
#pragma unroll
            for (int j = 0; j < 9; ++j) {
                ushort h, l2; bf16split(a9[j], h, l2);
                int c = cin * 9 + j;
                if (c & 1) { rh[c >> 1] |= (unsigned)h << 16; rl[c >> 1] |= (unsigned)l2 << 16; }
                else       { rh[c >> 1] |= h;                  rl[c >> 1] |= l2; }
            }
        }
        int wb = threadIdx.x * 14;
#pragma unroll
        for (int w = 0; w < 14; ++w) { SB[wb + w] = rh[w]; SB[3584 + wb + w] = rl[w]; }
        __syncthreads();
        const ushort* sb = (const ushort*)SB;
        size_t base = (size_t)bid * 7168;
#pragma unroll
        for (int e = 0; e < 4; ++e) {
            int q = e * 256 + threadIdx.x;
            if (q < 896) {
                *(uint4*)(A1h + base + q * 8) = *(const uint4*)(sb + q * 8);
                *(uint4*)(A1l + base + q * 8) = *(const uint4*)(sb + 7168 + q * 8);
            }
        }
        return;
    }
    // ---- pack path ----
    int i = blockIdx.x * 256 + threadIdx.x;
    if (i < 1152) {                            // conv1: (t, 2 ksteps, l)
        int l = i & 63, s = (i >> 6) & 1, t = i / 128;
#pragma unroll
        for (int e = 0; e < 8; ++e) {
            int k = s * 16 + ((l >> 5) * 8) + e, o = l & 31;
            float w = 0.f;
            if (k < 27 && o < 4) w = wval(bw1, sw1, sc1, 27, (k / 9) * 9 + t, k % 9, o);
            ushort h, lo; bf16split(w, h, lo);
            k1h[i * 8 + e] = h; k1l[i * 8 + e] = lo;
        }
    } else if (i < 2880) {                     // conv2: (t, 3 ksteps, l)
        int q = i - 1152;
        int l = q & 63, s = (q >> 6) % 3, t = q / 192;
#pragma unroll
        for (int e = 0; e < 8; ++e) {
            int k = s * 16 + ((l >> 5) * 8) + e, o = l & 31;
            float w = 0.f;
            if (k < 36 && o < 8) w = wval(bw2, sw2, sc2, 36, (k / 9) * 9 + t, k % 9, o);
            ushort h, lo; bf16split(w, h, lo);
            k2h[q * 8 + e] = h; k2l[q * 8 + e] = lo;
        }
    } else if (i < 5760) {                     // conv3: (t, 5 ksteps, l)
        int q = i - 2880;
        int l = q & 63, s = (q >> 6) % 5, t = q / 320;
#pragma unroll
        for (int e = 0; e < 8; ++e) {
            int k = s * 16 + ((l >> 5) * 8) + e, o = l & 31;
            float w = 0.f;
            if (k < 72 && o < 16) w = wval(bw3, sw3, sc3, 72, (k / 9) * 9 + t, k % 9, o);
            ushort h, lo; bf16split(w, h, lo);
            k3h[q * 8 + e] = h; k3l[q * 8 + e] = lo;
        }
    } else if (i < 11520) {                    // conv4: (phase, t, 5 ksteps, l)
        int q = i - 5760;
        int l = q & 63, s = (q >> 6) % 5, t = (q / 320) % 9, p = q / 2880;
#pragma unroll
        for (int e = 0; e < 8; ++e) {
            int k = s * 16 + ((l >> 5) * 8) + e, o = l & 31;
            float w = 0.f;
            if (k < 72) w = wval(bw4, sw4, sc4, 144, (p * 8 + k / 9) * 9 + t, k % 9, o);
            ushort h, lo; bf16split(w, h, lo);
            k4h[q * 8 + e] = h; k4l[q * 8 + e] = lo;
        }
    } else if (i < 11600) {
        int c = i - 11520;
        ushort h, lo; bf16split(ZPAD[c % 9], h, lo);
        zph[c] = h; zpl[c] = lo;
    }
}

// ---------------------------------------------------------------------------
// Strip MFMA conv for 32x32 layers (conv1/conv2) — unchanged (verified).
// ---------------------------------------------------------------------------
template <int KG, int CHG, int CHL, int ASTR, int KSTEPS, int NCO, int EPI>
__global__ __launch_bounds__(256) void conv_strip(
    const ushort* __restrict__ Agh, const ushort* __restrict__ Agl,
    const ushort* __restrict__ Bgh, const ushort* __restrict__ Bgl,
    const ushort* __restrict__ zph, const ushort* __restrict__ zpl,
    ushort* __restrict__ Oh, ushort* __restrict__ Ol) {
    __shared__ ushort AH[340 * ASTR];
    __shared__ ushort AL[340 * ASTR];
    const int tid = threadIdx.x;
    const int b = blockIdx.x >> 2, strip = blockIdx.x & 3;
    const int r0 = strip * 8;
    const int lane = tid & 63, wv = tid >> 6;

    {
        const ushort* ash = Agh + (size_t)b * 1024 * KG;
        const ushort* asl = Agl + (size_t)b * 1024 * KG;
        for (int idx = tid; idx < 320 * CHL; idx += 256) {
            int pxl = idx / CHL, ch = idx - pxl * CHL;
            int lr = pxl >> 5, c = pxl & 31;
            int grow = r0 - 1 + lr;
            uint2 vh, vl;
            if (ch >= CHG) { vh = make_uint2(0u, 0u); vl = make_uint2(0u, 0u); }
            else if ((unsigned)grow < 32u) {
                vh = *(const uint2*)(ash + (size_t)(grow * 32 + c) * KG + ch * 4);
                vl = *(const uint2*)(asl + (size_t)(grow * 32 + c) * KG + ch * 4);
            } else {
                vh = *(const uint2*)(zph + ch * 4);
                vl = *(const uint2*)(zpl + ch * 4);
            }
            int spx = lr * 34 + c + 1;
            *(uint2*)(&AH[spx * ASTR + ch * 4]) = vh;
            *(uint2*)(&AL[spx * ASTR + ch * 4]) = vl;
        }
        for (int idx = tid; idx < 20 * CHL; idx += 256) {
            int sel = idx / CHL, ch = idx - sel * CHL;
            int lr = sel >> 1, c = (sel & 1) ? 33 : 0;
            int spx = lr * 34 + c;
            uint2 vh, vl;
            if (ch >= CHG) { vh = make_uint2(0u, 0u); vl = make_uint2(0u, 0u); }
            else { vh = *(const uint2*)(zph + ch * 4); vl = *(const uint2*)(zpl + ch * 4); }
            *(uint2*)(&AH[spx * ASTR + ch * 4]) = vh;
            *(uint2*)(&AL[spx * ASTR + ch * 4]) = vl;
        }
    }
    __syncthreads();

    f32x16 acc0, acc1;
#pragma unroll
    for (int i = 0; i < 16; ++i) { acc0[i] = 0.f; acc1[i] = 0.f; }

    const int p0 = wv * 64 + (lane & 31);
    const int sp0 = ((p0 >> 5) + 1) * 34 + (p0 & 31) + 1;
    const int sp1 = sp0 + 34;
    const int koff = (lane >> 5) * 8;

#pragma unroll 1
    for (int t = 0; t < 9; ++t) {
        const int dA = ((t / 3) - 1) * 34 + (t % 3) - 1;
#pragma unroll
        for (int s = 0; s < KSTEPS; ++s) {
            bf16x8 a0h = *(const bf16x8*)(&AH[(sp0 + dA) * ASTR + s * 16 + koff]);
            bf16x8 a0l = *(const bf16x8*)(&AL[(sp0 + dA) * ASTR + s * 16 + koff]);
            bf16x8 a1h = *(const bf16x8*)(&AH[(sp1 + dA) * ASTR + s * 16 + koff]);
            bf16x8 a1l = *(const bf16x8*)(&AL[(sp1 + dA) * ASTR + s * 16 + koff]);
            bf16x8 bh = *(const bf16x8*)(Bgh + (size_t)((t * KSTEPS + s) * 64 + lane) * 8);
            bf16x8 bl = *(const bf16x8*)(Bgl + (size_t)((t * KSTEPS + s) * 64 + lane) * 8);
            acc0 = __builtin_amdgcn_mfma_f32_32x32x16_bf16(a0h, bh, acc0, 0, 0, 0);
            acc1 = __builtin_amdgcn_mfma_f32_32x32x16_bf16(a1h, bh, acc1, 0, 0, 0);
            acc0 = __builtin_amdgcn_mfma_f32_32x32x16_bf16(a0h, bl, acc0, 0, 0, 0);
            acc1 = __builtin_amdgcn_mfma_f32_32x32x16_bf16(a1h, bl, acc1, 0, 0, 0);
            acc0 = __builtin_amdgcn_mfma_f32_32x32x16_bf16(a0l, bh, acc0, 0, 0, 0);
            acc1 = __builtin_amdgcn_mfma_f32_32x32x16_bf16(a1l, bh, acc1, 0, 0, 0);
        }
    }
    __syncthreads();

    float* fl = (float*)AH;
    {
        int ccol = lane & 31;
        if (ccol < NCO) {
#pragma unroll
            for (int r = 0; r < 16; ++r) {
                int row = (r & 3) + 8 * (r >> 2) + 4 * (lane >> 5);
                fl[ccol * 257 + wv * 64 + row] = acc0[r];
                fl[ccol * 257 + wv * 64 + 32 + row] = acc1[r];
            }
        }
    }
    __syncthreads();

    if (EPI == 0) {
        unsigned* ubh = (unsigned*)AL;
        unsigned* ubl = (unsigned*)AH + 1032;
        unsigned rwh[18], rwl[18];
#pragma unroll
        for (int w = 0; w < 18; ++w) { rwh[w] = 0u; rwl[w] = 0u; }
#pragma unroll
        for (int co = 0; co < 4; ++co) {
            float a9[9];
            spline_acts(fl[co * 257 + tid], a9);
#pragma unroll
            for (int j = 0; j < 9; ++j) {
                ushort h, l2; bf16split(a9[j], h, l2);
                int c = co * 9 + j;
                if (c & 1) { rwh[c >> 1] |= (unsigned)h << 16; rwl[c >> 1] |= (unsigned)l2 << 16; }
                else       { rwh[c >> 1] |= h;                  rwl[c >> 1] |= l2; }
            }
        }
#pragma unroll
        for (int w = 0; w < 18; ++w) { ubh[tid * 18 + w] = rwh[w]; ubl[tid * 18 + w] = rwl[w]; }
        __syncthreads();
        size_t basew = ((size_t)b * 1024 + strip * 256) * 18;
        unsigned* goh = (unsigned*)Oh + basew;
        unsigned* gol = (unsigned*)Ol + basew;
#pragma unroll
        for (int e = 0; e < 18; ++e) {
            int q = e * 256 + tid;
            goh[q] = ubh[q];
            gol[q] = ubl[q];
        }
    } else {
        int cg = tid >> 6, pl = tid & 63;
        int phl = pl >> 4, pw = pl & 15;
        int base_m = (2 * phl) * 32 + 2 * pw;
        unsigned rwh[9], rwl[9];
#pragma unroll
        for (int w = 0; w < 9; ++w) { rwh[w] = 0u; rwl[w] = 0u; }
#pragma unroll
        for (int e = 0; e < 2; ++e) {
            int co = cg * 2 + e;
            const float* fb = fl + co * 257 + base_m;
            float m = fmaxf(fmaxf(fb[0], fb[1]), fmaxf(fb[32], fb[33]));
            float a9[9];
            spline_acts(m, a9);
#pragma unroll
            for (int j = 0; j < 9; ++j) {
                ushort h, l2; bf16split(a9[j], h, l2);
                int c = e * 9 + j;
                if (c & 1) { rwh[c >> 1] |= (unsigned)h << 16; rwl[c >> 1] |= (unsigned)l2 << 16; }
                else       { rwh[c >> 1] |= h;                  rwl[c >> 1] |= l2; }
            }
        }
        unsigned* ubh = (unsigned*)AL;
        unsigned* ubl = (unsigned*)AL + 2560;
#pragma unroll
        for (int w = 0; w < 9; ++w) {
            ubh[pl * 40 + cg * 9 + w] = rwh[w];
            ubl[pl * 40 + cg * 9 + w] = rwl[w];
        }
        if (cg == 3) {
#pragma unroll
            for (int w = 0; w < 4; ++w) { ubh[pl * 40 + 36 + w] = 0u; ubl[pl * 40 + 36 + w] = 0u; }
        }
        __syncthreads();
        size_t base = ((size_t)b * 256 + strip * 64) * 80;
        const ushort* sbh = (const ushort*)ubh;
        const ushort* sbl = (const ushort*)ubl;
#pragma unroll
        for (int e = 0; e < 3; ++e) {
            int q = e * 256 + tid;
            if (q < 640) {
                *(uint4*)(Oh + base + q * 8) = *(const uint4*)(sbh + q * 8);
                *(uint4*)(Ol + base + q * 8) = *(const uint4*)(sbl + q * 8);
            }
        }
    }
}

// ---------------------------------------------------------------------------
// conv34_part: split-K MFMA partial, z = dh-group (3); cin-phases looped
// inside with accumulation. Writes P[g][b*2+half][px 0..127][NCO].
// ---------------------------------------------------------------------------
template <int NPH, int NCO>
__global__ __launch_bounds__(256) void conv34_part(
    const ushort* __restrict__ Agh, const ushort* __restrict__ Agl,
    const ushort* __restrict__ Bgh, const ushort* __restrict__ Bgl,
    const ushort* __restrict__ zph, const ushort* __restrict__ zpl,
    float* __restrict__ P) {
    __shared__ ushort AH[144 * AST];
    __shared__ ushort AL[144 * AST];
    const int tid = threadIdx.x;
    const int b = blockIdx.x, half = blockIdx.y, g = blockIdx.z;
    const int r0 = half * 8;
    const int lane = tid & 63, wv = tid >> 6;

    f32x16 acc;
#pragma unroll
    for (int i = 0; i < 16; ++i) acc[i] = 0.f;

    const int m = wv * 32 + (lane & 31);
    const int sbase = (m >> 4) * 18 + (m & 15);
    const int koff = (lane >> 5) * 8;

#pragma unroll 1
    for (int p = 0; p < NPH; ++p) {
        if (p) __syncthreads();
        const ushort* ash = Agh + ((size_t)b * NPH + p) * 256 * 80;
        const ushort* asl = Agl + ((size_t)b * NPH + p) * 256 * 80;
#pragma unroll
        for (int e = 0; e < 6; ++e) {
            int idx = e * 256 + tid;
            if (idx < 1440) {
                int px = idx / 10, ch = idx - px * 10;
                int pr = px / 18, pc = px - pr * 18;
                int r = r0 - 1 + g + pr, c = pc - 1;
                bool inb = ((unsigned)r < 16u) && ((unsigned)c < 16u);
                uint4 vh, vl;
                if (inb) {
                    vh = *(const uint4*)(ash + (size_t)(r * 16 + c) * 80 + ch * 8);
                    vl = *(const uint4*)(asl + (size_t)(r * 16 + c) * 80 + ch * 8);
                } else {
                    vh = *(const uint4*)(zph + ch * 8);
                    vl = *(const uint4*)(zpl + ch * 8);
                }
                *(uint4*)(&AH[px * AST + ch * 8]) = vh;
                *(uint4*)(&AL[px * AST + ch * 8]) = vl;
            }
        }
        __syncthreads();

        const ushort* bsh = Bgh + (size_t)p * 2880 * 8;
        const ushort* bsl = Bgl + (size_t)p * 2880 * 8;
#pragma unroll
        for (int dw = 0; dw < 3; ++dw) {
            const int t = g * 3 + dw;
#pragma unroll
            for (int s = 0; s < 5; ++s) {
                bf16x8 ah = *(const bf16x8*)(&AH[(sbase + dw) * AST + s * 16 + koff]);
                bf16x8 al = *(const bf16x8*)(&AL[(sbase + dw) * AST + s * 16 + koff]);
                bf16x8 bh = *(const bf16x8*)(bsh + (size_t)((t * 5 + s) * 64 + lane) * 8);
                bf16x8 bl = *(const bf16x8*)(bsl + (size_t)((t * 5 + s) * 64 + lane) * 8);
                acc = __builtin_amdgcn_mfma_f32_32x32x16_bf16(ah, bh, acc, 0, 0, 0);
                acc = __builtin_amdgcn_mfma_f32_32x32x16_bf16(ah, bl, acc, 0, 0, 0);
                acc = __builtin_amdgcn_mfma_f32_32x32x16_bf16(al, bh, acc, 0, 0, 0);
            }
        }
    }

    int co = lane & 31;
    if (co < NCO) {
        float* pb = P + ((size_t)(g * 256 + b * 2 + half) * 128) * NCO;
#pragma unroll
        for (int r = 0; r < 16; ++r) {
            int px = wv * 32 + (r & 3) + 8 * (r >> 2) + 4 * (lane >> 5);
            pb[px * NCO + co] = acc[r];
        }
    }
}

// ---------------------------------------------------------------------------
// conv3_reduce: sum 3 partials + spline -> A4 (B,2,256,80) bf16 hi/lo.
// ---------------------------------------------------------------------------
__global__ __launch_bounds__(256) void conv3_reduce(const float* __restrict__ P3,
                                                    ushort* __restrict__ A4h,
                                                    ushort* __restrict__ A4l) {
    __shared__ ushort SBH[20480], SBL[20480];  // 256 px x 80 ushorts
    int b = blockIdx.x, p2 = blockIdx.y;
    int t = threadIdx.x;
    int co8 = t & 7, pxg = t >> 3;
    int co = p2 * 8 + co8;

#pragma unroll
    for (int q = 0; q < 8; ++q) {
        int px = pxg * 8 + q;
        int bh = b * 2 + (px >> 7), lpx = px & 127;
        float s = 0.f;
#pragma unroll
        for (int zz = 0; zz < 3; ++zz)
            s += P3[((size_t)(zz * 256 + bh) * 128 + lpx) * 16 + co];
        float a9[9];
        spline_acts(s, a9);
#pragma unroll
        for (int j = 0; j < 9; ++j) {
            ushort h, l2; bf16split(a9[j], h, l2);
            SBH[px * 80 + co8 * 9 + j] = h;
            SBL[px * 80 + co8 * 9 + j] = l2;
        }
        if (co8 == 7) {
#pragma unroll
            for (int w = 0; w < 8; ++w) { SBH[px * 80 + 72 + w] = 0; SBL[px * 80 + 72 + w] = 0; }
        }
    }
    __syncthreads();
    size_t base = ((size_t)(b * 2 + p2) * 256) * 80;
#pragma unroll
    for (int e = 0; e < 10; ++e) {
        int q = e * 256 + t;
        *(uint4*)(A4h + base + q * 8) = *(const uint4*)(SBH + q * 8);
        *(uint4*)(A4l + base + q * 8) = *(const uint4*)(SBL + q * 8);
    }
}

// ---------------------------------------------------------------------------
// conv4_reduce_pool: sum 3 partials + 2x2 maxpool -> pooled (B,2048) fp32.
// ---------------------------------------------------------------------------
__global__ __launch_bounds__(256) void conv4_reduce_pool(const float* __restrict__ P4,
                                                         float* __restrict__ pooled) {
    __shared__ float SM[32 * 65];
    int b = blockIdx.x;
    int t = threadIdx.x;
    int co = t & 31, pg = t >> 5;
#pragma unroll
    for (int q = 0; q < 8; ++q) {
        int pp = pg * 8 + q;
        int pr = pp >> 3, pc = pp & 7;
        int half = pr >> 2, lr = pr & 3;
        int bh = b * 2 + half;
        int px00 = (2 * lr) * 16 + 2 * pc;
        float s00 = 0.f, s01 = 0.f, s10 = 0.f, s11 = 0.f;
#pragma unroll
        for (int zz = 0; zz < 3; ++zz) {
            const float* pb = P4 + ((size_t)(zz * 256 + bh) * 128) * 32 + co;
            s00 += pb[(size_t)px00 * 32];
            s01 += pb[(size_t)(px00 + 1) * 32];
            s10 += pb[(size_t)(px00 + 16) * 32];
            s11 += pb[(size_t)(px00 + 17) * 32];
        }
        SM[co * 65 + pp] = fmaxf(fmaxf(s00, s01), fmaxf(s10, s11));
    }
    __syncthreads();
#pragma unroll
    for (int e = 0; e < 8; ++e) {
        int idx = e * 256 + t;
        pooled[(size_t)b * 2048 + idx] = SM[(idx >> 6) * 65 + (idx & 63)];
    }
}

// ---------------------------------------------------------------------------
// fc_big: 64x64 tile, 4x4/thread, K_TILE=32, split-K; float4 global staging.
// ---------------------------------------------------------------------------
template <int SPLIT>
__global__ __launch_bounds__(256) void fc_big(const float* __restrict__ A,
                                              const float* __restrict__ Wt,
                                              float* __restrict__ part,
                                              int M, int N, int K) {
    __shared__ float As[32][68];
    __shared__ float Ws[32][68];
    const int tid = threadIdx.x;
    const int tx = tid & 15, ty = tid >> 4;
    const int bm = blockIdx.y * 64, bn = blockIdx.x * 64;
    const int kc = K / SPLIT;
    const int kbeg = blockIdx.z * kc;
    float acc[4][4] = {};
    for (int k0 = kbeg; k0 < kbeg + kc; k0 += 32) {
#pragma unroll
        for (int e = 0; e < 2; ++e) {
            int q = e * 256 + tid;           // 512 float4 = 64 rows x 8
            int r = q >> 3, k4 = (q & 7) * 4;
            float4 av = *(const float4*)&A[(size_t)(bm + r) * K + k0 + k4];
            float4 wv = *(const float4*)&Wt[(size_t)(bn + r) * K + k0 + k4];
            As[k4 + 0][r] = av.x; As[k4 + 1][r] = av.y;
            As[k4 + 2][r] = av.z; As[k4 + 3][r] = av.w;
            Ws[k4 + 0][r] = wv.x; Ws[k4 + 1][r] = wv.y;
            Ws[k4 + 2][r] = wv.z; Ws[k4 + 3][r] = wv.w;
        }
        __syncthreads();
#pragma unroll
        for (int kk = 0; kk < 32; ++kk) {
            float4 av = *(const float4*)(&As[kk][ty * 4]);
            float4 wv = *(const float4*)(&Ws[kk][tx * 4]);
            acc[0][0] = fmaf(av.x, wv.x, acc[0][0]);
            acc[0][1] = fmaf(av.x, wv.y, acc[0][1]);
            acc[0][2] = fmaf(av.x, wv.z, acc[0][2]);
            acc[0][3] = fmaf(av.x, wv.w, acc[0][3]);
            acc[1][0] = fmaf(av.y, wv.x, acc[1][0]);
            acc[1][1] = fmaf(av.y, wv.y, acc[1][1]);
            acc[1][2] = fmaf(av.y, wv.z, acc[1][2]);
            acc[1][3] = fmaf(av.y, wv.w, acc[1][3]);
            acc[2][0] = fmaf(av.z, wv.x, acc[2][0]);
            acc[2][1] = fmaf(av.z, wv.y, acc[2][1]);
            acc[2][2] = fmaf(av.z, wv.z, acc[2][2]);
            acc[2][3] = fmaf(av.z, wv.w, acc[2][3]);
            acc[3][0] = fmaf(av.w, wv.x, acc[3][0]);
            acc[3][1] = fmaf(av.w, wv.y, acc[3][1]);
            acc[3][2] = fmaf(av.w, wv.z, acc[3][2]);
            acc[3][3] = fmaf(av.w, wv.w, acc[3][3]);
        }
        __syncthreads();
    }
    float* p = part + (size_t)blockIdx.z * M * N;
#pragma unroll
    for (int i = 0; i < 4; ++i) {
        float4 v = make_float4(acc[i][0], acc[i][1], acc[i][2], acc[i][3]);
        *(float4*)&p[(size_t)(bm + ty * 4 + i) * N + (bn + tx * 4)] = v;
    }
}

template <int SPLIT>
__global__ void fc_reduce(const float* __restrict__ part, const float* __restrict__ bias,
                          float* __restrict__ C, int MN, int N, int relu) {
    int i = blockIdx.x * 256 + threadIdx.x;
    if (i >= MN) return;
    float s = bias[i % N];
#pragma unroll
    for (int z = 0; z < SPLIT; ++z) s += part[(size_t)z * MN + i];
    C[i] = relu ? fmaxf(s, 0.f) : s;
}

__global__ __launch_bounds__(256) void fc3_kernel(const float* __restrict__ A,
                                                  const float* __restrict__ Wt,
                                                  const float* __restrict__ bias,
                                                  float* __restrict__ C) {
    int gid = blockIdx.x * 256 + threadIdx.x;
    int wid = gid >> 6;
    int lane = gid & 63;
    int m = wid / 10, n = wid - m * 10;
    const float4* a = (const float4*)(A + (size_t)m * 1024);
    const float4* w = (const float4*)(Wt + (size_t)n * 1024);
    float s = 0.f;
#pragma unroll
    for (int it = 0; it < 4; ++it) {
        float4 av = a[it * 64 + lane];
        float4 wv = w[it * 64 + lane];
        s += av.x * wv.x + av.y * wv.y + av.z * wv.z + av.w * wv.w;
    }
#pragma unroll
    for (int off = 32; off; off >>= 1) s += __shfl_xor(s, off);
    if (lane == 0) C[wid] = s + bias[n];
}

// ---------------------------------------------------------------------------
extern "C" void kernel_launch(void* const* d_in, const int* in_sizes, int n_in,
                              void* d_out, int out_size, void* d_ws, size_t ws_size,
                              hipStream_t stream) {
    const float* x   = (const float*)d_in[0];
    const float* bw1 = (const float*)d_in[1];
    const float* sw1 = (const float*)d_in[2];
    const float* sc1 = (const float*)d_in[3];
    const float* bw2 = (const float*)d_in[4];
    const float* sw2 = (const float*)d_in[5];
    const float* sc2 = (const float*)d_in[6];
    const float* bw3 = (const float*)d_in[7];
    const float* sw3 = (const float*)d_in[8];
    const float* sc3 = (const float*)d_in[9];
    const float* bw4 = (const float*)d_in[10];
    const float* sw4 = (const float*)d_in[11];
    const float* sc4 = (const float*)d_in[12];
    const float* w1  = (const float*)d_in[13];
    const float* b1  = (const float*)d_in[14];
    const float* w2  = (const float*)d_in[15];
    const float* b2  = (const float*)d_in[16];
    const float* w3  = (const float*)d_in[17];
    const float* b3  = (const float*)d_in[18];

    float*  wsf = (float*)d_ws;
    ushort* wsu = (ushort*)d_ws;
    ushort* k1h = wsu + 110848;
    ushort* k1l = wsu + 120064;
    ushort* k2h = wsu + 129280;
    ushort* k2l = wsu + 143104;
    ushort* k3h = wsu + 156928;
    ushort* k3l = wsu + 179968;
    ushort* k4h = wsu + 203008;
    ushort* k4l = wsu + 249088;
    ushort* zph = wsu + 295168;
    ushort* zpl = wsu + 295248;
    ushort* A1h = wsu + 524288;
    ushort* A1l = wsu + 4194304;
    ushort* A2h = wsu + 7864320;
    ushort* A2l = wsu + 12582912;
    ushort* A3h = wsu + 524288;
    ushort* A3l = wsu + 3145728;
    ushort* A4h = wsu + 5767168;
    ushort* A4l = wsu + 11010048;
    float* P3   = wsf + 9437184;    // 3x256x128x16 fp32 = 6.3MB
    float* P4   = wsf + 11534336;   // 3x256x128x32 fp32 = 12.6MB
    float* pooled = wsf + 262144;
    float* part1  = wsf + 524288;
    float* fc1o   = wsf + 2621440;
    float* part2  = wsf + 2883584;
    float* fc2o   = wsf + 3932160;

    // prep: blocks 0..45 = B-frag packing, 46..557 = spline of x
    prep_kernel<<<558, 256, 0, stream>>>(x, bw1, sw1, sc1, bw2, sw2, sc2,
                                         bw3, sw3, sc3, bw4, sw4, sc4,
                                         k1h, k1l, k2h, k2l, k3h, k3l, k4h, k4l,
                                         zph, zpl, A1h, A1l);

    conv_strip<28, 7, 8, 40, 2, 4, 0><<<512, 256, 0, stream>>>(A1h, A1l, k1h, k1l,
                                                               zph, zpl, A2h, A2l);
    conv_strip<36, 9, 12, 56, 3, 8, 1><<<512, 256, 0, stream>>>(A2h, A2l, k2h, k2l,
                                                                zph, zpl, A3h, A3l);
    conv34_part<1, 16><<<dim3(128, 2, 3), 256, 0, stream>>>(A3h, A3l, k3h, k3l,
                                                            zph, zpl, P3);
    conv3_reduce<<<dim3(128, 2), 256, 0, stream>>>(P3, A4h, A4l);
    conv34_part<2, 32><<<dim3(128, 2, 3), 256, 0, stream>>>(A4h, A4l, k4h, k4l,
                                                            zph, zpl, P4);
    conv4_reduce_pool<<<128, 256, 0, stream>>>(P4, pooled);

    fc_big<8><<<dim3(32, 2, 8), 256, 0, stream>>>(pooled, w1, part1, 128, 2048, 2048);
    fc_reduce<8><<<1024, 256, 0, stream>>>(part1, b1, fc1o, 262144, 2048, 1);
    fc_big<8><<<dim3(16, 2, 8), 256, 0, stream>>>(fc1o, w2, part2, 128, 1024, 2048);
    fc_reduce<8><<<512, 256, 0, stream>>>(part2, b2, fc2o, 131072, 1024, 1);
    fc3_kernel<<<320, 256, 0, stream>>>(fc2o, w3, b3, (float*)d_out);
}

// Round 14
// 136.814 us; speedup vs baseline: 1.3063x; 1.0322x over previous
//
#include <hip/hip_runtime.h>

#define BATCH 128
#define AST 88  // padded-A LDS row stride in ushorts (176B, 16B-aligned)

typedef __attribute__((ext_vector_type(8))) short bf16x8;
typedef __attribute__((ext_vector_type(16))) float f32x16;

// ---------------------------------------------------------------------------
// Spline activation: act[0] = silu(x), act[1..8] = cubic B-spline bases
// ---------------------------------------------------------------------------
__device__ __forceinline__ void spline_acts(float xv, float act[9]) {
    act[0] = xv * (1.0f / (1.0f + __expf(-xv)));  // silu
    float g[12];
#pragma unroll
    for (int i = 0; i < 12; ++i) g[i] = (float)(i - 3) * 0.4f - 1.0f;
    float bb[11];
#pragma unroll
    for (int c = 0; c < 11; ++c) bb[c] = (xv >= g[c] && xv < g[c + 1]) ? 1.0f : 0.0f;
#pragma unroll
    for (int k = 1; k <= 3; ++k) {
#pragma unroll
        for (int c = 0; c + k < 11; ++c) {
            float left  = (xv - g[c]) * (1.0f / (g[c + k] - g[c])) * bb[c];
            float right = (g[c + k + 1] - xv) * (1.0f / (g[c + k + 1] - g[c + 1])) * bb[c + 1];
            bb[c] = left + right;
        }
    }
#pragma unroll
    for (int c = 0; c < 8; ++c) act[c + 1] = bb[c];
}

__device__ __constant__ float ZPAD[9] = {0.0f, 0.0f, 0.0f, 0.02083333333f,
                                         0.47916666667f, 0.47916666667f,
                                         0.02083333333f, 0.0f, 0.0f};

// bf16 hi/lo split (round-to-nearest-even); x = hi + lo + O(2^-18 x)
__device__ __forceinline__ void bf16split(float x, ushort& h, ushort& l) {
    union { float f; unsigned u; } a; a.f = x;
    unsigned r = a.u + 0x7FFF + ((a.u >> 16) & 1);
    h = (ushort)(r >> 16);
    union { unsigned u; float f; } hf; hf.u = (unsigned)h << 16;
    union { float f; unsigned u; } bres; bres.f = x - hf.f;
    unsigned r2 = bres.u + 0x7FFF + ((bres.u >> 16) & 1);
    l = (ushort)(r2 >> 16);
}

// packed conv weight value: f = cin*9 + tap, j = spline idx
__device__ __forceinline__ float wval(const float* bw, const float* sw, const float* sc,
                                      int F, int f, int j, int o) {
    if (j == 0) return bw[o * F + f];
    return sw[(o * F + f) * 8 + (j - 1)] * sc[o * F + f];
}

// ---------------------------------------------------------------------------
// prep: blocks 0..45 pack MFMA B-fragments; blocks 46..557 do spline_x.
// ---------------------------------------------------------------------------
__global__ __launch_bounds__(256) void prep_kernel(
    const float* __restrict__ x,
    const float* __restrict__ bw1, const float* __restrict__ sw1, const float* __restrict__ sc1,
    const float* __restrict__ bw2, const float* __restrict__ sw2, const float* __restrict__ sc2,
    const float* __restrict__ bw3, const float* __restrict__ sw3, const float* __restrict__ sc3,
    const float* __restrict__ bw4, const float* __restrict__ sw4, const float* __restrict__ sc4,
    ushort* __restrict__ k1h, ushort* __restrict__ k1l,
    ushort* __restrict__ k2h, ushort* __restrict__ k2l,
    ushort* __restrict__ k3h, ushort* __restrict__ k3l,
    ushort* __restrict__ k4h, ushort* __restrict__ k4l,
    ushort* __restrict__ zph, ushort* __restrict__ zpl,
    ushort* __restrict__ A1h, ushort* __restrict__ A1l) {
    __shared__ unsigned SB[7168];
    if (blockIdx.x >= 46) {
        int bid = blockIdx.x - 46;
        int i = bid * 256 + threadIdx.x;
        int px = i & 1023, b = i >> 10;
        const float* xb = x + (size_t)b * 3072 + px;
        unsigned rh[14] = {}, rl[14] = {};
#pragma unroll
        for (int cin = 0; cin < 3; ++cin) {
            float a9[9];
            spline_acts(xb[cin * 1024], a9);
#pragma unroll
            for (int j = 0; j < 9; ++j) {
                ushort h, l2; bf16split(a9[j], h, l2);
                int c = cin * 9 + j;
                if (c & 1) { rh[c >> 1] |= (unsigned)h << 16; rl[c >> 1] |= (unsigned)l2 << 16; }
                else       { rh[c >> 1] |= h;                  rl[c >> 1] |= l2; }
            }
        }
        int wb = threadIdx.x * 14;
#pragma unroll
        for (int w = 0; w < 14; ++w) { SB[wb + w] = rh[w]; SB[3584 + wb + w] = rl[w]; }
        __syncthreads();
        const ushort* sb = (const ushort*)SB;
        size_t base = (size_t)bid * 7168;
#pragma unroll
        for (int e = 0; e < 4; ++e) {
            int q = e * 256 + threadIdx.x;
            if (q < 896) {
                *(uint4*)(A1h + base + q * 8) = *(const uint4*)(sb + q * 8);
                *(uint4*)(A1l + base + q * 8) = *(const uint4*)(sb + 7168 + q * 8);
            }
        }
        return;
    }
    int i = blockIdx.x * 256 + threadIdx.x;
    if (i < 1152) {                            // conv1
        int l = i & 63, s = (i >> 6) & 1, t = i / 128;
#pragma unroll
        for (int e = 0; e < 8; ++e) {
            int k = s * 16 + ((l >> 5) * 8) + e, o = l & 31;
            float w = 0.f;
            if (k < 27 && o < 4) w = wval(bw1, sw1, sc1, 27, (k / 9) * 9 + t, k % 9, o);
            ushort h, lo; bf16split(w, h, lo);
            k1h[i * 8 + e] = h; k1l[i * 8 + e] = lo;
        }
    } else if (i < 2880) {                     // conv2
        int q = i - 1152;
        int l = q & 63, s = (q >> 6) % 3, t = q / 192;
#pragma unroll
        for (int e = 0; e < 8; ++e) {
            int k = s * 16 + ((l >> 5) * 8) + e, o = l & 31;
            float w = 0.f;
            if (k < 36 && o < 8) w = wval(bw2, sw2, sc2, 36, (k / 9) * 9 + t, k % 9, o);
            ushort h, lo; bf16split(w, h, lo);
            k2h[q * 8 + e] = h; k2l[q * 8 + e] = lo;
        }
    } else if (i < 5760) {                     // conv3
        int q = i - 2880;
        int l = q & 63, s = (q >> 6) % 5, t = q / 320;
#pragma unroll
        for (int e = 0; e < 8; ++e) {
            int k = s * 16 + ((l >> 5) * 8) + e, o = l & 31;
            float w = 0.f;
            if (k < 72 && o < 16) w = wval(bw3, sw3, sc3, 72, (k / 9) * 9 + t, k % 9, o);
            ushort h, lo; bf16split(w, h, lo);
            k3h[q * 8 + e] = h; k3l[q * 8 + e] = lo;
        }
    } else if (i < 11520) {                    // conv4
        int q = i - 5760;
        int l = q & 63, s = (q >> 6) % 5, t = (q / 320) % 9, p = q / 2880;
#pragma unroll
        for (int e = 0; e < 8; ++e) {
            int k = s * 16 + ((l >> 5) * 8) + e, o = l & 31;
            float w = 0.f;
            if (k < 72) w = wval(bw4, sw4, sc4, 144, (p * 8 + k / 9) * 9 + t, k % 9, o);
            ushort h, lo; bf16split(w, h, lo);
            k4h[q * 8 + e] = h; k4l[q * 8 + e] = lo;
        }
    } else if (i < 11600) {
        int c = i - 11520;
        ushort h, lo; bf16split(ZPAD[c % 9], h, lo);
        zph[c] = h; zpl[c] = lo;
    }
}

// ---------------------------------------------------------------------------
// Strip MFMA conv for 32x32 layers (conv1/conv2) — unchanged (verified).
// ---------------------------------------------------------------------------
template <int KG, int CHG, int CHL, int ASTR, int KSTEPS, int NCO, int EPI>
__global__ __launch_bounds__(256) void conv_strip(
    const ushort* __restrict__ Agh, const ushort* __restrict__ Agl,
    const ushort* __restrict__ Bgh, const ushort* __restrict__ Bgl,
    const ushort* __restrict__ zph, const ushort* __restrict__ zpl,
    ushort* __restrict__ Oh, ushort* __restrict__ Ol) {
    __shared__ ushort AH[340 * ASTR];
    __shared__ ushort AL[340 * ASTR];
    const int tid = threadIdx.x;
    const int b = blockIdx.x >> 2, strip = blockIdx.x & 3;
    const int r0 = strip * 8;
    const int lane = tid & 63, wv = tid >> 6;

    {
        const ushort* ash = Agh + (size_t)b * 1024 * KG;
        const ushort* asl = Agl + (size_t)b * 1024 * KG;
        for (int idx = tid; idx < 320 * CHL; idx += 256) {
            int pxl = idx / CHL, ch = idx - pxl * CHL;
            int lr = pxl >> 5, c = pxl & 31;
            int grow = r0 - 1 + lr;
            uint2 vh, vl;
            if (ch >= CHG) { vh = make_uint2(0u, 0u); vl = make_uint2(0u, 0u); }
            else if ((unsigned)grow < 32u) {
                vh = *(const uint2*)(ash + (size_t)(grow * 32 + c) * KG + ch * 4);
                vl = *(const uint2*)(asl + (size_t)(grow * 32 + c) * KG + ch * 4);
            } else {
                vh = *(const uint2*)(zph + ch * 4);
                vl = *(const uint2*)(zpl + ch * 4);
            }
            int spx = lr * 34 + c + 1;
            *(uint2*)(&AH[spx * ASTR + ch * 4]) = vh;
            *(uint2*)(&AL[spx * ASTR + ch * 4]) = vl;
        }
        for (int idx = tid; idx < 20 * CHL; idx += 256) {
            int sel = idx / CHL, ch = idx - sel * CHL;
            int lr = sel >> 1, c = (sel & 1) ? 33 : 0;
            int spx = lr * 34 + c;
            uint2 vh, vl;
            if (ch >= CHG) { vh = make_uint2(0u, 0u); vl = make_uint2(0u, 0u); }
            else { vh = *(const uint2*)(zph + ch * 4); vl = *(const uint2*)(zpl + ch * 4); }
            *(uint2*)(&AH[spx * ASTR + ch * 4]) = vh;
            *(uint2*)(&AL[spx * ASTR + ch * 4]) = vl;
        }
    }
    __syncthreads();

    f32x16 acc0, acc1;
#pragma unroll
    for (int i = 0; i < 16; ++i) { acc0[i] = 0.f; acc1[i] = 0.f; }

    const int p0 = wv * 64 + (lane & 31);
    const int sp0 = ((p0 >> 5) + 1) * 34 + (p0 & 31) + 1;
    const int sp1 = sp0 + 34;
    const int koff = (lane >> 5) * 8;

#pragma unroll 1
    for (int t = 0; t < 9; ++t) {
        const int dA = ((t / 3) - 1) * 34 + (t % 3) - 1;
#pragma unroll
        for (int s = 0; s < KSTEPS; ++s) {
            bf16x8 a0h = *(const bf16x8*)(&AH[(sp0 + dA) * ASTR + s * 16 + koff]);
            bf16x8 a0l = *(const bf16x8*)(&AL[(sp0 + dA) * ASTR + s * 16 + koff]);
            bf16x8 a1h = *(const bf16x8*)(&AH[(sp1 + dA) * ASTR + s * 16 + koff]);
            bf16x8 a1l = *(const bf16x8*)(&AL[(sp1 + dA) * ASTR + s * 16 + koff]);
            bf16x8 bh = *(const bf16x8*)(Bgh + (size_t)((t * KSTEPS + s) * 64 + lane) * 8);
            bf16x8 bl = *(const bf16x8*)(Bgl + (size_t)((t * KSTEPS + s) * 64 + lane) * 8);
            acc0 = __builtin_amdgcn_mfma_f32_32x32x16_bf16(a0h, bh, acc0, 0, 0, 0);
            acc1 = __builtin_amdgcn_mfma_f32_32x32x16_bf16(a1h, bh, acc1, 0, 0, 0);
            acc0 = __builtin_amdgcn_mfma_f32_32x32x16_bf16(a0h, bl, acc0, 0, 0, 0);
            acc1 = __builtin_amdgcn_mfma_f32_32x32x16_bf16(a1h, bl, acc1, 0, 0, 0);
            acc0 = __builtin_amdgcn_mfma_f32_32x32x16_bf16(a0l, bh, acc0, 0, 0, 0);
            acc1 = __builtin_amdgcn_mfma_f32_32x32x16_bf16(a1l, bh, acc1, 0, 0, 0);
        }
    }
    __syncthreads();

    float* fl = (float*)AH;
    {
        int ccol = lane & 31;
        if (ccol < NCO) {
#pragma unroll
            for (int r = 0; r < 16; ++r) {
                int row = (r & 3) + 8 * (r >> 2) + 4 * (lane >> 5);
                fl[ccol * 257 + wv * 64 + row] = acc0[r];
                fl[ccol * 257 + wv * 64 + 32 + row] = acc1[r];
            }
        }
    }
    __syncthreads();

    if (EPI == 0) {
        unsigned* ubh = (unsigned*)AL;
        unsigned* ubl = (unsigned*)AH + 1032;
        unsigned rwh[18], rwl[18];
#pragma unroll
        for (int w = 0; w < 18; ++w) { rwh[w] = 0u; rwl[w] = 0u; }
#pragma unroll
        for (int co = 0; co < 4; ++co) {
            float a9[9];
            spline_acts(fl[co * 257 + tid], a9);
#pragma unroll
            for (int j = 0; j < 9; ++j) {
                ushort h, l2; bf16split(a9[j], h, l2);
                int c = co * 9 + j;
                if (c & 1) { rwh[c >> 1] |= (unsigned)h << 16; rwl[c >> 1] |= (unsigned)l2 << 16; }
                else       { rwh[c >> 1] |= h;                  rwl[c >> 1] |= l2; }
            }
        }
#pragma unroll
        for (int w = 0; w < 18; ++w) { ubh[tid * 18 + w] = rwh[w]; ubl[tid * 18 + w] = rwl[w]; }
        __syncthreads();
        size_t basew = ((size_t)b * 1024 + strip * 256) * 18;
        unsigned* goh = (unsigned*)Oh + basew;
        unsigned* gol = (unsigned*)Ol + basew;
#pragma unroll
        for (int e = 0; e < 18; ++e) {
            int q = e * 256 + tid;
            goh[q] = ubh[q];
            gol[q] = ubl[q];
        }
    } else {
        int cg = tid >> 6, pl = tid & 63;
        int phl = pl >> 4, pw = pl & 15;
        int base_m = (2 * phl) * 32 + 2 * pw;
        unsigned rwh[9], rwl[9];
#pragma unroll
        for (int w = 0; w < 9; ++w) { rwh[w] = 0u; rwl[w] = 0u; }
#pragma unroll
        for (int e = 0; e < 2; ++e) {
            int co = cg * 2 + e;
            const float* fb = fl + co * 257 + base_m;
            float m = fmaxf(fmaxf(fb[0], fb[1]), fmaxf(fb[32], fb[33]));
            float a9[9];
            spline_acts(m, a9);
#pragma unroll
            for (int j = 0; j < 9; ++j) {
                ushort h, l2; bf16split(a9[j], h, l2);
                int c = e * 9 + j;
                if (c & 1) { rwh[c >> 1] |= (unsigned)h << 16; rwl[c >> 1] |= (unsigned)l2 << 16; }
                else       { rwh[c >> 1] |= h;                  rwl[c >> 1] |= l2; }
            }
        }
        unsigned* ubh = (unsigned*)AL;
        unsigned* ubl = (unsigned*)AL + 2560;
#pragma unroll
        for (int w = 0; w < 9; ++w) {
            ubh[pl * 40 + cg * 9 + w] = rwh[w];
            ubl[pl * 40 + cg * 9 + w] = rwl[w];
        }
        if (cg == 3) {
#pragma unroll
            for (int w = 0; w < 4; ++w) { ubh[pl * 40 + 36 + w] = 0u; ubl[pl * 40 + 36 + w] = 0u; }
        }
        __syncthreads();
        size_t base = ((size_t)b * 256 + strip * 64) * 80;
        const ushort* sbh = (const ushort*)ubh;
        const ushort* sbl = (const ushort*)ubl;
#pragma unroll
        for (int e = 0; e < 3; ++e) {
            int q = e * 256 + tid;
            if (q < 640) {
                *(uint4*)(Oh + base + q * 8) = *(const uint4*)(sbh + q * 8);
                *(uint4*)(Ol + base + q * 8) = *(const uint4*)(sbl + q * 8);
            }
        }
    }
}

// ---------------------------------------------------------------------------
// conv34_part: split-K MFMA partial, z = dh-group (3); cin-phases looped.
// Writes P[g][b*2+half][px 0..127][NCO] (co-fast, coalesced). Unchanged.
// ---------------------------------------------------------------------------
template <int NPH, int NCO>
__global__ __launch_bounds__(256) void conv34_part(
    const ushort* __restrict__ Agh, const ushort* __restrict__ Agl,
    const ushort* __restrict__ Bgh, const ushort* __restrict__ Bgl,
    const ushort* __restrict__ zph, const ushort* __restrict__ zpl,
    float* __restrict__ P) {
    __shared__ ushort AH[144 * AST];
    __shared__ ushort AL[144 * AST];
    const int tid = threadIdx.x;
    const int b = blockIdx.x, half = blockIdx.y, g = blockIdx.z;
    const int r0 = half * 8;
    const int lane = tid & 63, wv = tid >> 6;

    f32x16 acc;
#pragma unroll
    for (int i = 0; i < 16; ++i) acc[i] = 0.f;

    const int m = wv * 32 + (lane & 31);
    const int sbase = (m >> 4) * 18 + (m & 15);
    const int koff = (lane >> 5) * 8;

#pragma unroll 1
    for (int p = 0; p < NPH; ++p) {
        if (p) __syncthreads();
        const ushort* ash = Agh + ((size_t)b * NPH + p) * 256 * 80;
        const ushort* asl = Agl + ((size_t)b * NPH + p) * 256 * 80;
#pragma unroll
        for (int e = 0; e < 6; ++e) {
            int idx = e * 256 + tid;
            if (idx < 1440) {
                int px = idx / 10, ch = idx - px * 10;
                int pr = px / 18, pc = px - pr * 18;
                int r = r0 - 1 + g + pr, c = pc - 1;
                bool inb = ((unsigned)r < 16u) && ((unsigned)c < 16u);
                uint4 vh, vl;
                if (inb) {
                    vh = *(const uint4*)(ash + (size_t)(r * 16 + c) * 80 + ch * 8);
                    vl = *(const uint4*)(asl + (size_t)(r * 16 + c) * 80 + ch * 8);
                } else {
                    vh = *(const uint4*)(zph + ch * 8);
                    vl = *(const uint4*)(zpl + ch * 8);
                }
                *(uint4*)(&AH[px * AST + ch * 8]) = vh;
                *(uint4*)(&AL[px * AST + ch * 8]) = vl;
            }
        }
        __syncthreads();

        const ushort* bsh = Bgh + (size_t)p * 2880 * 8;
        const ushort* bsl = Bgl + (size_t)p * 2880 * 8;
#pragma unroll
        for (int dw = 0; dw < 3; ++dw) {
            const int t = g * 3 + dw;
#pragma unroll
            for (int s = 0; s < 5; ++s) {
                bf16x8 ah = *(const bf16x8*)(&AH[(sbase + dw) * AST + s * 16 + koff]);
                bf16x8 al = *(const bf16x8*)(&AL[(sbase + dw) * AST + s * 16 + koff]);
                bf16x8 bh = *(const bf16x8*)(bsh + (size_t)((t * 5 + s) * 64 + lane) * 8);
                bf16x8 bl = *(const bf16x8*)(bsl + (size_t)((t * 5 + s) * 64 + lane) * 8);
                acc = __builtin_amdgcn_mfma_f32_32x32x16_bf16(ah, bh, acc, 0, 0, 0);
                acc = __builtin_amdgcn_mfma_f32_32x32x16_bf16(ah, bl, acc, 0, 0, 0);
                acc = __builtin_amdgcn_mfma_f32_32x32x16_bf16(al, bh, acc, 0, 0, 0);
            }
        }
    }

    int co = lane & 31;
    if (co < NCO) {
        float* pb = P + ((size_t)(g * 256 + b * 2 + half) * 128) * NCO;
#pragma unroll
        for (int r = 0; r < 16; ++r) {
            int px = wv * 32 + (r & 3) + 8 * (r >> 2) + 4 * (lane >> 5);
            pb[px * NCO + co] = acc[r];
        }
    }
}

// ---------------------------------------------------------------------------
// conv3_reduce v3: block = (b, px-quarter), all 16 couts, 64 px.
// Full 64B-line P3 reads; 41KB LDS -> 3 blocks/CU; grid 512.
// ---------------------------------------------------------------------------
__global__ __launch_bounds__(256) void conv3_reduce(const float* __restrict__ P3,
                                                    ushort* __restrict__ A4h,
                                                    ushort* __restrict__ A4l) {
    __shared__ ushort SBH[2][64 * 80];
    __shared__ ushort SBL[2][64 * 80];
    int b = blockIdx.x, pxq = blockIdx.y;
    int t = threadIdx.x;
    int co = t & 15, pxg = t >> 4;  // 16 couts fast, 16 px-groups
#pragma unroll
    for (int q = 0; q < 4; ++q) {
        int lpx64 = pxg * 4 + q;             // 0..63
        int px = pxq * 64 + lpx64;           // 0..255
        int bh = b * 2 + (px >> 7), lpx = px & 127;
        float s = 0.f;
#pragma unroll
        for (int zz = 0; zz < 3; ++zz)
            s += P3[((size_t)(zz * 256 + bh) * 128 + lpx) * 16 + co];
        float a9[9];
        spline_acts(s, a9);
        int ph = co >> 3, c8 = co & 7;
#pragma unroll
        for (int j = 0; j < 9; ++j) {
            ushort h, l2; bf16split(a9[j], h, l2);
            SBH[ph][lpx64 * 80 + c8 * 9 + j] = h;
            SBL[ph][lpx64 * 80 + c8 * 9 + j] = l2;
        }
        if (c8 == 7) {
#pragma unroll
            for (int w = 0; w < 8; ++w) {
                SBH[ph][lpx64 * 80 + 72 + w] = 0;
                SBL[ph][lpx64 * 80 + 72 + w] = 0;
            }
        }
    }
    __syncthreads();
#pragma unroll
    for (int ph = 0; ph < 2; ++ph) {
        size_t base = ((size_t)(b * 2 + ph) * 256 + pxq * 64) * 80;
#pragma unroll
        for (int e = 0; e < 3; ++e) {
            int q = e * 256 + t;   // 640 uint4 per buffer
            if (q < 640) {
                *(uint4*)(A4h + base + q * 8) = *(const uint4*)(&SBH[ph][q * 8]);
                *(uint4*)(A4l + base + q * 8) = *(const uint4*)(&SBL[ph][q * 8]);
            }
        }
    }
}

// ---------------------------------------------------------------------------
// conv4_reduce_pool v2: block = (b, half); sum 3 partials + 2x2 pool.
// ---------------------------------------------------------------------------
__global__ __launch_bounds__(256) void conv4_reduce_pool(const float* __restrict__ P4,
                                                         float* __restrict__ pooled) {
    __shared__ float SM[32 * 33];
    int b = blockIdx.x, half = blockIdx.y;
    int t = threadIdx.x;
    int co = t & 31, pg = t >> 5;  // pg 0..7
    int bh = b * 2 + half;
#pragma unroll
    for (int q = 0; q < 4; ++q) {
        int pp = pg * 4 + q;       // 0..31: local pooled px of this half
        int lr = pp >> 3, pc = pp & 7;
        int px00 = (2 * lr) * 16 + 2 * pc;
        float s00 = 0.f, s01 = 0.f, s10 = 0.f, s11 = 0.f;
#pragma unroll
        for (int zz = 0; zz < 3; ++zz) {
            const float* pb = P4 + ((size_t)(zz * 256 + bh) * 128) * 32 + co;
            s00 += pb[(size_t)px00 * 32];
            s01 += pb[(size_t)(px00 + 1) * 32];
            s10 += pb[(size_t)(px00 + 16) * 32];
            s11 += pb[(size_t)(px00 + 17) * 32];
        }
        SM[co * 33 + pp] = fmaxf(fmaxf(s00, s01), fmaxf(s10, s11));
    }
    __syncthreads();
#pragma unroll
    for (int e = 0; e < 4; ++e) {
        int idx = e * 256 + t;     // 0..1023
        int co2 = idx >> 5, pp2 = idx & 31;
        int lr2 = pp2 >> 3, pc2 = pp2 & 7;
        pooled[(size_t)b * 2048 + co2 * 64 + (half * 4 + lr2) * 8 + pc2] = SM[co2 * 33 + pp2];
    }
}

// ---------------------------------------------------------------------------
// fc_big: 64x64 tile, 4x4/thread, K_TILE=32, split-K; float4 global staging.
// ---------------------------------------------------------------------------
template <int SPLIT>
__global__ __launch_bounds__(256) void fc_big(const float* __restrict__ A,
                                              const float* __restrict__ Wt,
                                              float* __restrict__ part,
                                              int M, int N, int K) {
    __shared__ float As[32][68];
    __shared__ float Ws[32][68];
    const int tid = threadIdx.x;
    const int tx = tid & 15, ty = tid >> 4;
    const int bm = blockIdx.y * 64, bn = blockIdx.x * 64;
    const int kc = K / SPLIT;
    const int kbeg = blockIdx.z * kc;
    float acc[4][4] = {};
    for (int k0 = kbeg; k0 < kbeg + kc; k0 += 32) {
#pragma unroll
        for (int e = 0; e < 2; ++e) {
            int q = e * 256 + tid;
            int r = q >> 3, k4 = (q & 7) * 4;
            float4 av = *(const float4*)&A[(size_t)(bm + r) * K + k0 + k4];
            float4 wv = *(const float4*)&Wt[(size_t)(bn + r) * K + k0 + k4];
            As[k4 + 0][r] = av.x; As[k4 + 1][r] = av.y;
            As[k4 + 2][r] = av.z; As[k4 + 3][r] = av.w;
            Ws[k4 + 0][r] = wv.x; Ws[k4 + 1][r] = wv.y;
            Ws[k4 + 2][r] = wv.z; Ws[k4 + 3][r] = wv.w;
        }
        __syncthreads();
#pragma unroll
        for (int kk = 0; kk < 32; ++kk) {
            float4 av = *(const float4*)(&As[kk][ty * 4]);
            float4 wv = *(const float4*)(&Ws[kk][tx * 4]);
            acc[0][0] = fmaf(av.x, wv.x, acc[0][0]);
            acc[0][1] = fmaf(av.x, wv.y, acc[0][1]);
            acc[0][2] = fmaf(av.x, wv.z, acc[0][2]);
            acc[0][3] = fmaf(av.x, wv.w, acc[0][3]);
            acc[1][0] = fmaf(av.y, wv.x, acc[1][0]);
            acc[1][1] = fmaf(av.y, wv.y, acc[1][1]);
            acc[1][2] = fmaf(av.y, wv.z, acc[1][2]);
            acc[1][3] = fmaf(av.y, wv.w, acc[1][3]);
            acc[2][0] = fmaf(av.z, wv.x, acc[2][0]);
            acc[2][1] = fmaf(av.z, wv.y, acc[2][1]);
            acc[2][2] = fmaf(av.z, wv.z, acc[2][2]);
            acc[2][3] = fmaf(av.z, wv.w, acc[2][3]);
            acc[3][0] = fmaf(av.w, wv.x, acc[3][0]);
            acc[3][1] = fmaf(av.w, wv.y, acc[3][1]);
            acc[3][2] = fmaf(av.w, wv.z, acc[3][2]);
            acc[3][3] = fmaf(av.w, wv.w, acc[3][3]);
        }
        __syncthreads();
    }
    float* p = part + (size_t)blockIdx.z * M * N;
#pragma unroll
    for (int i = 0; i < 4; ++i) {
        float4 v = make_float4(acc[i][0], acc[i][1], acc[i][2], acc[i][3]);
        *(float4*)&p[(size_t)(bm + ty * 4 + i) * N + (bn + tx * 4)] = v;
    }
}

template <int SPLIT>
__global__ void fc_reduce(const float* __restrict__ part, const float* __restrict__ bias,
                          float* __restrict__ C, int MN, int N, int relu) {
    int i = blockIdx.x * 256 + threadIdx.x;
    if (i >= MN) return;
    float s = bias[i % N];
#pragma unroll
    for (int z = 0; z < SPLIT; ++z) s += part[(size_t)z * MN + i];
    C[i] = relu ? fmaxf(s, 0.f) : s;
}

__global__ __launch_bounds__(256) void fc3_kernel(const float* __restrict__ A,
                                                  const float* __restrict__ Wt,
                                                  const float* __restrict__ bias,
                                                  float* __restrict__ C) {
    int gid = blockIdx.x * 256 + threadIdx.x;
    int wid = gid >> 6;
    int lane = gid & 63;
    int m = wid / 10, n = wid - m * 10;
    const float4* a = (const float4*)(A + (size_t)m * 1024);
    const float4* w = (const float4*)(Wt + (size_t)n * 1024);
    float s = 0.f;
#pragma unroll
    for (int it = 0; it < 4; ++it) {
        float4 av = a[it * 64 + lane];
        float4 wv = w[it * 64 + lane];
        s += av.x * wv.x + av.y * wv.y + av.z * wv.z + av.w * wv.w;
    }
#pragma unroll
    for (int off = 32; off; off >>= 1) s += __shfl_xor(s, off);
    if (lane == 0) C[wid] = s + bias[n];
}

// ---------------------------------------------------------------------------
extern "C" void kernel_launch(void* const* d_in, const int* in_sizes, int n_in,
                              void* d_out, int out_size, void* d_ws, size_t ws_size,
                              hipStream_t stream) {
    const float* x   = (const float*)d_in[0];
    const float* bw1 = (const float*)d_in[1];
    const float* sw1 = (const float*)d_in[2];
    const float* sc1 = (const float*)d_in[3];
    const float* bw2 = (const float*)d_in[4];
    const float* sw2 = (const float*)d_in[5];
    const float* sc2 = (const float*)d_in[6];
    const float* bw3 = (const float*)d_in[7];
    const float* sw3 = (const float*)d_in[8];
    const float* sc3 = (const float*)d_in[9];
    const float* bw4 = (const float*)d_in[10];
    const float* sw4 = (const float*)d_in[11];
    const float* sc4 = (const float*)d_in[12];
    const float* w1  = (const float*)d_in[13];
    const float* b1  = (const float*)d_in[14];
    const float* w2  = (const float*)d_in[15];
    const float* b2  = (const float*)d_in[16];
    const float* w3  = (const float*)d_in[17];
    const float* b3  = (const float*)d_in[18];

    float*  wsf = (float*)d_ws;
    ushort* wsu = (ushort*)d_ws;
    ushort* k1h = wsu + 110848;
    ushort* k1l = wsu + 120064;
    ushort* k2h = wsu + 129280;
    ushort* k2l = wsu + 143104;
    ushort* k3h = wsu + 156928;
    ushort* k3l = wsu + 179968;
    ushort* k4h = wsu + 203008;
    ushort* k4l = wsu + 249088;
    ushort* zph = wsu + 295168;
    ushort* zpl = wsu + 295248;
    ushort* A1h = wsu + 524288;
    ushort* A1l = wsu + 4194304;
    ushort* A2h = wsu + 7864320;
    ushort* A2l = wsu + 12582912;
    ushort* A3h = wsu + 524288;
    ushort* A3l = wsu + 3145728;
    ushort* A4h = wsu + 5767168;
    ushort* A4l = wsu + 11010048;
    float* P3   = wsf + 9437184;    // 3x256x128x16 fp32
    float* P4   = wsf + 11534336;   // 3x256x128x32 fp32
    float* pooled = wsf + 262144;
    float* part1  = wsf + 524288;
    float* fc1o   = wsf + 2621440;
    float* part2  = wsf + 2883584;
    float* fc2o   = wsf + 3932160;

    prep_kernel<<<558, 256, 0, stream>>>(x, bw1, sw1, sc1, bw2, sw2, sc2,
                                         bw3, sw3, sc3, bw4, sw4, sc4,
                                         k1h, k1l, k2h, k2l, k3h, k3l, k4h, k4l,
                                         zph, zpl, A1h, A1l);

    conv_strip<28, 7, 8, 40, 2, 4, 0><<<512, 256, 0, stream>>>(A1h, A1l, k1h, k1l,
                                                               zph, zpl, A2h, A2l);
    conv_strip<36, 9, 12, 56, 3, 8, 1><<<512, 256, 0, stream>>>(A2h, A2l, k2h, k2l,
                                                                zph, zpl, A3h, A3l);
    conv34_part<1, 16><<<dim3(128, 2, 3), 256, 0, stream>>>(A3h, A3l, k3h, k3l,
                                                            zph, zpl, P3);
    conv3_reduce<<<dim3(128, 4), 256, 0, stream>>>(P3, A4h, A4l);
    conv34_part<2, 32><<<dim3(128, 2, 3), 256, 0, stream>>>(A4h, A4l, k4h, k4l,
                                                            zph, zpl, P4);
    conv4_reduce_pool<<<dim3(128, 2), 256, 0, stream>>>(P4, pooled);

    fc_big<8><<<dim3(32, 2, 8), 256, 0, stream>>>(pooled, w1, part1, 128, 2048, 2048);
    fc_reduce<8><<<1024, 256, 0, stream>>>(part1, b1, fc1o, 262144, 2048, 1);
    fc_big<8><<<dim3(16, 2, 8), 256, 0, stream>>>(fc1o, w2, part2, 128, 1024, 2048);
    fc_reduce<8><<<512, 256, 0, stream>>>(part2, b2, fc2o, 131072, 1024, 1);
    fc3_kernel<<<320, 256, 0, stream>>>(fc2o, w3, b3, (float*)d_out);
}

// Round 15
// 132.026 us; speedup vs baseline: 1.3537x; 1.0363x over previous
//
#include <hip/hip_runtime.h>

#define BATCH 128
#define AST 88  // padded-A LDS row stride in ushorts (176B, 16B-aligned)

typedef __attribute__((ext_vector_type(8))) short bf16x8;
typedef __attribute__((ext_vector_type(16))) float f32x16;

// ---------------------------------------------------------------------------
// Spline activation: act[0] = silu(x), act[1..8] = cubic B-spline bases
// ---------------------------------------------------------------------------
__device__ __forceinline__ void spline_acts(float xv, float act[9]) {
    act[0] = xv * (1.0f / (1.0f + __expf(-xv)));  // silu
    float g[12];
#pragma unroll
    for (int i = 0; i < 12; ++i) g[i] = (float)(i - 3) * 0.4f - 1.0f;
    float bb[11];
#pragma unroll
    for (int c = 0; c < 11; ++c) bb[c] = (xv >= g[c] && xv < g[c + 1]) ? 1.0f : 0.0f;
#pragma unroll
    for (int k = 1; k <= 3; ++k) {
#pragma unroll
        for (int c = 0; c + k < 11; ++c) {
            float left  = (xv - g[c]) * (1.0f / (g[c + k] - g[c])) * bb[c];
            float right = (g[c + k + 1] - xv) * (1.0f / (g[c + k + 1] - g[c + 1])) * bb[c + 1];
            bb[c] = left + right;
        }
    }
#pragma unroll
    for (int c = 0; c < 8; ++c) act[c + 1] = bb[c];
}

__device__ __constant__ float ZPAD[9] = {0.0f, 0.0f, 0.0f, 0.02083333333f,
                                         0.47916666667f, 0.47916666667f,
                                         0.02083333333f, 0.0f, 0.0f};

// bf16 hi/lo split (round-to-nearest-even); x = hi + lo + O(2^-18 x)
__device__ __forceinline__ void bf16split(float x, ushort& h, ushort& l) {
    union { float f; unsigned u; } a; a.f = x;
    unsigned r = a.u + 0x7FFF + ((a.u >> 16) & 1);
    h = (ushort)(r >> 16);
    union { unsigned u; float f; } hf; hf.u = (unsigned)h << 16;
    union { float f; unsigned u; } bres; bres.f = x - hf.f;
    unsigned r2 = bres.u + 0x7FFF + ((bres.u >> 16) & 1);
    l = (ushort)(r2 >> 16);
}

// packed conv weight value: f = cin*9 + tap, j = spline idx
__device__ __forceinline__ float wval(const float* bw, const float* sw, const float* sc,
                                      int F, int f, int j, int o) {
    if (j == 0) return bw[o * F + f];
    return sw[(o * F + f) * 8 + (j - 1)] * sc[o * F + f];
}

// ---------------------------------------------------------------------------
// prep: pack MFMA B-fragments (bf16 hi/lo) for all 4 conv layers + zp pattern.
// B-frag (32x32x16): value(lane l, elem e) = W[k = s*16+(l>>5)*8+e][o = l&31]
// ---------------------------------------------------------------------------
__global__ __launch_bounds__(256) void prep_kernel(
    const float* __restrict__ bw1, const float* __restrict__ sw1, const float* __restrict__ sc1,
    const float* __restrict__ bw2, const float* __restrict__ sw2, const float* __restrict__ sc2,
    const float* __restrict__ bw3, const float* __restrict__ sw3, const float* __restrict__ sc3,
    const float* __restrict__ bw4, const float* __restrict__ sw4, const float* __restrict__ sc4,
    ushort* __restrict__ k1h, ushort* __restrict__ k1l,
    ushort* __restrict__ k2h, ushort* __restrict__ k2l,
    ushort* __restrict__ k3h, ushort* __restrict__ k3l,
    ushort* __restrict__ k4h, ushort* __restrict__ k4l,
    ushort* __restrict__ zph, ushort* __restrict__ zpl) {
    int i = blockIdx.x * 256 + threadIdx.x;
    if (i < 1152) {                            // conv1
        int l = i & 63, s = (i >> 6) & 1, t = i / 128;
#pragma unroll
        for (int e = 0; e < 8; ++e) {
            int k = s * 16 + ((l >> 5) * 8) + e, o = l & 31;
            float w = 0.f;
            if (k < 27 && o < 4) w = wval(bw1, sw1, sc1, 27, (k / 9) * 9 + t, k % 9, o);
            ushort h, lo; bf16split(w, h, lo);
            k1h[i * 8 + e] = h; k1l[i * 8 + e] = lo;
        }
    } else if (i < 2880) {                     // conv2
        int q = i - 1152;
        int l = q & 63, s = (q >> 6) % 3, t = q / 192;
#pragma unroll
        for (int e = 0; e < 8; ++e) {
            int k = s * 16 + ((l >> 5) * 8) + e, o = l & 31;
            float w = 0.f;
            if (k < 36 && o < 8) w = wval(bw2, sw2, sc2, 36, (k / 9) * 9 + t, k % 9, o);
            ushort h, lo; bf16split(w, h, lo);
            k2h[q * 8 + e] = h; k2l[q * 8 + e] = lo;
        }
    } else if (i < 5760) {                     // conv3
        int q = i - 2880;
        int l = q & 63, s = (q >> 6) % 5, t = q / 320;
#pragma unroll
        for (int e = 0; e < 8; ++e) {
            int k = s * 16 + ((l >> 5) * 8) + e, o = l & 31;
            float w = 0.f;
            if (k < 72 && o < 16) w = wval(bw3, sw3, sc3, 72, (k / 9) * 9 + t, k % 9, o);
            ushort h, lo; bf16split(w, h, lo);
            k3h[q * 8 + e] = h; k3l[q * 8 + e] = lo;
        }
    } else if (i < 11520) {                    // conv4
        int q = i - 5760;
        int l = q & 63, s = (q >> 6) % 5, t = (q / 320) % 9, p = q / 2880;
#pragma unroll
        for (int e = 0; e < 8; ++e) {
            int k = s * 16 + ((l >> 5) * 8) + e, o = l & 31;
            float w = 0.f;
            if (k < 72) w = wval(bw4, sw4, sc4, 144, (p * 8 + k / 9) * 9 + t, k % 9, o);
            ushort h, lo; bf16split(w, h, lo);
            k4h[q * 8 + e] = h; k4l[q * 8 + e] = lo;
        }
    } else if (i < 11600) {
        int c = i - 11520;
        ushort h, lo; bf16split(ZPAD[c % 9], h, lo);
        zph[c] = h; zpl[c] = lo;
    }
}

// ---------------------------------------------------------------------------
// conv1_fused: raw x -> (inline spline+bf16split into LDS) -> MFMA -> spline
// epilogue -> A2 (B,1024,36). Block = one 8-row strip. No A1 buffer.
// ---------------------------------------------------------------------------
__global__ __launch_bounds__(256) void conv1_fused(
    const float* __restrict__ x,
    const ushort* __restrict__ Bgh, const ushort* __restrict__ Bgl,
    ushort* __restrict__ Oh, ushort* __restrict__ Ol) {
    constexpr int ASTR = 40, KSTEPS = 2, NCO = 4;
    __shared__ ushort AH[340 * ASTR];  // 13.6 KB
    __shared__ ushort AL[340 * ASTR];
    const int tid = threadIdx.x;
    const int b = blockIdx.x >> 2, strip = blockIdx.x & 3;
    const int r0 = strip * 8;
    const int lane = tid & 63, wv = tid >> 6;

    // stage: 340 padded slots; inline spline of raw x (border -> ZPAD pattern)
    for (int px = tid; px < 340; px += 256) {
        int lr = px / 34, pc = px - lr * 34;
        int grow = r0 - 1 + lr, gc = pc - 1;
        bool inb = ((unsigned)grow < 32u) && ((unsigned)gc < 32u);
        unsigned rh[16], rl[16];
#pragma unroll
        for (int w = 0; w < 16; ++w) { rh[w] = 0u; rl[w] = 0u; }
        if (inb) {
            const float* xb = x + (size_t)b * 3072 + grow * 32 + gc;
#pragma unroll
            for (int cin = 0; cin < 3; ++cin) {
                float a9[9];
                spline_acts(xb[cin * 1024], a9);
#pragma unroll
                for (int j = 0; j < 9; ++j) {
                    ushort h, l2; bf16split(a9[j], h, l2);
                    int c = cin * 9 + j;
                    if (c & 1) { rh[c >> 1] |= (unsigned)h << 16; rl[c >> 1] |= (unsigned)l2 << 16; }
                    else       { rh[c >> 1] |= h;                  rl[c >> 1] |= l2; }
                }
            }
        } else {
#pragma unroll
            for (int c = 0; c < 27; ++c) {
                ushort h, l2; bf16split(ZPAD[c % 9], h, l2);
                if (c & 1) { rh[c >> 1] |= (unsigned)h << 16; rl[c >> 1] |= (unsigned)l2 << 16; }
                else       { rh[c >> 1] |= h;                  rl[c >> 1] |= l2; }
            }
        }
        unsigned* dh = (unsigned*)&AH[px * ASTR];
        unsigned* dl = (unsigned*)&AL[px * ASTR];
#pragma unroll
        for (int w = 0; w < 16; ++w) { dh[w] = rh[w]; dl[w] = rl[w]; }
    }
    __syncthreads();

    f32x16 acc0, acc1;
#pragma unroll
    for (int i = 0; i < 16; ++i) { acc0[i] = 0.f; acc1[i] = 0.f; }

    const int p0 = wv * 64 + (lane & 31);
    const int sp0 = ((p0 >> 5) + 1) * 34 + (p0 & 31) + 1;
    const int sp1 = sp0 + 34;
    const int koff = (lane >> 5) * 8;

#pragma unroll 1
    for (int t = 0; t < 9; ++t) {
        const int dA = ((t / 3) - 1) * 34 + (t % 3) - 1;
#pragma unroll
        for (int s = 0; s < KSTEPS; ++s) {
            bf16x8 a0h = *(const bf16x8*)(&AH[(sp0 + dA) * ASTR + s * 16 + koff]);
            bf16x8 a0l = *(const bf16x8*)(&AL[(sp0 + dA) * ASTR + s * 16 + koff]);
            bf16x8 a1h = *(const bf16x8*)(&AH[(sp1 + dA) * ASTR + s * 16 + koff]);
            bf16x8 a1l = *(const bf16x8*)(&AL[(sp1 + dA) * ASTR + s * 16 + koff]);
            bf16x8 bh = *(const bf16x8*)(Bgh + (size_t)((t * KSTEPS + s) * 64 + lane) * 8);
            bf16x8 bl = *(const bf16x8*)(Bgl + (size_t)((t * KSTEPS + s) * 64 + lane) * 8);
            acc0 = __builtin_amdgcn_mfma_f32_32x32x16_bf16(a0h, bh, acc0, 0, 0, 0);
            acc1 = __builtin_amdgcn_mfma_f32_32x32x16_bf16(a1h, bh, acc1, 0, 0, 0);
            acc0 = __builtin_amdgcn_mfma_f32_32x32x16_bf16(a0h, bl, acc0, 0, 0, 0);
            acc1 = __builtin_amdgcn_mfma_f32_32x32x16_bf16(a1h, bl, acc1, 0, 0, 0);
            acc0 = __builtin_amdgcn_mfma_f32_32x32x16_bf16(a0l, bh, acc0, 0, 0, 0);
            acc1 = __builtin_amdgcn_mfma_f32_32x32x16_bf16(a1l, bh, acc1, 0, 0, 0);
        }
    }
    __syncthreads();

    // transpose acc -> LDS fp32 [NCO][257]
    float* fl = (float*)AH;
    {
        int ccol = lane & 31;
        if (ccol < NCO) {
#pragma unroll
            for (int r = 0; r < 16; ++r) {
                int row = (r & 3) + 8 * (r >> 2) + 4 * (lane >> 5);
                fl[ccol * 257 + wv * 64 + row] = acc0[r];
                fl[ccol * 257 + wv * 64 + 32 + row] = acc1[r];
            }
        }
    }
    __syncthreads();

    // spline epilogue -> A2 (36-col rows) via dense bounce, word memcpy
    unsigned* ubh = (unsigned*)AL;                 // 4608 words (AL = 6800 words)
    unsigned* ubl = (unsigned*)AH + 1032;          // fl = 1028 words
    unsigned rwh[18], rwl[18];
#pragma unroll
    for (int w = 0; w < 18; ++w) { rwh[w] = 0u; rwl[w] = 0u; }
#pragma unroll
    for (int co = 0; co < 4; ++co) {
        float a9[9];
        spline_acts(fl[co * 257 + tid], a9);
#pragma unroll
        for (int j = 0; j < 9; ++j) {
            ushort h, l2; bf16split(a9[j], h, l2);
            int c = co * 9 + j;
            if (c & 1) { rwh[c >> 1] |= (unsigned)h << 16; rwl[c >> 1] |= (unsigned)l2 << 16; }
            else       { rwh[c >> 1] |= h;                  rwl[c >> 1] |= l2; }
        }
    }
#pragma unroll
    for (int w = 0; w < 18; ++w) { ubh[tid * 18 + w] = rwh[w]; ubl[tid * 18 + w] = rwl[w]; }
    __syncthreads();
    size_t basew = ((size_t)b * 1024 + strip * 256) * 18;
    unsigned* goh = (unsigned*)Oh + basew;
    unsigned* gol = (unsigned*)Ol + basew;
#pragma unroll
    for (int e = 0; e < 18; ++e) {
        int q = e * 256 + tid;
        goh[q] = ubh[q];
        gol[q] = ubl[q];
    }
}

// ---------------------------------------------------------------------------
// Strip MFMA conv for conv2 (32x32, pool+spline epilogue) — verified.
// ---------------------------------------------------------------------------
template <int KG, int CHG, int CHL, int ASTR, int KSTEPS, int NCO>
__global__ __launch_bounds__(256) void conv2_strip(
    const ushort* __restrict__ Agh, const ushort* __restrict__ Agl,
    const ushort* __restrict__ Bgh, const ushort* __restrict__ Bgl,
    const ushort* __restrict__ zph, const ushort* __restrict__ zpl,
    ushort* __restrict__ Oh, ushort* __restrict__ Ol) {
    __shared__ ushort AH[340 * ASTR];
    __shared__ ushort AL[340 * ASTR];
    const int tid = threadIdx.x;
    const int b = blockIdx.x >> 2, strip = blockIdx.x & 3;
    const int r0 = strip * 8;
    const int lane = tid & 63, wv = tid >> 6;

    {
        const ushort* ash = Agh + (size_t)b * 1024 * KG;
        const ushort* asl = Agl + (size_t)b * 1024 * KG;
        for (int idx = tid; idx < 320 * CHL; idx += 256) {
            int pxl = idx / CHL, ch = idx - pxl * CHL;
            int lr = pxl >> 5, c = pxl & 31;
            int grow = r0 - 1 + lr;
            uint2 vh, vl;
            if (ch >= CHG) { vh = make_uint2(0u, 0u); vl = make_uint2(0u, 0u); }
            else if ((unsigned)grow < 32u) {
                vh = *(const uint2*)(ash + (size_t)(grow * 32 + c) * KG + ch * 4);
                vl = *(const uint2*)(asl + (size_t)(grow * 32 + c) * KG + ch * 4);
            } else {
                vh = *(const uint2*)(zph + ch * 4);
                vl = *(const uint2*)(zpl + ch * 4);
            }
            int spx = lr * 34 + c + 1;
            *(uint2*)(&AH[spx * ASTR + ch * 4]) = vh;
            *(uint2*)(&AL[spx * ASTR + ch * 4]) = vl;
        }
        for (int idx = tid; idx < 20 * CHL; idx += 256) {
            int sel = idx / CHL, ch = idx - sel * CHL;
            int lr = sel >> 1, c = (sel & 1) ? 33 : 0;
            int spx = lr * 34 + c;
            uint2 vh, vl;
            if (ch >= CHG) { vh = make_uint2(0u, 0u); vl = make_uint2(0u, 0u); }
            else { vh = *(const uint2*)(zph + ch * 4); vl = *(const uint2*)(zpl + ch * 4); }
            *(uint2*)(&AH[spx * ASTR + ch * 4]) = vh;
            *(uint2*)(&AL[spx * ASTR + ch * 4]) = vl;
        }
    }
    __syncthreads();

    f32x16 acc0, acc1;
#pragma unroll
    for (int i = 0; i < 16; ++i) { acc0[i] = 0.f; acc1[i] = 0.f; }

    const int p0 = wv * 64 + (lane & 31);
    const int sp0 = ((p0 >> 5) + 1) * 34 + (p0 & 31) + 1;
    const int sp1 = sp0 + 34;
    const int koff = (lane >> 5) * 8;

#pragma unroll 1
    for (int t = 0; t < 9; ++t) {
        const int dA = ((t / 3) - 1) * 34 + (t % 3) - 1;
#pragma unroll
        for (int s = 0; s < KSTEPS; ++s) {
            bf16x8 a0h = *(const bf16x8*)(&AH[(sp0 + dA) * ASTR + s * 16 + koff]);
            bf16x8 a0l = *(const bf16x8*)(&AL[(sp0 + dA) * ASTR + s * 16 + koff]);
            bf16x8 a1h = *(const bf16x8*)(&AH[(sp1 + dA) * ASTR + s * 16 + koff]);
            bf16x8 a1l = *(const bf16x8*)(&AL[(sp1 + dA) * ASTR + s * 16 + koff]);
            bf16x8 bh = *(const bf16x8*)(Bgh + (size_t)((t * KSTEPS + s) * 64 + lane) * 8);
            bf16x8 bl = *(const bf16x8*)(Bgl + (size_t)((t * KSTEPS + s) * 64 + lane) * 8);
            acc0 = __builtin_amdgcn_mfma_f32_32x32x16_bf16(a0h, bh, acc0, 0, 0, 0);
            acc1 = __builtin_amdgcn_mfma_f32_32x32x16_bf16(a1h, bh, acc1, 0, 0, 0);
            acc0 = __builtin_amdgcn_mfma_f32_32x32x16_bf16(a0h, bl, acc0, 0, 0, 0);
            acc1 = __builtin_amdgcn_mfma_f32_32x32x16_bf16(a1h, bl, acc1, 0, 0, 0);
            acc0 = __builtin_amdgcn_mfma_f32_32x32x16_bf16(a0l, bh, acc0, 0, 0, 0);
            acc1 = __builtin_amdgcn_mfma_f32_32x32x16_bf16(a1l, bh, acc1, 0, 0, 0);
        }
    }
    __syncthreads();

    float* fl = (float*)AH;
    {
        int ccol = lane & 31;
        if (ccol < NCO) {
#pragma unroll
            for (int r = 0; r < 16; ++r) {
                int row = (r & 3) + 8 * (r >> 2) + 4 * (lane >> 5);
                fl[ccol * 257 + wv * 64 + row] = acc0[r];
                fl[ccol * 257 + wv * 64 + 32 + row] = acc1[r];
            }
        }
    }
    __syncthreads();

    // pool + spline -> A3 (80-col rows) via dense bounce
    int cg = tid >> 6, pl = tid & 63;
    int phl = pl >> 4, pw = pl & 15;
    int base_m = (2 * phl) * 32 + 2 * pw;
    unsigned rwh[9], rwl[9];
#pragma unroll
    for (int w = 0; w < 9; ++w) { rwh[w] = 0u; rwl[w] = 0u; }
#pragma unroll
    for (int e = 0; e < 2; ++e) {
        int co = cg * 2 + e;
        const float* fb = fl + co * 257 + base_m;
        float m = fmaxf(fmaxf(fb[0], fb[1]), fmaxf(fb[32], fb[33]));
        float a9[9];
        spline_acts(m, a9);
#pragma unroll
        for (int j = 0; j < 9; ++j) {
            ushort h, l2; bf16split(a9[j], h, l2);
            int c = e * 9 + j;
            if (c & 1) { rwh[c >> 1] |= (unsigned)h << 16; rwl[c >> 1] |= (unsigned)l2 << 16; }
            else       { rwh[c >> 1] |= h;                  rwl[c >> 1] |= l2; }
        }
    }
    unsigned* ubh = (unsigned*)AL;
    unsigned* ubl = (unsigned*)AL + 2560;
#pragma unroll
    for (int w = 0; w < 9; ++w) {
        ubh[pl * 40 + cg * 9 + w] = rwh[w];
        ubl[pl * 40 + cg * 9 + w] = rwl[w];
    }
    if (cg == 3) {
#pragma unroll
        for (int w = 0; w < 4; ++w) { ubh[pl * 40 + 36 + w] = 0u; ubl[pl * 40 + 36 + w] = 0u; }
    }
    __syncthreads();
    size_t base = ((size_t)b * 256 + strip * 64) * 80;
    const ushort* sbh = (const ushort*)ubh;
    const ushort* sbl = (const ushort*)ubl;
#pragma unroll
    for (int e = 0; e < 3; ++e) {
        int q = e * 256 + tid;
        if (q < 640) {
            *(uint4*)(Oh + base + q * 8) = *(const uint4*)(sbh + q * 8);
            *(uint4*)(Ol + base + q * 8) = *(const uint4*)(sbl + q * 8);
        }
    }
}

// ---------------------------------------------------------------------------
// conv34_part: split-K MFMA partial, z = dh-group (3); cin-phases looped.
// ---------------------------------------------------------------------------
template <int NPH, int NCO>
__global__ __launch_bounds__(256) void conv34_part(
    const ushort* __restrict__ Agh, const ushort* __restrict__ Agl,
    const ushort* __restrict__ Bgh, const ushort* __restrict__ Bgl,
    const ushort* __restrict__ zph, const ushort* __restrict__ zpl,
    float* __restrict__ P) {
    __shared__ ushort AH[144 * AST];
    __shared__ ushort AL[144 * AST];
    const int tid = threadIdx.x;
    const int b = blockIdx.x, half = blockIdx.y, g = blockIdx.z;
    const int r0 = half * 8;
    const int lane = tid & 63, wv = tid >> 6;

    f32x16 acc;
#pragma unroll
    for (int i = 0; i < 16; ++i) acc[i] = 0.f;

    const int m = wv * 32 + (lane & 31);
    const int sbase = (m >> 4) * 18 + (m & 15);
    const int koff = (lane >> 5) * 8;

#pragma unroll 1
    for (int p = 0; p < NPH; ++p) {
        if (p) __syncthreads();
        const ushort* ash = Agh + ((size_t)b * NPH + p) * 256 * 80;
        const ushort* asl = Agl + ((size_t)b * NPH + p) * 256 * 80;
#pragma unroll
        for (int e = 0; e < 6; ++e) {
            int idx = e * 256 + tid;
            if (idx < 1440) {
                int px = idx / 10, ch = idx - px * 10;
                int pr = px / 18, pc = px - pr * 18;
                int r = r0 - 1 + g + pr, c = pc - 1;
                bool inb = ((unsigned)r < 16u) && ((unsigned)c < 16u);
                uint4 vh, vl;
                if (inb) {
                    vh = *(const uint4*)(ash + (size_t)(r * 16 + c) * 80 + ch * 8);
                    vl = *(const uint4*)(asl + (size_t)(r * 16 + c) * 80 + ch * 8);
                } else {
                    vh = *(const uint4*)(zph + ch * 8);
                    vl = *(const uint4*)(zpl + ch * 8);
                }
                *(uint4*)(&AH[px * AST + ch * 8]) = vh;
                *(uint4*)(&AL[px * AST + ch * 8]) = vl;
            }
        }
        __syncthreads();

        const ushort* bsh = Bgh + (size_t)p * 2880 * 8;
        const ushort* bsl = Bgl + (size_t)p * 2880 * 8;
#pragma unroll
        for (int dw = 0; dw < 3; ++dw) {
            const int t = g * 3 + dw;
#pragma unroll
            for (int s = 0; s < 5; ++s) {
                bf16x8 ah = *(const bf16x8*)(&AH[(sbase + dw) * AST + s * 16 + koff]);
                bf16x8 al = *(const bf16x8*)(&AL[(sbase + dw) * AST + s * 16 + koff]);
                bf16x8 bh = *(const bf16x8*)(bsh + (size_t)((t * 5 + s) * 64 + lane) * 8);
                bf16x8 bl = *(const bf16x8*)(bsl + (size_t)((t * 5 + s) * 64 + lane) * 8);
                acc = __builtin_amdgcn_mfma_f32_32x32x16_bf16(ah, bh, acc, 0, 0, 0);
                acc = __builtin_amdgcn_mfma_f32_32x32x16_bf16(ah, bl, acc, 0, 0, 0);
                acc = __builtin_amdgcn_mfma_f32_32x32x16_bf16(al, bh, acc, 0, 0, 0);
            }
        }
    }

    int co = lane & 31;
    if (co < NCO) {
        float* pb = P + ((size_t)(g * 256 + b * 2 + half) * 128) * NCO;
#pragma unroll
        for (int r = 0; r < 16; ++r) {
            int px = wv * 32 + (r & 3) + 8 * (r >> 2) + 4 * (lane >> 5);
            pb[px * NCO + co] = acc[r];
        }
    }
}

// ---------------------------------------------------------------------------
// conv3_reduce v3: block = (b, px-quarter), all 16 couts, 64 px.
// ---------------------------------------------------------------------------
__global__ __launch_bounds__(256) void conv3_reduce(const float* __restrict__ P3,
                                                    ushort* __restrict__ A4h,
                                                    ushort* __restrict__ A4l) {
    __shared__ ushort SBH[2][64 * 80];
    __shared__ ushort SBL[2][64 * 80];
    int b = blockIdx.x, pxq = blockIdx.y;
    int t = threadIdx.x;
    int co = t & 15, pxg = t >> 4;
#pragma unroll
    for (int q = 0; q < 4; ++q) {
        int lpx64 = pxg * 4 + q;
        int px = pxq * 64 + lpx64;
        int bh = b * 2 + (px >> 7), lpx = px & 127;
        float s = 0.f;
#pragma unroll
        for (int zz = 0; zz < 3; ++zz)
            s += P3[((size_t)(zz * 256 + bh) * 128 + lpx) * 16 + co];
        float a9[9];
        spline_acts(s, a9);
        int ph = co >> 3, c8 = co & 7;
#pragma unroll
        for (int j = 0; j < 9; ++j) {
            ushort h, l2; bf16split(a9[j], h, l2);
            SBH[ph][lpx64 * 80 + c8 * 9 + j] = h;
            SBL[ph][lpx64 * 80 + c8 * 9 + j] = l2;
        }
        if (c8 == 7) {
#pragma unroll
            for (int w = 0; w < 8; ++w) {
                SBH[ph][lpx64 * 80 + 72 + w] = 0;
                SBL[ph][lpx64 * 80 + 72 + w] = 0;
            }
        }
    }
    __syncthreads();
#pragma unroll
    for (int ph = 0; ph < 2; ++ph) {
        size_t base = ((size_t)(b * 2 + ph) * 256 + pxq * 64) * 80;
#pragma unroll
        for (int e = 0; e < 3; ++e) {
            int q = e * 256 + t;
            if (q < 640) {
                *(uint4*)(A4h + base + q * 8) = *(const uint4*)(&SBH[ph][q * 8]);
                *(uint4*)(A4l + base + q * 8) = *(const uint4*)(&SBL[ph][q * 8]);
            }
        }
    }
}

// ---------------------------------------------------------------------------
// conv4_reduce_pool v2: block = (b, half); sum 3 partials + 2x2 pool.
// ---------------------------------------------------------------------------
__global__ __launch_bounds__(256) void conv4_reduce_pool(const float* __restrict__ P4,
                                                         float* __restrict__ pooled) {
    __shared__ float SM[32 * 33];
    int b = blockIdx.x, half = blockIdx.y;
    int t = threadIdx.x;
    int co = t & 31, pg = t >> 5;
    int bh = b * 2 + half;
#pragma unroll
    for (int q = 0; q < 4; ++q) {
        int pp = pg * 4 + q;
        int lr = pp >> 3, pc = pp & 7;
        int px00 = (2 * lr) * 16 + 2 * pc;
        float s00 = 0.f, s01 = 0.f, s10 = 0.f, s11 = 0.f;
#pragma unroll
        for (int zz = 0; zz < 3; ++zz) {
            const float* pb = P4 + ((size_t)(zz * 256 + bh) * 128) * 32 + co;
            s00 += pb[(size_t)px00 * 32];
            s01 += pb[(size_t)(px00 + 1) * 32];
            s10 += pb[(size_t)(px00 + 16) * 32];
            s11 += pb[(size_t)(px00 + 17) * 32];
        }
        SM[co * 33 + pp] = fmaxf(fmaxf(s00, s01), fmaxf(s10, s11));
    }
    __syncthreads();
#pragma unroll
    for (int e = 0; e < 4; ++e) {
        int idx = e * 256 + t;
        int co2 = idx >> 5, pp2 = idx & 31;
        int lr2 = pp2 >> 3, pc2 = pp2 & 7;
        pooled[(size_t)b * 2048 + co2 * 64 + (half * 4 + lr2) * 8 + pc2] = SM[co2 * 33 + pp2];
    }
}

// ---------------------------------------------------------------------------
// fc_big: 64x64 tile, 4x4/thread, K_TILE=32, split-K; float4 global staging.
// ---------------------------------------------------------------------------
template <int SPLIT>
__global__ __launch_bounds__(256) void fc_big(const float* __restrict__ A,
                                              const float* __restrict__ Wt,
                                              float* __restrict__ part,
                                              int M, int N, int K) {
    __shared__ float As[32][68];
    __shared__ float Ws[32][68];
    const int tid = threadIdx.x;
    const int tx = tid & 15, ty = tid >> 4;
    const int bm = blockIdx.y * 64, bn = blockIdx.x * 64;
    const int kc = K / SPLIT;
    const int kbeg = blockIdx.z * kc;
    float acc[4][4] = {};
    for (int k0 = kbeg; k0 < kbeg + kc; k0 += 32) {
#pragma unroll
        for (int e = 0; e < 2; ++e) {
            int q = e * 256 + tid;
            int r = q >> 3, k4 = (q & 7) * 4;
            float4 av = *(const float4*)&A[(size_t)(bm + r) * K + k0 + k4];
            float4 wv = *(const float4*)&Wt[(size_t)(bn + r) * K + k0 + k4];
            As[k4 + 0][r] = av.x; As[k4 + 1][r] = av.y;
            As[k4 + 2][r] = av.z; As[k4 + 3][r] = av.w;
            Ws[k4 + 0][r] = wv.x; Ws[k4 + 1][r] = wv.y;
            Ws[k4 + 2][r] = wv.z; Ws[k4 + 3][r] = wv.w;
        }
        __syncthreads();
#pragma unroll
        for (int kk = 0; kk < 32; ++kk) {
            float4 av = *(const float4*)(&As[kk][ty * 4]);
            float4 wv = *(const float4*)(&Ws[kk][tx * 4]);
            acc[0][0] = fmaf(av.x, wv.x, acc[0][0]);
            acc[0][1] = fmaf(av.x, wv.y, acc[0][1]);
            acc[0][2] = fmaf(av.x, wv.z, acc[0][2]);
            acc[0][3] = fmaf(av.x, wv.w, acc[0][3]);
            acc[1][0] = fmaf(av.y, wv.x, acc[1][0]);
            acc[1][1] = fmaf(av.y, wv.y, acc[1][1]);
            acc[1][2] = fmaf(av.y, wv.z, acc[1][2]);
            acc[1][3] = fmaf(av.y, wv.w, acc[1][3]);
            acc[2][0] = fmaf(av.z, wv.x, acc[2][0]);
            acc[2][1] = fmaf(av.z, wv.y, acc[2][1]);
            acc[2][2] = fmaf(av.z, wv.z, acc[2][2]);
            acc[2][3] = fmaf(av.z, wv.w, acc[2][3]);
            acc[3][0] = fmaf(av.w, wv.x, acc[3][0]);
            acc[3][1] = fmaf(av.w, wv.y, acc[3][1]);
            acc[3][2] = fmaf(av.w, wv.z, acc[3][2]);
            acc[3][3] = fmaf(av.w, wv.w, acc[3][3]);
        }
        __syncthreads();
    }
    float* p = part + (size_t)blockIdx.z * M * N;
#pragma unroll
    for (int i = 0; i < 4; ++i) {
        float4 v = make_float4(acc[i][0], acc[i][1], acc[i][2], acc[i][3]);
        *(float4*)&p[(size_t)(bm + ty * 4 + i) * N + (bn + tx * 4)] = v;
    }
}

template <int SPLIT>
__global__ void fc_reduce(const float* __restrict__ part, const float* __restrict__ bias,
                          float* __restrict__ C, int MN, int N, int relu) {
    int i = blockIdx.x * 256 + threadIdx.x;
    if (i >= MN) return;
    float s = bias[i % N];
#pragma unroll
    for (int z = 0; z < SPLIT; ++z) s += part[(size_t)z * MN + i];
    C[i] = relu ? fmaxf(s, 0.f) : s;
}

__global__ __launch_bounds__(256) void fc3_kernel(const float* __restrict__ A,
                                                  const float* __restrict__ Wt,
                                                  const float* __restrict__ bias,
                                                  float* __restrict__ C) {
    int gid = blockIdx.x * 256 + threadIdx.x;
    int wid = gid >> 6;
    int lane = gid & 63;
    int m = wid / 10, n = wid - m * 10;
    const float4* a = (const float4*)(A + (size_t)m * 1024);
    const float4* w = (const float4*)(Wt + (size_t)n * 1024);
    float s = 0.f;
#pragma unroll
    for (int it = 0; it < 4; ++it) {
        float4 av = a[it * 64 + lane];
        float4 wv = w[it * 64 + lane];
        s += av.x * wv.x + av.y * wv.y + av.z * wv.z + av.w * wv.w;
    }
#pragma unroll
    for (int off = 32; off; off >>= 1) s += __shfl_xor(s, off);
    if (lane == 0) C[wid] = s + bias[n];
}

// ---------------------------------------------------------------------------
extern "C" void kernel_launch(void* const* d_in, const int* in_sizes, int n_in,
                              void* d_out, int out_size, void* d_ws, size_t ws_size,
                              hipStream_t stream) {
    const float* x   = (const float*)d_in[0];
    const float* bw1 = (const float*)d_in[1];
    const float* sw1 = (const float*)d_in[2];
    const float* sc1 = (const float*)d_in[3];
    const float* bw2 = (const float*)d_in[4];
    const float* sw2 = (const float*)d_in[5];
    const float* sc2 = (const float*)d_in[6];
    const float* bw3 = (const float*)d_in[7];
    const float* sw3 = (const float*)d_in[8];
    const float* sc3 = (const float*)d_in[9];
    const float* bw4 = (const float*)d_in[10];
    const float* sw4 = (const float*)d_in[11];
    const float* sc4 = (const float*)d_in[12];
    const float* w1  = (const float*)d_in[13];
    const float* b1  = (const float*)d_in[14];
    const float* w2  = (const float*)d_in[15];
    const float* b2  = (const float*)d_in[16];
    const float* w3  = (const float*)d_in[17];
    const float* b3  = (const float*)d_in[18];

    float*  wsf = (float*)d_ws;
    ushort* wsu = (ushort*)d_ws;
    ushort* k1h = wsu + 110848;
    ushort* k1l = wsu + 120064;
    ushort* k2h = wsu + 129280;
    ushort* k2l = wsu + 143104;
    ushort* k3h = wsu + 156928;
    ushort* k3l = wsu + 179968;
    ushort* k4h = wsu + 203008;
    ushort* k4l = wsu + 249088;
    ushort* zph = wsu + 295168;
    ushort* zpl = wsu + 295248;
    ushort* A2h = wsu + 7864320;    // (B,1024,36)
    ushort* A2l = wsu + 12582912;
    ushort* A3h = wsu + 524288;     // (B,256,80)
    ushort* A3l = wsu + 3145728;
    ushort* A4h = wsu + 5767168;    // (B,2,256,80)
    ushort* A4l = wsu + 11010048;
    float* P3   = wsf + 9437184;    // 3x256x128x16 fp32
    float* P4   = wsf + 11534336;   // 3x256x128x32 fp32
    float* pooled = wsf + 262144;
    float* part1  = wsf + 524288;
    float* fc1o   = wsf + 2621440;
    float* part2  = wsf + 2883584;
    float* fc2o   = wsf + 3932160;

    // weight-frag packing only (A1 eliminated; conv1 reads raw x)
    prep_kernel<<<46, 256, 0, stream>>>(bw1, sw1, sc1, bw2, sw2, sc2,
                                        bw3, sw3, sc3, bw4, sw4, sc4,
                                        k1h, k1l, k2h, k2l, k3h, k3l, k4h, k4l,
                                        zph, zpl);

    conv1_fused<<<512, 256, 0, stream>>>(x, k1h, k1l, A2h, A2l);
    conv2_strip<36, 9, 12, 56, 3, 8><<<512, 256, 0, stream>>>(A2h, A2l, k2h, k2l,
                                                              zph, zpl, A3h, A3l);
    conv34_part<1, 16><<<dim3(128, 2, 3), 256, 0, stream>>>(A3h, A3l, k3h, k3l,
                                                            zph, zpl, P3);
    conv3_reduce<<<dim3(128, 4), 256, 0, stream>>>(P3, A4h, A4l);
    conv34_part<2, 32><<<dim3(128, 2, 3), 256, 0, stream>>>(A4h, A4l, k4h, k4l,
                                                            zph, zpl, P4);
    conv4_reduce_pool<<<dim3(128, 2), 256, 0, stream>>>(P4, pooled);

    fc_big<8><<<dim3(32, 2, 8), 256, 0, stream>>>(pooled, w1, part1, 128, 2048, 2048);
    fc_reduce<8><<<1024, 256, 0, stream>>>(part1, b1, fc1o, 262144, 2048, 1);
    fc_big<8><<<dim3(16, 2, 8), 256, 0, stream>>>(fc1o, w2, part2, 128, 1024, 2048);
    fc_reduce<8><<<512, 256, 0, stream>>>(part2, b2, fc2o, 131072, 1024, 1);
    fc3_kernel<<<320, 256, 0, stream>>>(fc2o, w3, b3, (float*)d_out);
}

// Round 16
// 130.699 us; speedup vs baseline: 1.3674x; 1.0102x over previous
//
#include <hip/hip_runtime.h>
#include <hip/hip_bf16.h>

#define BATCH 128
#define AST 88  // conv34 padded-A LDS row stride in ushorts (176B, 16B-aligned)

typedef __attribute__((ext_vector_type(8))) short bf16x8;
typedef __attribute__((ext_vector_type(16))) float f32x16;

// ---------------------------------------------------------------------------
// Spline activation: act[0] = silu(x), act[1..8] = cubic B-spline bases
// ---------------------------------------------------------------------------
__device__ __forceinline__ void spline_acts(float xv, float act[9]) {
    act[0] = xv * (1.0f / (1.0f + __expf(-xv)));  // silu
    float g[12];
#pragma unroll
    for (int i = 0; i < 12; ++i) g[i] = (float)(i - 3) * 0.4f - 1.0f;
    float bb[11];
#pragma unroll
    for (int c = 0; c < 11; ++c) bb[c] = (xv >= g[c] && xv < g[c + 1]) ? 1.0f : 0.0f;
#pragma unroll
    for (int k = 1; k <= 3; ++k) {
#pragma unroll
        for (int c = 0; c + k < 11; ++c) {
            float left  = (xv - g[c]) * (1.0f / (g[c + k] - g[c])) * bb[c];
            float right = (g[c + k + 1] - xv) * (1.0f / (g[c + k + 1] - g[c + 1])) * bb[c + 1];
            bb[c] = left + right;
        }
    }
#pragma unroll
    for (int c = 0; c < 8; ++c) act[c + 1] = bb[c];
}

__device__ __constant__ float ZPAD[9] = {0.0f, 0.0f, 0.0f, 0.02083333333f,
                                         0.47916666667f, 0.47916666667f,
                                         0.02083333333f, 0.0f, 0.0f};

// bf16 hi/lo split via HW RNE converts (same rounding as manual RNE version)
__device__ __forceinline__ void bf16split(float x, ushort& h, ushort& l) {
    __hip_bfloat16 bh = __float2bfloat16(x);
    float hf = __bfloat162float(bh);
    __hip_bfloat16 bl = __float2bfloat16(x - hf);
    h = *(ushort*)&bh;
    l = *(ushort*)&bl;
}

// packed conv weight value: f = cin*9 + tap, j = spline idx
__device__ __forceinline__ float wval(const float* bw, const float* sw, const float* sc,
                                      int F, int f, int j, int o) {
    if (j == 0) return bw[o * F + f];
    return sw[(o * F + f) * 8 + (j - 1)] * sc[o * F + f];
}

// ---------------------------------------------------------------------------
// prep: pack MFMA B-fragments (bf16 hi/lo) for all 4 conv layers + zp pattern.
// B-frag (32x32x16): value(lane l, elem e) = W[k = s*16+(l>>5)*8+e][o = l&31]
// ---------------------------------------------------------------------------
__global__ __launch_bounds__(256) void prep_kernel(
    const float* __restrict__ bw1, const float* __restrict__ sw1, const float* __restrict__ sc1,
    const float* __restrict__ bw2, const float* __restrict__ sw2, const float* __restrict__ sc2,
    const float* __restrict__ bw3, const float* __restrict__ sw3, const float* __restrict__ sc3,
    const float* __restrict__ bw4, const float* __restrict__ sw4, const float* __restrict__ sc4,
    ushort* __restrict__ k1h, ushort* __restrict__ k1l,
    ushort* __restrict__ k2h, ushort* __restrict__ k2l,
    ushort* __restrict__ k3h, ushort* __restrict__ k3l,
    ushort* __restrict__ k4h, ushort* __restrict__ k4l,
    ushort* __restrict__ zph, ushort* __restrict__ zpl) {
    int i = blockIdx.x * 256 + threadIdx.x;
    if (i < 1152) {                            // conv1
        int l = i & 63, s = (i >> 6) & 1, t = i / 128;
#pragma unroll
        for (int e = 0; e < 8; ++e) {
            int k = s * 16 + ((l >> 5) * 8) + e, o = l & 31;
            float w = 0.f;
            if (k < 27 && o < 4) w = wval(bw1, sw1, sc1, 27, (k / 9) * 9 + t, k % 9, o);
            ushort h, lo; bf16split(w, h, lo);
            k1h[i * 8 + e] = h; k1l[i * 8 + e] = lo;
        }
    } else if (i < 2880) {                     // conv2
        int q = i - 1152;
        int l = q & 63, s = (q >> 6) % 3, t = q / 192;
#pragma unroll
        for (int e = 0; e < 8; ++e) {
            int k = s * 16 + ((l >> 5) * 8) + e, o = l & 31;
            float w = 0.f;
            if (k < 36 && o < 8) w = wval(bw2, sw2, sc2, 36, (k / 9) * 9 + t, k % 9, o);
            ushort h, lo; bf16split(w, h, lo);
            k2h[q * 8 + e] = h; k2l[q * 8 + e] = lo;
        }
    } else if (i < 5760) {                     // conv3
        int q = i - 2880;
        int l = q & 63, s = (q >> 6) % 5, t = q / 320;
#pragma unroll
        for (int e = 0; e < 8; ++e) {
            int k = s * 16 + ((l >> 5) * 8) + e, o = l & 31;
            float w = 0.f;
            if (k < 72 && o < 16) w = wval(bw3, sw3, sc3, 72, (k / 9) * 9 + t, k % 9, o);
            ushort h, lo; bf16split(w, h, lo);
            k3h[q * 8 + e] = h; k3l[q * 8 + e] = lo;
        }
    } else if (i < 11520) {                    // conv4
        int q = i - 5760;
        int l = q & 63, s = (q >> 6) % 5, t = (q / 320) % 9, p = q / 2880;
#pragma unroll
        for (int e = 0; e < 8; ++e) {
            int k = s * 16 + ((l >> 5) * 8) + e, o = l & 31;
            float w = 0.f;
            if (k < 72) w = wval(bw4, sw4, sc4, 144, (p * 8 + k / 9) * 9 + t, k % 9, o);
            ushort h, lo; bf16split(w, h, lo);
            k4h[q * 8 + e] = h; k4l[q * 8 + e] = lo;
        }
    } else if (i < 11600) {
        int c = i - 11520;
        ushort h, lo; bf16split(ZPAD[c % 9], h, lo);
        zph[c] = h; zpl[c] = lo;
    }
}

// ---------------------------------------------------------------------------
// conv1_fused: raw x -> (inline spline into LDS) -> MFMA -> spline -> A2.
// ASTR=32 (27 feats + 5 zero cols): LDS 43.5KB -> 3 blocks/CU.
// ---------------------------------------------------------------------------
__global__ __launch_bounds__(256) void conv1_fused(
    const float* __restrict__ x,
    const ushort* __restrict__ Bgh, const ushort* __restrict__ Bgl,
    ushort* __restrict__ Oh, ushort* __restrict__ Ol) {
    constexpr int ASTR = 32, KSTEPS = 2, NCO = 4;
    __shared__ ushort AH[340 * ASTR];  // 21760 B
    __shared__ ushort AL[340 * ASTR];
    const int tid = threadIdx.x;
    const int b = blockIdx.x >> 2, strip = blockIdx.x & 3;
    const int r0 = strip * 8;
    const int lane = tid & 63, wv = tid >> 6;

    // stage: 340 padded slots; inline spline of raw x (border -> ZPAD pattern)
    for (int px = tid; px < 340; px += 256) {
        int lr = px / 34, pc = px - lr * 34;
        int grow = r0 - 1 + lr, gc = pc - 1;
        bool inb = ((unsigned)grow < 32u) && ((unsigned)gc < 32u);
        unsigned rh[16], rl[16];
#pragma unroll
        for (int w = 0; w < 16; ++w) { rh[w] = 0u; rl[w] = 0u; }
        if (inb) {
            const float* xb = x + (size_t)b * 3072 + grow * 32 + gc;
#pragma unroll
            for (int cin = 0; cin < 3; ++cin) {
                float a9[9];
                spline_acts(xb[cin * 1024], a9);
#pragma unroll
                for (int j = 0; j < 9; ++j) {
                    ushort h, l2; bf16split(a9[j], h, l2);
                    int c = cin * 9 + j;
                    if (c & 1) { rh[c >> 1] |= (unsigned)h << 16; rl[c >> 1] |= (unsigned)l2 << 16; }
                    else       { rh[c >> 1] |= h;                  rl[c >> 1] |= l2; }
                }
            }
        } else {
#pragma unroll
            for (int c = 0; c < 27; ++c) {
                ushort h, l2; bf16split(ZPAD[c % 9], h, l2);
                if (c & 1) { rh[c >> 1] |= (unsigned)h << 16; rl[c >> 1] |= (unsigned)l2 << 16; }
                else       { rh[c >> 1] |= h;                  rl[c >> 1] |= l2; }
            }
        }
        unsigned* dh = (unsigned*)&AH[px * ASTR];
        unsigned* dl = (unsigned*)&AL[px * ASTR];
#pragma unroll
        for (int w = 0; w < 16; ++w) { dh[w] = rh[w]; dl[w] = rl[w]; }
    }
    __syncthreads();

    f32x16 acc0, acc1;
#pragma unroll
    for (int i = 0; i < 16; ++i) { acc0[i] = 0.f; acc1[i] = 0.f; }

    const int p0 = wv * 64 + (lane & 31);
    const int sp0 = ((p0 >> 5) + 1) * 34 + (p0 & 31) + 1;
    const int sp1 = sp0 + 34;
    const int koff = (lane >> 5) * 8;

#pragma unroll 1
    for (int t = 0; t < 9; ++t) {
        const int dA = ((t / 3) - 1) * 34 + (t % 3) - 1;
#pragma unroll
        for (int s = 0; s < KSTEPS; ++s) {
            bf16x8 a0h = *(const bf16x8*)(&AH[(sp0 + dA) * ASTR + s * 16 + koff]);
            bf16x8 a0l = *(const bf16x8*)(&AL[(sp0 + dA) * ASTR + s * 16 + koff]);
            bf16x8 a1h = *(const bf16x8*)(&AH[(sp1 + dA) * ASTR + s * 16 + koff]);
            bf16x8 a1l = *(const bf16x8*)(&AL[(sp1 + dA) * ASTR + s * 16 + koff]);
            bf16x8 bh = *(const bf16x8*)(Bgh + (size_t)((t * KSTEPS + s) * 64 + lane) * 8);
            bf16x8 bl = *(const bf16x8*)(Bgl + (size_t)((t * KSTEPS + s) * 64 + lane) * 8);
            acc0 = __builtin_amdgcn_mfma_f32_32x32x16_bf16(a0h, bh, acc0, 0, 0, 0);
            acc1 = __builtin_amdgcn_mfma_f32_32x32x16_bf16(a1h, bh, acc1, 0, 0, 0);
            acc0 = __builtin_amdgcn_mfma_f32_32x32x16_bf16(a0h, bl, acc0, 0, 0, 0);
            acc1 = __builtin_amdgcn_mfma_f32_32x32x16_bf16(a1h, bl, acc1, 0, 0, 0);
            acc0 = __builtin_amdgcn_mfma_f32_32x32x16_bf16(a0l, bh, acc0, 0, 0, 0);
            acc1 = __builtin_amdgcn_mfma_f32_32x32x16_bf16(a1l, bh, acc1, 0, 0, 0);
        }
    }
    __syncthreads();

    // transpose acc -> LDS fp32 [NCO][257]
    float* fl = (float*)AH;
    {
        int ccol = lane & 31;
        if (ccol < NCO) {
#pragma unroll
            for (int r = 0; r < 16; ++r) {
                int row = (r & 3) + 8 * (r >> 2) + 4 * (lane >> 5);
                fl[ccol * 257 + wv * 64 + row] = acc0[r];
                fl[ccol * 257 + wv * 64 + 32 + row] = acc1[r];
            }
        }
    }
    __syncthreads();

    // spline epilogue -> A2 (36-col rows) via dense bounce, word memcpy
    unsigned* ubh = (unsigned*)AL;                 // 4608 words (AL = 5440 words)
    unsigned* ubl = (unsigned*)AH + 1032;          // fl = 1028 words; 1032+4608=5640>5440? AH words=5440
    // NOTE: AH has 340*32/2 = 5440 words; 1032+4608 = 5640 > 5440 -> overlap!
    // place ubl in AH from 832 behind end instead: use offset 832? Simpler:
    // split: ubl low 4608 words fit if we start at 832 -> 832+4608=5440 exactly.
    ubl = (unsigned*)AH + 832;  // fl occupies 1028 words; overlap [832,1028) !
    // fl is dead after we read it into registers below, so read first, then write.
    {
        unsigned rwh[18], rwl[18];
        float v4[4];
#pragma unroll
        for (int co = 0; co < 4; ++co) v4[co] = fl[co * 257 + tid];
        __syncthreads();  // all reads of fl done before ubl writes overlap it
#pragma unroll
        for (int w = 0; w < 18; ++w) { rwh[w] = 0u; rwl[w] = 0u; }
#pragma unroll
        for (int co = 0; co < 4; ++co) {
            float a9[9];
            spline_acts(v4[co], a9);
#pragma unroll
            for (int j = 0; j < 9; ++j) {
                ushort h, l2; bf16split(a9[j], h, l2);
                int c = co * 9 + j;
                if (c & 1) { rwh[c >> 1] |= (unsigned)h << 16; rwl[c >> 1] |= (unsigned)l2 << 16; }
                else       { rwh[c >> 1] |= h;                  rwl[c >> 1] |= l2; }
            }
        }
#pragma unroll
        for (int w = 0; w < 18; ++w) { ubh[tid * 18 + w] = rwh[w]; ubl[tid * 18 + w] = rwl[w]; }
    }
    __syncthreads();
    size_t basew = ((size_t)b * 1024 + strip * 256) * 18;
    unsigned* goh = (unsigned*)Oh + basew;
    unsigned* gol = (unsigned*)Ol + basew;
#pragma unroll
    for (int e = 0; e < 18; ++e) {
        int q = e * 256 + tid;
        goh[q] = ubh[q];
        gol[q] = ubl[q];
    }
}

// ---------------------------------------------------------------------------
// conv2_strip (32x32, pool+spline epilogue) — verified structure.
// ---------------------------------------------------------------------------
template <int KG, int CHG, int CHL, int ASTR, int KSTEPS, int NCO>
__global__ __launch_bounds__(256) void conv2_strip(
    const ushort* __restrict__ Agh, const ushort* __restrict__ Agl,
    const ushort* __restrict__ Bgh, const ushort* __restrict__ Bgl,
    const ushort* __restrict__ zph, const ushort* __restrict__ zpl,
    ushort* __restrict__ Oh, ushort* __restrict__ Ol) {
    __shared__ ushort AH[340 * ASTR];
    __shared__ ushort AL[340 * ASTR];
    const int tid = threadIdx.x;
    const int b = blockIdx.x >> 2, strip = blockIdx.x & 3;
    const int r0 = strip * 8;
    const int lane = tid & 63, wv = tid >> 6;

    {
        const ushort* ash = Agh + (size_t)b * 1024 * KG;
        const ushort* asl = Agl + (size_t)b * 1024 * KG;
        for (int idx = tid; idx < 320 * CHL; idx += 256) {
            int pxl = idx / CHL, ch = idx - pxl * CHL;
            int lr = pxl >> 5, c = pxl & 31;
            int grow = r0 - 1 + lr;
            uint2 vh, vl;
            if (ch >= CHG) { vh = make_uint2(0u, 0u); vl = make_uint2(0u, 0u); }
            else if ((unsigned)grow < 32u) {
                vh = *(const uint2*)(ash + (size_t)(grow * 32 + c) * KG + ch * 4);
                vl = *(const uint2*)(asl + (size_t)(grow * 32 + c) * KG + ch * 4);
            } else {
                vh = *(const uint2*)(zph + ch * 4);
                vl = *(const uint2*)(zpl + ch * 4);
            }
            int spx = lr * 34 + c + 1;
            *(uint2*)(&AH[spx * ASTR + ch * 4]) = vh;
            *(uint2*)(&AL[spx * ASTR + ch * 4]) = vl;
        }
        for (int idx = tid; idx < 20 * CHL; idx += 256) {
            int sel = idx / CHL, ch = idx - sel * CHL;
            int lr = sel >> 1, c = (sel & 1) ? 33 : 0;
            int spx = lr * 34 + c;
            uint2 vh, vl;
            if (ch >= CHG) { vh = make_uint2(0u, 0u); vl = make_uint2(0u, 0u); }
            else { vh = *(const uint2*)(zph + ch * 4); vl = *(const uint2*)(zpl + ch * 4); }
            *(uint2*)(&AH[spx * ASTR + ch * 4]) = vh;
            *(uint2*)(&AL[spx * ASTR + ch * 4]) = vl;
        }
    }
    __syncthreads();

    f32x16 acc0, acc1;
#pragma unroll
    for (int i = 0; i < 16; ++i) { acc0[i] = 0.f; acc1[i] = 0.f; }

    const int p0 = wv * 64 + (lane & 31);
    const int sp0 = ((p0 >> 5) + 1) * 34 + (p0 & 31) + 1;
    const int sp1 = sp0 + 34;
    const int koff = (lane >> 5) * 8;

#pragma unroll 1
    for (int t = 0; t < 9; ++t) {
        const int dA = ((t / 3) - 1) * 34 + (t % 3) - 1;
#pragma unroll
        for (int s = 0; s < KSTEPS; ++s) {
            bf16x8 a0h = *(const bf16x8*)(&AH[(sp0 + dA) * ASTR + s * 16 + koff]);
            bf16x8 a0l = *(const bf16x8*)(&AL[(sp0 + dA) * ASTR + s * 16 + koff]);
            bf16x8 a1h = *(const bf16x8*)(&AH[(sp1 + dA) * ASTR + s * 16 + koff]);
            bf16x8 a1l = *(const bf16x8*)(&AL[(sp1 + dA) * ASTR + s * 16 + koff]);
            bf16x8 bh = *(const bf16x8*)(Bgh + (size_t)((t * KSTEPS + s) * 64 + lane) * 8);
            bf16x8 bl = *(const bf16x8*)(Bgl + (size_t)((t * KSTEPS + s) * 64 + lane) * 8);
            acc0 = __builtin_amdgcn_mfma_f32_32x32x16_bf16(a0h, bh, acc0, 0, 0, 0);
            acc1 = __builtin_amdgcn_mfma_f32_32x32x16_bf16(a1h, bh, acc1, 0, 0, 0);
            acc0 = __builtin_amdgcn_mfma_f32_32x32x16_bf16(a0h, bl, acc0, 0, 0, 0);
            acc1 = __builtin_amdgcn_mfma_f32_32x32x16_bf16(a1h, bl, acc1, 0, 0, 0);
            acc0 = __builtin_amdgcn_mfma_f32_32x32x16_bf16(a0l, bh, acc0, 0, 0, 0);
            acc1 = __builtin_amdgcn_mfma_f32_32x32x16_bf16(a1l, bh, acc1, 0, 0, 0);
        }
    }
    __syncthreads();

    float* fl = (float*)AH;
    {
        int ccol = lane & 31;
        if (ccol < NCO) {
#pragma unroll
            for (int r = 0; r < 16; ++r) {
                int row = (r & 3) + 8 * (r >> 2) + 4 * (lane >> 5);
                fl[ccol * 257 + wv * 64 + row] = acc0[r];
                fl[ccol * 257 + wv * 64 + 32 + row] = acc1[r];
            }
        }
    }
    __syncthreads();

    // pool + spline -> A3 (80-col rows) via dense bounce
    int cg = tid >> 6, pl = tid & 63;
    int phl = pl >> 4, pw = pl & 15;
    int base_m = (2 * phl) * 32 + 2 * pw;
    unsigned rwh[9], rwl[9];
#pragma unroll
    for (int w = 0; w < 9; ++w) { rwh[w] = 0u; rwl[w] = 0u; }
#pragma unroll
    for (int e = 0; e < 2; ++e) {
        int co = cg * 2 + e;
        const float* fb = fl + co * 257 + base_m;
        float m = fmaxf(fmaxf(fb[0], fb[1]), fmaxf(fb[32], fb[33]));
        float a9[9];
        spline_acts(m, a9);
#pragma unroll
        for (int j = 0; j < 9; ++j) {
            ushort h, l2; bf16split(a9[j], h, l2);
            int c = e * 9 + j;
            if (c & 1) { rwh[c >> 1] |= (unsigned)h << 16; rwl[c >> 1] |= (unsigned)l2 << 16; }
            else       { rwh[c >> 1] |= h;                  rwl[c >> 1] |= l2; }
        }
    }
    unsigned* ubh = (unsigned*)AL;
    unsigned* ubl = (unsigned*)AL + 2560;
#pragma unroll
    for (int w = 0; w < 9; ++w) {
        ubh[pl * 40 + cg * 9 + w] = rwh[w];
        ubl[pl * 40 + cg * 9 + w] = rwl[w];
    }
    if (cg == 3) {
#pragma unroll
        for (int w = 0; w < 4; ++w) { ubh[pl * 40 + 36 + w] = 0u; ubl[pl * 40 + 36 + w] = 0u; }
    }
    __syncthreads();
    size_t base = ((size_t)b * 256 + strip * 64) * 80;
    const ushort* sbh = (const ushort*)ubh;
    const ushort* sbl = (const ushort*)ubl;
#pragma unroll
    for (int e = 0; e < 3; ++e) {
        int q = e * 256 + tid;
        if (q < 640) {
            *(uint4*)(Oh + base + q * 8) = *(const uint4*)(sbh + q * 8);
            *(uint4*)(Ol + base + q * 8) = *(const uint4*)(sbl + q * 8);
        }
    }
}

// ---------------------------------------------------------------------------
// conv34_part: split-K MFMA partial, z = dh-group (3); cin-phases looped.
// ---------------------------------------------------------------------------
template <int NPH, int NCO>
__global__ __launch_bounds__(256) void conv34_part(
    const ushort* __restrict__ Agh, const ushort* __restrict__ Agl,
    const ushort* __restrict__ Bgh, const ushort* __restrict__ Bgl,
    const ushort* __restrict__ zph, const ushort* __restrict__ zpl,
    float* __restrict__ P) {
    __shared__ ushort AH[144 * AST];
    __shared__ ushort AL[144 * AST];
    const int tid = threadIdx.x;
    const int b = blockIdx.x, half = blockIdx.y, g = blockIdx.z;
    const int r0 = half * 8;
    const int lane = tid & 63, wv = tid >> 6;

    f32x16 acc;
#pragma unroll
    for (int i = 0; i < 16; ++i) acc[i] = 0.f;

    const int m = wv * 32 + (lane & 31);
    const int sbase = (m >> 4) * 18 + (m & 15);
    const int koff = (lane >> 5) * 8;

#pragma unroll 1
    for (int p = 0; p < NPH; ++p) {
        if (p) __syncthreads();
        const ushort* ash = Agh + ((size_t)b * NPH + p) * 256 * 80;
        const ushort* asl = Agl + ((size_t)b * NPH + p) * 256 * 80;
#pragma unroll
        for (int e = 0; e < 6; ++e) {
            int idx = e * 256 + tid;
            if (idx < 1440) {
                int px = idx / 10, ch = idx - px * 10;
                int pr = px / 18, pc = px - pr * 18;
                int r = r0 - 1 + g + pr, c = pc - 1;
                bool inb = ((unsigned)r < 16u) && ((unsigned)c < 16u);
                uint4 vh, vl;
                if (inb) {
                    vh = *(const uint4*)(ash + (size_t)(r * 16 + c) * 80 + ch * 8);
                    vl = *(const uint4*)(asl + (size_t)(r * 16 + c) * 80 + ch * 8);
                } else {
                    vh = *(const uint4*)(zph + ch * 8);
                    vl = *(const uint4*)(zpl + ch * 8);
                }
                *(uint4*)(&AH[px * AST + ch * 8]) = vh;
                *(uint4*)(&AL[px * AST + ch * 8]) = vl;
            }
        }
        __syncthreads();

        const ushort* bsh = Bgh + (size_t)p * 2880 * 8;
        const ushort* bsl = Bgl + (size_t)p * 2880 * 8;
#pragma unroll
        for (int dw = 0; dw < 3; ++dw) {
            const int t = g * 3 + dw;
#pragma unroll
            for (int s = 0; s < 5; ++s) {
                bf16x8 ah = *(const bf16x8*)(&AH[(sbase + dw) * AST + s * 16 + koff]);
                bf16x8 al = *(const bf16x8*)(&AL[(sbase + dw) * AST + s * 16 + koff]);
                bf16x8 bh = *(const bf16x8*)(bsh + (size_t)((t * 5 + s) * 64 + lane) * 8);
                bf16x8 bl = *(const bf16x8*)(bsl + (size_t)((t * 5 + s) * 64 + lane) * 8);
                acc = __builtin_amdgcn_mfma_f32_32x32x16_bf16(ah, bh, acc, 0, 0, 0);
                acc = __builtin_amdgcn_mfma_f32_32x32x16_bf16(ah, bl, acc, 0, 0, 0);
                acc = __builtin_amdgcn_mfma_f32_32x32x16_bf16(al, bh, acc, 0, 0, 0);
            }
        }
    }

    int co = lane & 31;
    if (co < NCO) {
        float* pb = P + ((size_t)(g * 256 + b * 2 + half) * 128) * NCO;
#pragma unroll
        for (int r = 0; r < 16; ++r) {
            int px = wv * 32 + (r & 3) + 8 * (r >> 2) + 4 * (lane >> 5);
            pb[px * NCO + co] = acc[r];
        }
    }
}

// ---------------------------------------------------------------------------
// conv3_reduce v3: block = (b, px-quarter), all 16 couts, 64 px.
// ---------------------------------------------------------------------------
__global__ __launch_bounds__(256) void conv3_reduce(const float* __restrict__ P3,
                                                    ushort* __restrict__ A4h,
                                                    ushort* __restrict__ A4l) {
    __shared__ ushort SBH[2][64 * 80];
    __shared__ ushort SBL[2][64 * 80];
    int b = blockIdx.x, pxq = blockIdx.y;
    int t = threadIdx.x;
    int co = t & 15, pxg = t >> 4;
#pragma unroll
    for (int q = 0; q < 4; ++q) {
        int lpx64 = pxg * 4 + q;
        int px = pxq * 64 + lpx64;
        int bh = b * 2 + (px >> 7), lpx = px & 127;
        float s = 0.f;
#pragma unroll
        for (int zz = 0; zz < 3; ++zz)
            s += P3[((size_t)(zz * 256 + bh) * 128 + lpx) * 16 + co];
        float a9[9];
        spline_acts(s, a9);
        int ph = co >> 3, c8 = co & 7;
#pragma unroll
        for (int j = 0; j < 9; ++j) {
            ushort h, l2; bf16split(a9[j], h, l2);
            SBH[ph][lpx64 * 80 + c8 * 9 + j] = h;
            SBL[ph][lpx64 * 80 + c8 * 9 + j] = l2;
        }
        if (c8 == 7) {
#pragma unroll
            for (int w = 0; w < 8; ++w) {
                SBH[ph][lpx64 * 80 + 72 + w] = 0;
                SBL[ph][lpx64 * 80 + 72 + w] = 0;
            }
        }
    }
    __syncthreads();
#pragma unroll
    for (int ph = 0; ph < 2; ++ph) {
        size_t base = ((size_t)(b * 2 + ph) * 256 + pxq * 64) * 80;
#pragma unroll
        for (int e = 0; e < 3; ++e) {
            int q = e * 256 + t;
            if (q < 640) {
                *(uint4*)(A4h + base + q * 8) = *(const uint4*)(&SBH[ph][q * 8]);
                *(uint4*)(A4l + base + q * 8) = *(const uint4*)(&SBL[ph][q * 8]);
            }
        }
    }
}

// ---------------------------------------------------------------------------
// conv4_reduce_pool v2: block = (b, half); sum 3 partials + 2x2 pool.
// ---------------------------------------------------------------------------
__global__ __launch_bounds__(256) void conv4_reduce_pool(const float* __restrict__ P4,
                                                         float* __restrict__ pooled) {
    __shared__ float SM[32 * 33];
    int b = blockIdx.x, half = blockIdx.y;
    int t = threadIdx.x;
    int co = t & 31, pg = t >> 5;
    int bh = b * 2 + half;
#pragma unroll
    for (int q = 0; q < 4; ++q) {
        int pp = pg * 4 + q;
        int lr = pp >> 3, pc = pp & 7;
        int px00 = (2 * lr) * 16 + 2 * pc;
        float s00 = 0.f, s01 = 0.f, s10 = 0.f, s11 = 0.f;
#pragma unroll
        for (int zz = 0; zz < 3; ++zz) {
            const float* pb = P4 + ((size_t)(zz * 256 + bh) * 128) * 32 + co;
            s00 += pb[(size_t)px00 * 32];
            s01 += pb[(size_t)(px00 + 1) * 32];
            s10 += pb[(size_t)(px00 + 16) * 32];
            s11 += pb[(size_t)(px00 + 17) * 32];
        }
        SM[co * 33 + pp] = fmaxf(fmaxf(s00, s01), fmaxf(s10, s11));
    }
    __syncthreads();
#pragma unroll
    for (int e = 0; e < 4; ++e) {
        int idx = e * 256 + t;
        int co2 = idx >> 5, pp2 = idx & 31;
        int lr2 = pp2 >> 3, pc2 = pp2 & 7;
        pooled[(size_t)b * 2048 + co2 * 64 + (half * 4 + lr2) * 8 + pc2] = SM[co2 * 33 + pp2];
    }
}

// ---------------------------------------------------------------------------
// fc_big: 64x64 tile, 4x4/thread, K_TILE=32, split-K; float4 global staging.
// ---------------------------------------------------------------------------
template <int SPLIT>
__global__ __launch_bounds__(256) void fc_big(const float* __restrict__ A,
                                              const float* __restrict__ Wt,
                                              float* __restrict__ part,
                                              int M, int N, int K) {
    __shared__ float As[32][68];
    __shared__ float Ws[32][68];
    const int tid = threadIdx.x;
    const int tx = tid & 15, ty = tid >> 4;
    const int bm = blockIdx.y * 64, bn = blockIdx.x * 64;
    const int kc = K / SPLIT;
    const int kbeg = blockIdx.z * kc;
    float acc[4][4] = {};
    for (int k0 = kbeg; k0 < kbeg + kc; k0 += 32) {
#pragma unroll
        for (int e = 0; e < 2; ++e) {
            int q = e * 256 + tid;
            int r = q >> 3, k4 = (q & 7) * 4;
            float4 av = *(const float4*)&A[(size_t)(bm + r) * K + k0 + k4];
            float4 wv = *(const float4*)&Wt[(size_t)(bn + r) * K + k0 + k4];
            As[k4 + 0][r] = av.x; As[k4 + 1][r] = av.y;
            As[k4 + 2][r] = av.z; As[k4 + 3][r] = av.w;
            Ws[k4 + 0][r] = wv.x; Ws[k4 + 1][r] = wv.y;
            Ws[k4 + 2][r] = wv.z; Ws[k4 + 3][r] = wv.w;
        }
        __syncthreads();
#pragma unroll
        for (int kk = 0; kk < 32; ++kk) {
            float4 av = *(const float4*)(&As[kk][ty * 4]);
            float4 wv = *(const float4*)(&Ws[kk][tx * 4]);
            acc[0][0] = fmaf(av.x, wv.x, acc[0][0]);
            acc[0][1] = fmaf(av.x, wv.y, acc[0][1]);
            acc[0][2] = fmaf(av.x, wv.z, acc[0][2]);
            acc[0][3] = fmaf(av.x, wv.w, acc[0][3]);
            acc[1][0] = fmaf(av.y, wv.x, acc[1][0]);
            acc[1][1] = fmaf(av.y, wv.y, acc[1][1]);
            acc[1][2] = fmaf(av.y, wv.z, acc[1][2]);
            acc[1][3] = fmaf(av.y, wv.w, acc[1][3]);
            acc[2][0] = fmaf(av.z, wv.x, acc[2][0]);
            acc[2][1] = fmaf(av.z, wv.y, acc[2][1]);
            acc[2][2] = fmaf(av.z, wv.z, acc[2][2]);
            acc[2][3] = fmaf(av.z, wv.w, acc[2][3]);
            acc[3][0] = fmaf(av.w, wv.x, acc[3][0]);
            acc[3][1] = fmaf(av.w, wv.y, acc[3][1]);
            acc[3][2] = fmaf(av.w, wv.z, acc[3][2]);
            acc[3][3] = fmaf(av.w, wv.w, acc[3][3]);
        }
        __syncthreads();
    }
    float* p = part + (size_t)blockIdx.z * M * N;
#pragma unroll
    for (int i = 0; i < 4; ++i) {
        float4 v = make_float4(acc[i][0], acc[i][1], acc[i][2], acc[i][3]);
        *(float4*)&p[(size_t)(bm + ty * 4 + i) * N + (bn + tx * 4)] = v;
    }
}

template <int SPLIT>
__global__ void fc_reduce(const float* __restrict__ part, const float* __restrict__ bias,
                          float* __restrict__ C, int MN, int N, int relu) {
    int i = blockIdx.x * 256 + threadIdx.x;
    if (i >= MN) return;
    float s = bias[i % N];
#pragma unroll
    for (int z = 0; z < SPLIT; ++z) s += part[(size_t)z * MN + i];
    C[i] = relu ? fmaxf(s, 0.f) : s;
}

__global__ __launch_bounds__(256) void fc3_kernel(const float* __restrict__ A,
                                                  const float* __restrict__ Wt,
                                                  const float* __restrict__ bias,
                                                  float* __restrict__ C) {
    int gid = blockIdx.x * 256 + threadIdx.x;
    int wid = gid >> 6;
    int lane = gid & 63;
    int m = wid / 10, n = wid - m * 10;
    const float4* a = (const float4*)(A + (size_t)m * 1024);
    const float4* w = (const float4*)(Wt + (size_t)n * 1024);
    float s = 0.f;
#pragma unroll
    for (int it = 0; it < 4; ++it) {
        float4 av = a[it * 64 + lane];
        float4 wv = w[it * 64 + lane];
        s += av.x * wv.x + av.y * wv.y + av.z * wv.z + av.w * wv.w;
    }
#pragma unroll
    for (int off = 32; off; off >>= 1) s += __shfl_xor(s, off);
    if (lane == 0) C[wid] = s + bias[n];
}

// ---------------------------------------------------------------------------
extern "C" void kernel_launch(void* const* d_in, const int* in_sizes, int n_in,
                              void* d_out, int out_size, void* d_ws, size_t ws_size,
                              hipStream_t stream) {
    const float* x   = (const float*)d_in[0];
    const float* bw1 = (const float*)d_in[1];
    const float* sw1 = (const float*)d_in[2];
    const float* sc1 = (const float*)d_in[3];
    const float* bw2 = (const float*)d_in[4];
    const float* sw2 = (const float*)d_in[5];
    const float* sc2 = (const float*)d_in[6];
    const float* bw3 = (const float*)d_in[7];
    const float* sw3 = (const float*)d_in[8];
    const float* sc3 = (const float*)d_in[9];
    const float* bw4 = (const float*)d_in[10];
    const float* sw4 = (const float*)d_in[11];
    const float* sc4 = (const float*)d_in[12];
    const float* w1  = (const float*)d_in[13];
    const float* b1  = (const float*)d_in[14];
    const float* w2  = (const float*)d_in[15];
    const float* b2  = (const float*)d_in[16];
    const float* w3  = (const float*)d_in[17];
    const float* b3  = (const float*)d_in[18];

    float*  wsf = (float*)d_ws;
    ushort* wsu = (ushort*)d_ws;
    ushort* k1h = wsu + 110848;
    ushort* k1l = wsu + 120064;
    ushort* k2h = wsu + 129280;
    ushort* k2l = wsu + 143104;
    ushort* k3h = wsu + 156928;
    ushort* k3l = wsu + 179968;
    ushort* k4h = wsu + 203008;
    ushort* k4l = wsu + 249088;
    ushort* zph = wsu + 295168;
    ushort* zpl = wsu + 295248;
    ushort* A2h = wsu + 7864320;    // (B,1024,36)
    ushort* A2l = wsu + 12582912;
    ushort* A3h = wsu + 524288;     // (B,256,80)
    ushort* A3l = wsu + 3145728;
    ushort* A4h = wsu + 5767168;    // (B,2,256,80)
    ushort* A4l = wsu + 11010048;
    float* P3   = wsf + 9437184;    // 3x256x128x16 fp32
    float* P4   = wsf + 11534336;   // 3x256x128x32 fp32
    float* pooled = wsf + 262144;
    float* part1  = wsf + 524288;
    float* fc1o   = wsf + 2621440;
    float* part2  = wsf + 2883584;
    float* fc2o   = wsf + 3932160;

    prep_kernel<<<46, 256, 0, stream>>>(bw1, sw1, sc1, bw2, sw2, sc2,
                                        bw3, sw3, sc3, bw4, sw4, sc4,
                                        k1h, k1l, k2h, k2l, k3h, k3l, k4h, k4l,
                                        zph, zpl);

    conv1_fused<<<512, 256, 0, stream>>>(x, k1h, k1l, A2h, A2l);
    conv2_strip<36, 9, 12, 56, 3, 8><<<512, 256, 0, stream>>>(A2h, A2l, k2h, k2l,
                                                              zph, zpl, A3h, A3l);
    conv34_part<1, 16><<<dim3(128, 2, 3), 256, 0, stream>>>(A3h, A3l, k3h, k3l,
                                                            zph, zpl, P3);
    conv3_reduce<<<dim3(128, 4), 256, 0, stream>>>(P3, A4h, A4l);
    conv34_part<2, 32><<<dim3(128, 2, 3), 256, 0, stream>>>(A4h, A4l, k4h, k4l,
                                                            zph, zpl, P4);
    conv4_reduce_pool<<<dim3(128, 2), 256, 0, stream>>>(P4, pooled);

    fc_big<8><<<dim3(32, 2, 8), 256, 0, stream>>>(pooled, w1, part1, 128, 2048, 2048);
    fc_reduce<8><<<1024, 256, 0, stream>>>(part1, b1, fc1o, 262144, 2048, 1);
    fc_big<8><<<dim3(16, 2, 8), 256, 0, stream>>>(fc1o, w2, part2, 128, 1024, 2048);
    fc_reduce<8><<<512, 256, 0, stream>>>(part2, b2, fc2o, 131072, 1024, 1);
    fc3_kernel<<<320, 256, 0, stream>>>(fc2o, w3, b3, (float*)d_out);
}

// Round 18
// 129.299 us; speedup vs baseline: 1.3822x; 1.0108x over previous
//
#include <hip/hip_runtime.h>
#include <hip/hip_bf16.h>

#define BATCH 128
#define AST 88  // conv34 padded-A LDS row stride in ushorts (176B, 16B-aligned)

typedef __attribute__((ext_vector_type(8))) short bf16x8;
typedef __attribute__((ext_vector_type(16))) float f32x16;

// ---------------------------------------------------------------------------
// Spline activation: act[0] = silu(x), act[1..8] = cubic B-spline bases
// ---------------------------------------------------------------------------
__device__ __forceinline__ void spline_acts(float xv, float act[9]) {
    act[0] = xv * (1.0f / (1.0f + __expf(-xv)));  // silu
    float g[12];
#pragma unroll
    for (int i = 0; i < 12; ++i) g[i] = (float)(i - 3) * 0.4f - 1.0f;
    float bb[11];
#pragma unroll
    for (int c = 0; c < 11; ++c) bb[c] = (xv >= g[c] && xv < g[c + 1]) ? 1.0f : 0.0f;
#pragma unroll
    for (int k = 1; k <= 3; ++k) {
#pragma unroll
        for (int c = 0; c + k < 11; ++c) {
            float left  = (xv - g[c]) * (1.0f / (g[c + k] - g[c])) * bb[c];
            float right = (g[c + k + 1] - xv) * (1.0f / (g[c + k + 1] - g[c + 1])) * bb[c + 1];
            bb[c] = left + right;
        }
    }
#pragma unroll
    for (int c = 0; c < 8; ++c) act[c + 1] = bb[c];
}

__device__ __constant__ float ZPAD[9] = {0.0f, 0.0f, 0.0f, 0.02083333333f,
                                         0.47916666667f, 0.47916666667f,
                                         0.02083333333f, 0.0f, 0.0f};

// bf16 hi/lo split via HW RNE converts
__device__ __forceinline__ void bf16split(float x, ushort& h, ushort& l) {
    __hip_bfloat16 bh = __float2bfloat16(x);
    float hf = __bfloat162float(bh);
    __hip_bfloat16 bl = __float2bfloat16(x - hf);
    h = *(ushort*)&bh;
    l = *(ushort*)&bl;
}

// packed conv weight value: f = cin*9 + tap, j = spline idx
__device__ __forceinline__ float wval(const float* bw, const float* sw, const float* sc,
                                      int F, int f, int j, int o) {
    if (j == 0) return bw[o * F + f];
    return sw[(o * F + f) * 8 + (j - 1)] * sc[o * F + f];
}

// ---------------------------------------------------------------------------
// prep: pack MFMA B-fragments (bf16 hi/lo) for all 4 conv layers + zp pattern.
// ---------------------------------------------------------------------------
__global__ __launch_bounds__(256) void prep_kernel(
    const float* __restrict__ bw1, const float* __restrict__ sw1, const float* __restrict__ sc1,
    const float* __restrict__ bw2, const float* __restrict__ sw2, const float* __restrict__ sc2,
    const float* __restrict__ bw3, const float* __restrict__ sw3, const float* __restrict__ sc3,
    const float* __restrict__ bw4, const float* __restrict__ sw4, const float* __restrict__ sc4,
    ushort* __restrict__ k1h, ushort* __restrict__ k1l,
    ushort* __restrict__ k2h, ushort* __restrict__ k2l,
    ushort* __restrict__ k3h, ushort* __restrict__ k3l,
    ushort* __restrict__ k4h, ushort* __restrict__ k4l,
    ushort* __restrict__ zph, ushort* __restrict__ zpl) {
    int i = blockIdx.x * 256 + threadIdx.x;
    if (i < 1152) {                            // conv1
        int l = i & 63, s = (i >> 6) & 1, t = i / 128;
#pragma unroll
        for (int e = 0; e < 8; ++e) {
            int k = s * 16 + ((l >> 5) * 8) + e, o = l & 31;
            float w = 0.f;
            if (k < 27 && o < 4) w = wval(bw1, sw1, sc1, 27, (k / 9) * 9 + t, k % 9, o);
            ushort h, lo; bf16split(w, h, lo);
            k1h[i * 8 + e] = h; k1l[i * 8 + e] = lo;
        }
    } else if (i < 2880) {                     // conv2
        int q = i - 1152;
        int l = q & 63, s = (q >> 6) % 3, t = q / 192;
#pragma unroll
        for (int e = 0; e < 8; ++e) {
            int k = s * 16 + ((l >> 5) * 8) + e, o = l & 31;
            float w = 0.f;
            if (k < 36 && o < 8) w = wval(bw2, sw2, sc2, 36, (k / 9) * 9 + t, k % 9, o);
            ushort h, lo; bf16split(w, h, lo);
            k2h[q * 8 + e] = h; k2l[q * 8 + e] = lo;
        }
    } else if (i < 5760) {                     // conv3
        int q = i - 2880;
        int l = q & 63, s = (q >> 6) % 5, t = q / 320;
#pragma unroll
        for (int e = 0; e < 8; ++e) {
            int k = s * 16 + ((l >> 5) * 8) + e, o = l & 31;
            float w = 0.f;
            if (k < 72 && o < 16) w = wval(bw3, sw3, sc3, 72, (k / 9) * 9 + t, k % 9, o);
            ushort h, lo; bf16split(w, h, lo);
            k3h[q * 8 + e] = h; k3l[q * 8 + e] = lo;
        }
    } else if (i < 11520) {                    // conv4
        int q = i - 5760;
        int l = q & 63, s = (q >> 6) % 5, t = (q / 320) % 9, p = q / 2880;
#pragma unroll
        for (int e = 0; e < 8; ++e) {
            int k = s * 16 + ((l >> 5) * 8) + e, o = l & 31;
            float w = 0.f;
            if (k < 72) w = wval(bw4, sw4, sc4, 144, (p * 8 + k / 9) * 9 + t, k % 9, o);
            ushort h, lo; bf16split(w, h, lo);
            k4h[q * 8 + e] = h; k4l[q * 8 + e] = lo;
        }
    } else if (i < 11600) {
        int c = i - 11520;
        ushort h, lo; bf16split(ZPAD[c % 9], h, lo);
        zph[c] = h; zpl[c] = lo;
    }
}

// ---------------------------------------------------------------------------
// conv1_fused v4: 4-row strips (grid 1024), ASTR=40 (measured conflict-free),
// linear addressing. raw x -> inline spline -> MFMA -> spline -> A2.
// LDS 2 x 204 x 40 x 2B = 31.9KB -> 4 blocks/CU.
// ---------------------------------------------------------------------------
__global__ __launch_bounds__(256) void conv1_fused(
    const float* __restrict__ x,
    const ushort* __restrict__ Bgh, const ushort* __restrict__ Bgl,
    ushort* __restrict__ Oh, ushort* __restrict__ Ol) {
    constexpr int ASTR = 40, KSTEPS = 2, NCO = 4;
    __shared__ ushort AH[204 * ASTR];  // 16320 B
    __shared__ ushort AL[204 * ASTR];
    const int tid = threadIdx.x;
    const int b = blockIdx.x >> 3, strip = blockIdx.x & 7;
    const int r0 = strip * 4;
    const int lane = tid & 63, wv = tid >> 6;

    // stage 6 rows x 34 padded cols = 204 slots (linear, word stores)
    for (int px = tid; px < 204; px += 256) {
        int lr = px / 34, pc = px - lr * 34;
        int grow = r0 - 1 + lr, gc = pc - 1;
        bool inb = ((unsigned)grow < 32u) && ((unsigned)gc < 32u);
        unsigned rh[16], rl[16];
#pragma unroll
        for (int w = 0; w < 16; ++w) { rh[w] = 0u; rl[w] = 0u; }
        if (inb) {
            const float* xb = x + (size_t)b * 3072 + grow * 32 + gc;
#pragma unroll
            for (int cin = 0; cin < 3; ++cin) {
                float a9[9];
                spline_acts(xb[cin * 1024], a9);
#pragma unroll
                for (int j = 0; j < 9; ++j) {
                    ushort h, l2; bf16split(a9[j], h, l2);
                    int c = cin * 9 + j;
                    if (c & 1) { rh[c >> 1] |= (unsigned)h << 16; rl[c >> 1] |= (unsigned)l2 << 16; }
                    else       { rh[c >> 1] |= h;                  rl[c >> 1] |= l2; }
                }
            }
        } else {
#pragma unroll
            for (int c = 0; c < 27; ++c) {
                ushort h, l2; bf16split(ZPAD[c % 9], h, l2);
                if (c & 1) { rh[c >> 1] |= (unsigned)h << 16; rl[c >> 1] |= (unsigned)l2 << 16; }
                else       { rh[c >> 1] |= h;                  rl[c >> 1] |= l2; }
            }
        }
        unsigned* dh = (unsigned*)&AH[px * ASTR];
        unsigned* dl = (unsigned*)&AL[px * ASTR];
#pragma unroll
        for (int w = 0; w < 16; ++w) { dh[w] = rh[w]; dl[w] = rl[w]; }
    }
    __syncthreads();

    f32x16 acc;
#pragma unroll
    for (int i = 0; i < 16; ++i) acc[i] = 0.f;

    const int p0 = wv * 32 + (lane & 31);                 // local px 0..127
    const int sp0 = ((p0 >> 5) + 1) * 34 + (p0 & 31) + 1; // staged slot
    const int koff = (lane >> 5) * 8;

#pragma unroll 1
    for (int t = 0; t < 9; ++t) {
        const int dA = ((t / 3) - 1) * 34 + (t % 3) - 1;
#pragma unroll
        for (int s = 0; s < KSTEPS; ++s) {
            bf16x8 ah = *(const bf16x8*)(&AH[(sp0 + dA) * ASTR + s * 16 + koff]);
            bf16x8 al = *(const bf16x8*)(&AL[(sp0 + dA) * ASTR + s * 16 + koff]);
            bf16x8 bh = *(const bf16x8*)(Bgh + (size_t)((t * KSTEPS + s) * 64 + lane) * 8);
            bf16x8 bl = *(const bf16x8*)(Bgl + (size_t)((t * KSTEPS + s) * 64 + lane) * 8);
            acc = __builtin_amdgcn_mfma_f32_32x32x16_bf16(ah, bh, acc, 0, 0, 0);
            acc = __builtin_amdgcn_mfma_f32_32x32x16_bf16(ah, bl, acc, 0, 0, 0);
            acc = __builtin_amdgcn_mfma_f32_32x32x16_bf16(al, bh, acc, 0, 0, 0);
        }
    }
    __syncthreads();

    // transpose acc -> LDS fp32 [NCO][129] at start of AH
    float* fl = (float*)AH;
    {
        int ccol = lane & 31;
        if (ccol < NCO) {
#pragma unroll
            for (int r = 0; r < 16; ++r) {
                int row = (r & 3) + 8 * (r >> 2) + 4 * (lane >> 5);
                fl[ccol * 129 + wv * 32 + row] = acc[r];
            }
        }
    }
    __syncthreads();

    // spline epilogue: 128 px x 4 couts; thread = (px, cout-pair)
    unsigned* ubh = (unsigned*)AL;           // 2304 words (AL = 4080 words)
    unsigned* ubl = (unsigned*)AH + 1032;    // fl = 516 words; 1032+2304=3336 <= 4080
    {
        int px = tid >> 1, cop = tid & 1;
        unsigned rwh[9], rwl[9];
#pragma unroll
        for (int w = 0; w < 9; ++w) { rwh[w] = 0u; rwl[w] = 0u; }
#pragma unroll
        for (int e = 0; e < 2; ++e) {
            int co = cop * 2 + e;
            float a9[9];
            spline_acts(fl[co * 129 + px], a9);
#pragma unroll
            for (int j = 0; j < 9; ++j) {
                ushort h, l2; bf16split(a9[j], h, l2);
                int c = e * 9 + j;
                if (c & 1) { rwh[c >> 1] |= (unsigned)h << 16; rwl[c >> 1] |= (unsigned)l2 << 16; }
                else       { rwh[c >> 1] |= h;                  rwl[c >> 1] |= l2; }
            }
        }
#pragma unroll
        for (int w = 0; w < 9; ++w) {
            ubh[px * 18 + cop * 9 + w] = rwh[w];
            ubl[px * 18 + cop * 9 + w] = rwl[w];
        }
    }
    __syncthreads();
    size_t basew = ((size_t)b * 1024 + strip * 128) * 18;
    unsigned* goh = (unsigned*)Oh + basew;
    unsigned* gol = (unsigned*)Ol + basew;
#pragma unroll
    for (int e = 0; e < 9; ++e) {
        int q = e * 256 + tid;  // 2304 words
        goh[q] = ubh[q];
        gol[q] = ubl[q];
    }
}

// ---------------------------------------------------------------------------
// conv2_strip (32x32, pool+spline epilogue) — verified structure (ASTR=56).
// ---------------------------------------------------------------------------
template <int KG, int CHG, int CHL, int ASTR, int KSTEPS, int NCO>
__global__ __launch_bounds__(256) void conv2_strip(
    const ushort* __restrict__ Agh, const ushort* __restrict__ Agl,
    const ushort* __restrict__ Bgh, const ushort* __restrict__ Bgl,
    const ushort* __restrict__ zph, const ushort* __restrict__ zpl,
    ushort* __restrict__ Oh, ushort* __restrict__ Ol) {
    __shared__ ushort AH[340 * ASTR];
    __shared__ ushort AL[340 * ASTR];
    const int tid = threadIdx.x;
    const int b = blockIdx.x >> 2, strip = blockIdx.x & 3;
    const int r0 = strip * 8;
    const int lane = tid & 63, wv = tid >> 6;

    {
        const ushort* ash = Agh + (size_t)b * 1024 * KG;
        const ushort* asl = Agl + (size_t)b * 1024 * KG;
        for (int idx = tid; idx < 320 * CHL; idx += 256) {
            int pxl = idx / CHL, ch = idx - pxl * CHL;
            int lr = pxl >> 5, c = pxl & 31;
            int grow = r0 - 1 + lr;
            uint2 vh, vl;
            if (ch >= CHG) { vh = make_uint2(0u, 0u); vl = make_uint2(0u, 0u); }
            else if ((unsigned)grow < 32u) {
                vh = *(const uint2*)(ash + (size_t)(grow * 32 + c) * KG + ch * 4);
                vl = *(const uint2*)(asl + (size_t)(grow * 32 + c) * KG + ch * 4);
            } else {
                vh = *(const uint2*)(zph + ch * 4);
                vl = *(const uint2*)(zpl + ch * 4);
            }
            int spx = lr * 34 + c + 1;
            *(uint2*)(&AH[spx * ASTR + ch * 4]) = vh;
            *(uint2*)(&AL[spx * ASTR + ch * 4]) = vl;
        }
        for (int idx = tid; idx < 20 * CHL; idx += 256) {
            int sel = idx / CHL, ch = idx - sel * CHL;
            int lr = sel >> 1, c = (sel & 1) ? 33 : 0;
            int spx = lr * 34 + c;
            uint2 vh, vl;
            if (ch >= CHG) { vh = make_uint2(0u, 0u); vl = make_uint2(0u, 0u); }
            else { vh = *(const uint2*)(zph + ch * 4); vl = *(const uint2*)(zpl + ch * 4); }
            *(uint2*)(&AH[spx * ASTR + ch * 4]) = vh;
            *(uint2*)(&AL[spx * ASTR + ch * 4]) = vl;
        }
    }
    __syncthreads();

    f32x16 acc0, acc1;
#pragma unroll
    for (int i = 0; i < 16; ++i) { acc0[i] = 0.f; acc1[i] = 0.f; }

    const int p0 = wv * 64 + (lane & 31);
    const int sp0 = ((p0 >> 5) + 1) * 34 + (p0 & 31) + 1;
    const int sp1 = sp0 + 34;
    const int koff = (lane >> 5) * 8;

#pragma unroll 1
    for (int t = 0; t < 9; ++t) {
        const int dA = ((t / 3) - 1) * 34 + (t % 3) - 1;
#pragma unroll
        for (int s = 0; s < KSTEPS; ++s) {
            bf16x8 a0h = *(const bf16x8*)(&AH[(sp0 + dA) * ASTR + s * 16 + koff]);
            bf16x8 a0l = *(const bf16x8*)(&AL[(sp0 + dA) * ASTR + s * 16 + koff]);
            bf16x8 a1h = *(const bf16x8*)(&AH[(sp1 + dA) * ASTR + s * 16 + koff]);
            bf16x8 a1l = *(const bf16x8*)(&AL[(sp1 + dA) * ASTR + s * 16 + koff]);
            bf16x8 bh = *(const bf16x8*)(Bgh + (size_t)((t * KSTEPS + s) * 64 + lane) * 8);
            bf16x8 bl = *(const bf16x8*)(Bgl + (size_t)((t * KSTEPS + s) * 64 + lane) * 8);
            acc0 = __builtin_amdgcn_mfma_f32_32x32x16_bf16(a0h, bh, acc0, 0, 0, 0);
            acc1 = __builtin_amdgcn_mfma_f32_32x32x16_bf16(a1h, bh, acc1, 0, 0, 0);
            acc0 = __builtin_amdgcn_mfma_f32_32x32x16_bf16(a0h, bl, acc0, 0, 0, 0);
            acc1 = __builtin_amdgcn_mfma_f32_32x32x16_bf16(a1h, bl, acc1, 0, 0, 0);
            acc0 = __builtin_amdgcn_mfma_f32_32x32x16_bf16(a0l, bh, acc0, 0, 0, 0);
            acc1 = __builtin_amdgcn_mfma_f32_32x32x16_bf16(a1l, bh, acc1, 0, 0, 0);
        }
    }
    __syncthreads();

    float* fl = (float*)AH;
    {
        int ccol = lane & 31;
        if (ccol < NCO) {
#pragma unroll
            for (int r = 0; r < 16; ++r) {
                int row = (r & 3) + 8 * (r >> 2) + 4 * (lane >> 5);
                fl[ccol * 257 + wv * 64 + row] = acc0[r];
                fl[ccol * 257 + wv * 64 + 32 + row] = acc1[r];
            }
        }
    }
    __syncthreads();

    int cg = tid >> 6, pl = tid & 63;
    int phl = pl >> 4, pw = pl & 15;
    int base_m = (2 * phl) * 32 + 2 * pw;
    unsigned rwh[9], rwl[9];
#pragma unroll
    for (int w = 0; w < 9; ++w) { rwh[w] = 0u; rwl[w] = 0u; }
#pragma unroll
    for (int e = 0; e < 2; ++e) {
        int co = cg * 2 + e;
        const float* fb = fl + co * 257 + base_m;
        float m = fmaxf(fmaxf(fb[0], fb[1]), fmaxf(fb[32], fb[33]));
        float a9[9];
        spline_acts(m, a9);
#pragma unroll
        for (int j = 0; j < 9; ++j) {
            ushort h, l2; bf16split(a9[j], h, l2);
            int c = e * 9 + j;
            if (c & 1) { rwh[c >> 1] |= (unsigned)h << 16; rwl[c >> 1] |= (unsigned)l2 << 16; }
            else       { rwh[c >> 1] |= h;                  rwl[c >> 1] |= l2; }
        }
    }
    unsigned* ubh = (unsigned*)AL;
    unsigned* ubl = (unsigned*)AL + 2560;
#pragma unroll
    for (int w = 0; w < 9; ++w) {
        ubh[pl * 40 + cg * 9 + w] = rwh[w];
        ubl[pl * 40 + cg * 9 + w] = rwl[w];
    }
    if (cg == 3) {
#pragma unroll
        for (int w = 0; w < 4; ++w) { ubh[pl * 40 + 36 + w] = 0u; ubl[pl * 40 + 36 + w] = 0u; }
    }
    __syncthreads();
    size_t base = ((size_t)b * 256 + strip * 64) * 80;
    const ushort* sbh = (const ushort*)ubh;
    const ushort* sbl = (const ushort*)ubl;
#pragma unroll
    for (int e = 0; e < 3; ++e) {
        int q = e * 256 + tid;
        if (q < 640) {
            *(uint4*)(Oh + base + q * 8) = *(const uint4*)(sbh + q * 8);
            *(uint4*)(Ol + base + q * 8) = *(const uint4*)(sbl + q * 8);
        }
    }
}

// ---------------------------------------------------------------------------
// conv34_part: split-K MFMA partial, z = dh-group (3); cin-phases looped.
// ---------------------------------------------------------------------------
template <int NPH, int NCO>
__global__ __launch_bounds__(256) void conv34_part(
    const ushort* __restrict__ Agh, const ushort* __restrict__ Agl,
    const ushort* __restrict__ Bgh, const ushort* __restrict__ Bgl,
    const ushort* __restrict__ zph, const ushort* __restrict__ zpl,
    float* __restrict__ P) {
    __shared__ ushort AH[144 * AST];
    __shared__ ushort AL[144 * AST];
    const int tid = threadIdx.x;
    const int b = blockIdx.x, half = blockIdx.y, g = blockIdx.z;
    const int r0 = half * 8;
    const int lane = tid & 63, wv = tid >> 6;

    f32x16 acc;
#pragma unroll
    for (int i = 0; i < 16; ++i) acc[i] = 0.f;

    const int m = wv * 32 + (lane & 31);
    const int sbase = (m >> 4) * 18 + (m & 15);
    const int koff = (lane >> 5) * 8;

#pragma unroll 1
    for (int p = 0; p < NPH; ++p) {
        if (p) __syncthreads();
        const ushort* ash = Agh + ((size_t)b * NPH + p) * 256 * 80;
        const ushort* asl = Agl + ((size_t)b * NPH + p) * 256 * 80;
#pragma unroll
        for (int e = 0; e < 6; ++e) {
            int idx = e * 256 + tid;
            if (idx < 1440) {
                int px = idx / 10, ch = idx - px * 10;
                int pr = px / 18, pc = px - pr * 18;
                int r = r0 - 1 + g + pr, c = pc - 1;
                bool inb = ((unsigned)r < 16u) && ((unsigned)c < 16u);
                uint4 vh, vl;
                if (inb) {
                    vh = *(const uint4*)(ash + (size_t)(r * 16 + c) * 80 + ch * 8);
                    vl = *(const uint4*)(asl + (size_t)(r * 16 + c) * 80 + ch * 8);
                } else {
                    vh = *(const uint4*)(zph + ch * 8);
                    vl = *(const uint4*)(zpl + ch * 8);
                }
                *(uint4*)(&AH[px * AST + ch * 8]) = vh;
                *(uint4*)(&AL[px * AST + ch * 8]) = vl;
            }
        }
        __syncthreads();

        const ushort* bsh = Bgh + (size_t)p * 2880 * 8;
        const ushort* bsl = Bgl + (size_t)p * 2880 * 8;
#pragma unroll
        for (int dw = 0; dw < 3; ++dw) {
            const int t = g * 3 + dw;
#pragma unroll
            for (int s = 0; s < 5; ++s) {
                bf16x8 ah = *(const bf16x8*)(&AH[(sbase + dw) * AST + s * 16 + koff]);
                bf16x8 al = *(const bf16x8*)(&AL[(sbase + dw) * AST + s * 16 + koff]);
                bf16x8 bh = *(const bf16x8*)(bsh + (size_t)((t * 5 + s) * 64 + lane) * 8);
                bf16x8 bl = *(const bf16x8*)(bsl + (size_t)((t * 5 + s) * 64 + lane) * 8);
                acc = __builtin_amdgcn_mfma_f32_32x32x16_bf16(ah, bh, acc, 0, 0, 0);
                acc = __builtin_amdgcn_mfma_f32_32x32x16_bf16(ah, bl, acc, 0, 0, 0);
                acc = __builtin_amdgcn_mfma_f32_32x32x16_bf16(al, bh, acc, 0, 0, 0);
            }
        }
    }

    int co = lane & 31;
    if (co < NCO) {
        float* pb = P + ((size_t)(g * 256 + b * 2 + half) * 128) * NCO;
#pragma unroll
        for (int r = 0; r < 16; ++r) {
            int px = wv * 32 + (r & 3) + 8 * (r >> 2) + 4 * (lane >> 5);
            pb[px * NCO + co] = acc[r];
        }
    }
}

// ---------------------------------------------------------------------------
// conv3_reduce v3: block = (b, px-quarter), all 16 couts, 64 px.
// ---------------------------------------------------------------------------
__global__ __launch_bounds__(256) void conv3_reduce(const float* __restrict__ P3,
                                                    ushort* __restrict__ A4h,
                                                    ushort* __restrict__ A4l) {
    __shared__ ushort SBH[2][64 * 80];
    __shared__ ushort SBL[2][64 * 80];
    int b = blockIdx.x, pxq = blockIdx.y;
    int t = threadIdx.x;
    int co = t & 15, pxg = t >> 4;
#pragma unroll
    for (int q = 0; q < 4; ++q) {
        int lpx64 = pxg * 4 + q;
        int px = pxq * 64 + lpx64;
        int bh = b * 2 + (px >> 7), lpx = px & 127;
        float s = 0.f;
#pragma unroll
        for (int zz = 0; zz < 3; ++zz)
            s += P3[((size_t)(zz * 256 + bh) * 128 + lpx) * 16 + co];
        float a9[9];
        spline_acts(s, a9);
        int ph = co >> 3, c8 = co & 7;
#pragma unroll
        for (int j = 0; j < 9; ++j) {
            ushort h, l2; bf16split(a9[j], h, l2);
            SBH[ph][lpx64 * 80 + c8 * 9 + j] = h;
            SBL[ph][lpx64 * 80 + c8 * 9 + j] = l2;
        }
        if (c8 == 7) {
#pragma unroll
            for (int w = 0; w < 8; ++w) {
                SBH[ph][lpx64 * 80 + 72 + w] = 0;
                SBL[ph][lpx64 * 80 + 72 + w] = 0;
            }
        }
    }
    __syncthreads();
#pragma unroll
    for (int ph = 0; ph < 2; ++ph) {
        size_t base = ((size_t)(b * 2 + ph) * 256 + pxq * 64) * 80;
#pragma unroll
        for (int e = 0; e < 3; ++e) {
            int q = e * 256 + t;
            if (q < 640) {
                *(uint4*)(A4h + base + q * 8) = *(const uint4*)(&SBH[ph][q * 8]);
                *(uint4*)(A4l + base + q * 8) = *(const uint4*)(&SBL[ph][q * 8]);
            }
        }
    }
}

// ---------------------------------------------------------------------------
// conv4_reduce_pool v2: block = (b, half); sum 3 partials + 2x2 pool.
// ---------------------------------------------------------------------------
__global__ __launch_bounds__(256) void conv4_reduce_pool(const float* __restrict__ P4,
                                                         float* __restrict__ pooled) {
    __shared__ float SM[32 * 33];
    int b = blockIdx.x, half = blockIdx.y;
    int t = threadIdx.x;
    int co = t & 31, pg = t >> 5;
    int bh = b * 2 + half;
#pragma unroll
    for (int q = 0; q < 4; ++q) {
        int pp = pg * 4 + q;
        int lr = pp >> 3, pc = pp & 7;
        int px00 = (2 * lr) * 16 + 2 * pc;
        float s00 = 0.f, s01 = 0.f, s10 = 0.f, s11 = 0.f;
#pragma unroll
        for (int zz = 0; zz < 3; ++zz) {
            const float* pb = P4 + ((size_t)(zz * 256 + bh) * 128) * 32 + co;
            s00 += pb[(size_t)px00 * 32];
            s01 += pb[(size_t)(px00 + 1) * 32];
            s10 += pb[(size_t)(px00 + 16) * 32];
            s11 += pb[(size_t)(px00 + 17) * 32];
        }
        SM[co * 33 + pp] = fmaxf(fmaxf(s00, s01), fmaxf(s10, s11));
    }
    __syncthreads();
#pragma unroll
    for (int e = 0; e < 4; ++e) {
        int idx = e * 256 + t;
        int co2 = idx >> 5, pp2 = idx & 31;
        int lr2 = pp2 >> 3, pc2 = pp2 & 7;
        pooled[(size_t)b * 2048 + co2 * 64 + (half * 4 + lr2) * 8 + pc2] = SM[co2 * 33 + pp2];
    }
}

// ---------------------------------------------------------------------------
// fc_big: 64x64 tile, 4x4/thread, K_TILE=32, split-K; float4 global staging.
// ---------------------------------------------------------------------------
template <int SPLIT>
__global__ __launch_bounds__(256) void fc_big(const float* __restrict__ A,
                                              const float* __restrict__ Wt,
                                              float* __restrict__ part,
                                              int M, int N, int K) {
    __shared__ float As[32][68];
    __shared__ float Ws[32][68];
    const int tid = threadIdx.x;
    const int tx = tid & 15, ty = tid >> 4;
    const int bm = blockIdx.y * 64, bn = blockIdx.x * 64;
    const int kc = K / SPLIT;
    const int kbeg = blockIdx.z * kc;
    float acc[4][4] = {};
    for (int k0 = kbeg; k0 < kbeg + kc; k0 += 32) {
#pragma unroll
        for (int e = 0; e < 2; ++e) {
            int q = e * 256 + tid;
            int r = q >> 3, k4 = (q & 7) * 4;
            float4 av = *(const float4*)&A[(size_t)(bm + r) * K + k0 + k4];
            float4 wv = *(const float4*)&Wt[(size_t)(bn + r) * K + k0 + k4];
            As[k4 + 0][r] = av.x; As[k4 + 1][r] = av.y;
            As[k4 + 2][r] = av.z; As[k4 + 3][r] = av.w;
            Ws[k4 + 0][r] = wv.x; Ws[k4 + 1][r] = wv.y;
            Ws[k4 + 2][r] = wv.z; Ws[k4 + 3][r] = wv.w;
        }
        __syncthreads();
#pragma unroll
        for (int kk = 0; kk < 32; ++kk) {
            float4 av = *(const float4*)(&As[kk][ty * 4]);
            float4 wv = *(const float4*)(&Ws[kk][tx * 4]);
            acc[0][0] = fmaf(av.x, wv.x, acc[0][0]);
            acc[0][1] = fmaf(av.x, wv.y, acc[0][1]);
            acc[0][2] = fmaf(av.x, wv.z, acc[0][2]);
            acc[0][3] = fmaf(av.x, wv.w, acc[0][3]);
            acc[1][0] = fmaf(av.y, wv.x, acc[1][0]);
            acc[1][1] = fmaf(av.y, wv.y, acc[1][1]);
            acc[1][2] = fmaf(av.y, wv.z, acc[1][2]);
            acc[1][3] = fmaf(av.y, wv.w, acc[1][3]);
            acc[2][0] = fmaf(av.z, wv.x, acc[2][0]);
            acc[2][1] = fmaf(av.z, wv.y, acc[2][1]);
            acc[2][2] = fmaf(av.z, wv.z, acc[2][2]);
            acc[2][3] = fmaf(av.z, wv.w, acc[2][3]);
            acc[3][0] = fmaf(av.w, wv.x, acc[3][0]);
            acc[3][1] = fmaf(av.w, wv.y, acc[3][1]);
            acc[3][2] = fmaf(av.w, wv.z, acc[3][2]);
            acc[3][3] = fmaf(av.w, wv.w, acc[3][3]);
        }
        __syncthreads();
    }
    float* p = part + (size_t)blockIdx.z * M * N;
#pragma unroll
    for (int i = 0; i < 4; ++i) {
        float4 v = make_float4(acc[i][0], acc[i][1], acc[i][2], acc[i][3]);
        *(float4*)&p[(size_t)(bm + ty * 4 + i) * N + (bn + tx * 4)] = v;
    }
}

template <int SPLIT>
__global__ void fc_reduce(const float* __restrict__ part, const float* __restrict__ bias,
                          float* __restrict__ C, int MN, int N, int relu) {
    int i = blockIdx.x * 256 + threadIdx.x;
    if (i >= MN) return;
    float s = bias[i % N];
#pragma unroll
    for (int z = 0; z < SPLIT; ++z) s += part[(size_t)z * MN + i];
    C[i] = relu ? fmaxf(s, 0.f) : s;
}

__global__ __launch_bounds__(256) void fc3_kernel(const float* __restrict__ A,
                                                  const float* __restrict__ Wt,
                                                  const float* __restrict__ bias,
                                                  float* __restrict__ C) {
    int gid = blockIdx.x * 256 + threadIdx.x;
    int wid = gid >> 6;
    int lane = gid & 63;
    int m = wid / 10, n = wid - m * 10;
    const float4* a = (const float4*)(A + (size_t)m * 1024);
    const float4* w = (const float4*)(Wt + (size_t)n * 1024);
    float s = 0.f;
#pragma unroll
    for (int it = 0; it < 4; ++it) {
        float4 av = a[it * 64 + lane];
        float4 wv = w[it * 64 + lane];
        s += av.x * wv.x + av.y * wv.y + av.z * wv.z + av.w * wv.w;
    }
#pragma unroll
    for (int off = 32; off; off >>= 1) s += __shfl_xor(s, off);
    if (lane == 0) C[wid] = s + bias[n];
}

// ---------------------------------------------------------------------------
extern "C" void kernel_launch(void* const* d_in, const int* in_sizes, int n_in,
                              void* d_out, int out_size, void* d_ws, size_t ws_size,
                              hipStream_t stream) {
    const float* x   = (const float*)d_in[0];
    const float* bw1 = (const float*)d_in[1];
    const float* sw1 = (const float*)d_in[2];
    const float* sc1 = (const float*)d_in[3];
    const float* bw2 = (const float*)d_in[4];
    const float* sw2 = (const float*)d_in[5];
    const float* sc2 = (const float*)d_in[6];
    const float* bw3 = (const float*)d_in[7];
    const float* sw3 = (const float*)d_in[8];
    const float* sc3 = (const float*)d_in[9];
    const float* bw4 = (const float*)d_in[10];
    const float* sw4 = (const float*)d_in[11];
    const float* sc4 = (const float*)d_in[12];
    const float* w1  = (const float*)d_in[13];
    const float* b1  = (const float*)d_in[14];
    const float* w2  = (const float*)d_in[15];
    const float* b2  = (const float*)d_in[16];
    const float* w3  = (const float*)d_in[17];
    const float* b3  = (const float*)d_in[18];

    float*  wsf = (float*)d_ws;
    ushort* wsu = (ushort*)d_ws;
    ushort* k1h = wsu + 110848;
    ushort* k1l = wsu + 120064;
    ushort* k2h = wsu + 129280;
    ushort* k2l = wsu + 143104;
    ushort* k3h = wsu + 156928;
    ushort* k3l = wsu + 179968;
    ushort* k4h = wsu + 203008;
    ushort* k4l = wsu + 249088;
    ushort* zph = wsu + 295168;
    ushort* zpl = wsu + 295248;
    ushort* A2h = wsu + 7864320;    // (B,1024,36)
    ushort* A2l = wsu + 12582912;
    ushort* A3h = wsu + 524288;     // (B,256,80)
    ushort* A3l = wsu + 3145728;
    ushort* A4h = wsu + 5767168;    // (B,2,256,80)
    ushort* A4l = wsu + 11010048;
    float* P3   = wsf + 9437184;    // 3x256x128x16 fp32
    float* P4   = wsf + 11534336;   // 3x256x128x32 fp32
    float* pooled = wsf + 262144;
    float* part1  = wsf + 524288;
    float* fc1o   = wsf + 2621440;
    float* part2  = wsf + 2883584;
    float* fc2o   = wsf + 3932160;

    prep_kernel<<<46, 256, 0, stream>>>(bw1, sw1, sc1, bw2, sw2, sc2,
                                        bw3, sw3, sc3, bw4, sw4, sc4,
                                        k1h, k1l, k2h, k2l, k3h, k3l, k4h, k4l,
                                        zph, zpl);

    conv1_fused<<<1024, 256, 0, stream>>>(x, k1h, k1l, A2h, A2l);
    conv2_strip<36, 9, 12, 56, 3, 8><<<512, 256, 0, stream>>>(A2h, A2l, k2h, k2l,
                                                              zph, zpl, A3h, A3l);
    conv34_part<1, 16><<<dim3(128, 2, 3), 256, 0, stream>>>(A3h, A3l, k3h, k3l,
                                                            zph, zpl, P3);
    conv3_reduce<<<dim3(128, 4), 256, 0, stream>>>(P3, A4h, A4l);
    conv34_part<2, 32><<<dim3(128, 2, 3), 256, 0, stream>>>(A4h, A4l, k4h, k4l,
                                                            zph, zpl, P4);
    conv4_reduce_pool<<<dim3(128, 2), 256, 0, stream>>>(P4, pooled);

    fc_big<8><<<dim3(32, 2, 8), 256, 0, stream>>>(pooled, w1, part1, 128, 2048, 2048);
    fc_reduce<8><<<1024, 256, 0, stream>>>(part1, b1, fc1o, 262144, 2048, 1);
    fc_big<8><<<dim3(16, 2, 8), 256, 0, stream>>>(fc1o, w2, part2, 128, 1024, 2048);
    fc_reduce<8><<<512, 256, 0, stream>>>(part2, b2, fc2o, 131072, 1024, 1);
    fc3_kernel<<<320, 256, 0, stream>>>(fc2o, w3, b3, (float*)d_out);
}